// Round 1
// baseline (241.652 us; speedup 1.0000x reference)
//
#include <hip/hip_runtime.h>
#include <math.h>

// PQC autoencoder: out = f(x) where f collapses to
//   psi = U x  (U = fixed 256x256 unitary from thetas),
//   probs = |psi|^2, y_j = sum_i s_j(i) probs_i, out = (y/||y||)^2 padded.
// Input normalization cancels (y/||y|| is scale-invariant in x) -> skipped.
//
// Kernel A: build W[j][i] = U[i][j] (float2) into d_ws, one wave per column j.
// Kernel B: fused GEMM (32768x256 @ 256x256 complex) + Walsh epilogue.

#define DEV __device__ __forceinline__

struct Psi4 { float re[4]; float im[4]; };

// amplitude index for lane L, register r:  a = (r<<6) | L
// qubit bit q of a:  q<6 -> (L>>q)&1 ;  q==6 -> r&1 ;  q==7 -> (r>>1)&1

template <int NQ>
DEV void ansatz(Psi4& s, const float* __restrict__ th, int lane) {
  int k = 0;
  for (int d = 0; d < 2; ++d) {
#pragma unroll
    for (int q = 0; q < NQ; ++q) {
      float tx = th[k], ty = th[k + 1], tz = th[k + 2];
      k += 3;
      // ---- RX(tx): u00=u11=c, u01=u10=-i*s  -> new = c*mine + (-i s)*partner
      float c, sn;
      sincosf(0.5f * tx, &sn, &c);
      if (q < 6) {
#pragma unroll
        for (int r = 0; r < 4; ++r) {
          float pre = __shfl_xor(s.re[r], 1 << q, 64);
          float pim = __shfl_xor(s.im[r], 1 << q, 64);
          float nr = c * s.re[r] + sn * pim;
          float ni = c * s.im[r] - sn * pre;
          s.re[r] = nr; s.im[r] = ni;
        }
      } else {
        const int b = (q == 6) ? 1 : 2;
        Psi4 t = s;
#pragma unroll
        for (int r = 0; r < 4; ++r) {
          s.re[r] = c * t.re[r] + sn * t.im[r ^ b];
          s.im[r] = c * t.im[r] - sn * t.re[r ^ b];
        }
      }
      // ---- RY(ty): new = c*mine + (mybit ? +s : -s)*partner
      sincosf(0.5f * ty, &sn, &c);
      if (q < 6) {
#pragma unroll
        for (int r = 0; r < 4; ++r) {
          float pre = __shfl_xor(s.re[r], 1 << q, 64);
          float pim = __shfl_xor(s.im[r], 1 << q, 64);
          float sg = ((lane >> q) & 1) ? sn : -sn;
          float nr = c * s.re[r] + sg * pre;
          float ni = c * s.im[r] + sg * pim;
          s.re[r] = nr; s.im[r] = ni;
        }
      } else {
        const int b = (q == 6) ? 1 : 2;
        Psi4 t = s;
#pragma unroll
        for (int r = 0; r < 4; ++r) {
          int bit = (q == 6) ? (r & 1) : ((r >> 1) & 1);
          float sg = bit ? sn : -sn;
          s.re[r] = c * t.re[r] + sg * t.re[r ^ b];
          s.im[r] = c * t.im[r] + sg * t.im[r ^ b];
        }
      }
      // ---- RZ(tz): diag(e^{-it/2}, e^{+it/2}); sg = bit? +s : -s
      //      new_re = c*re - sg*im ; new_im = c*im + sg*re
      sincosf(0.5f * tz, &sn, &c);
#pragma unroll
      for (int r = 0; r < 4; ++r) {
        int bit = (q < 6) ? ((lane >> q) & 1) : ((q == 6) ? (r & 1) : ((r >> 1) & 1));
        float sg = bit ? sn : -sn;
        float nr = c * s.re[r] - sg * s.im[r];
        float ni = c * s.im[r] + sg * s.re[r];
        s.re[r] = nr; s.im[r] = ni;
      }
    }
    // ---- CX chain: ctrl=q, tgt=q+1: if bit_ctrl==1 take value at a^(1<<tgt)
#pragma unroll
    for (int q = 0; q < NQ - 1; ++q) {
      const int t = q + 1;
      if (t < 6) {
        bool ctl = ((lane >> q) & 1) != 0;
#pragma unroll
        for (int r = 0; r < 4; ++r) {
          float pre = __shfl_xor(s.re[r], 1 << t, 64);
          float pim = __shfl_xor(s.im[r], 1 << t, 64);
          s.re[r] = ctl ? pre : s.re[r];
          s.im[r] = ctl ? pim : s.im[r];
        }
      } else if (t == 6) {  // ctrl bit5 (lane), target flips r bit0
        bool ctl = ((lane >> 5) & 1) != 0;
        Psi4 tt = s;
#pragma unroll
        for (int r = 0; r < 4; ++r) {
          s.re[r] = ctl ? tt.re[r ^ 1] : tt.re[r];
          s.im[r] = ctl ? tt.im[r ^ 1] : tt.im[r];
        }
      } else {  // t == 7: ctrl bit6 = r&1, target flips r bit1
        Psi4 tt = s;
#pragma unroll
        for (int r = 0; r < 4; ++r) {
          bool ctl = (r & 1) != 0;
          s.re[r] = ctl ? tt.re[r ^ 2] : tt.re[r];
          s.im[r] = ctl ? tt.im[r ^ 2] : tt.im[r];
        }
      }
    }
  }
}

__global__ void build_u(const float* __restrict__ th1, const float* __restrict__ th2,
                        const float* __restrict__ th3, float2* __restrict__ W) {
  const int lane = threadIdx.x & 63;
  const int wv = threadIdx.x >> 6;
  const int j = blockIdx.x * 4 + wv;  // basis-state column
  Psi4 s;
#pragma unroll
  for (int r = 0; r < 4; ++r) {
    int a = (r << 6) | lane;
    s.re[r] = (a == j) ? 1.f : 0.f;
    s.im[r] = 0.f;
  }
  ansatz<8>(s, th1, lane);
  ansatz<7>(s, th2, lane);
  ansatz<8>(s, th3, lane);
#pragma unroll
  for (int r = 0; r < 4; ++r)
    W[j * 256 + (r << 6) + lane] = make_float2(s.re[r], s.im[r]);
}

// 16 rows per block, 128 threads; thread owns columns i0=tid, i1=tid+128.
__global__ __launch_bounds__(128) void pqc_main(const float* __restrict__ x,
                                                const float2* __restrict__ W,
                                                float* __restrict__ out) {
  const int tid = threadIdx.x;
  const int lane = tid & 63;
  const int wv = tid >> 6;
  const int row0 = blockIdx.x * 16;

  __shared__ float xs[16][256];
  __shared__ float part[2][16][8];
  __shared__ float ys[16][8];
  __shared__ float inv_n[16];

  {  // stage x tile: 4096 floats = 1024 float4, 8 per thread
    const float4* xsrc = (const float4*)(x + (size_t)row0 * 256);
    float4* xdst = (float4*)&xs[0][0];
#pragma unroll
    for (int t = 0; t < 8; ++t) xdst[tid + 128 * t] = xsrc[tid + 128 * t];
  }
  __syncthreads();

  float ar0[16], ai0[16], ar1[16], ai1[16];
#pragma unroll
  for (int r = 0; r < 16; ++r) { ar0[r] = 0.f; ai0[r] = 0.f; ar1[r] = 0.f; ai1[r] = 0.f; }

  for (int j = 0; j < 256; j += 4) {
    float2 w00 = W[(j + 0) * 256 + tid];
    float2 w01 = W[(j + 1) * 256 + tid];
    float2 w02 = W[(j + 2) * 256 + tid];
    float2 w03 = W[(j + 3) * 256 + tid];
    float2 w10 = W[(j + 0) * 256 + tid + 128];
    float2 w11 = W[(j + 1) * 256 + tid + 128];
    float2 w12 = W[(j + 2) * 256 + tid + 128];
    float2 w13 = W[(j + 3) * 256 + tid + 128];
#pragma unroll
    for (int r = 0; r < 16; ++r) {
      float4 xv = *(const float4*)&xs[r][j];
      ar0[r] = fmaf(xv.x, w00.x, ar0[r]); ai0[r] = fmaf(xv.x, w00.y, ai0[r]);
      ar0[r] = fmaf(xv.y, w01.x, ar0[r]); ai0[r] = fmaf(xv.y, w01.y, ai0[r]);
      ar0[r] = fmaf(xv.z, w02.x, ar0[r]); ai0[r] = fmaf(xv.z, w02.y, ai0[r]);
      ar0[r] = fmaf(xv.w, w03.x, ar0[r]); ai0[r] = fmaf(xv.w, w03.y, ai0[r]);
      ar1[r] = fmaf(xv.x, w10.x, ar1[r]); ai1[r] = fmaf(xv.x, w10.y, ai1[r]);
      ar1[r] = fmaf(xv.y, w11.x, ar1[r]); ai1[r] = fmaf(xv.y, w11.y, ai1[r]);
      ar1[r] = fmaf(xv.z, w12.x, ar1[r]); ai1[r] = fmaf(xv.z, w12.y, ai1[r]);
      ar1[r] = fmaf(xv.w, w13.x, ar1[r]); ai1[r] = fmaf(xv.w, w13.y, ai1[r]);
    }
  }

  // Epilogue. i0=tid (bit7=0), i1=tid+128 (bit7=1); low 6 bits = lane, bit6 = wv.
  // q = p0+p1 feeds j>=1; d = p0-p1 feeds j=0 (bit7 sign).
#pragma unroll
  for (int r = 0; r < 16; ++r) {
    float p0 = fmaf(ar0[r], ar0[r], ai0[r] * ai0[r]);
    float p1 = fmaf(ar1[r], ar1[r], ai1[r] * ai1[r]);
    float qv = p0 + p1;
    float dv = p0 - p1;
#pragma unroll
    for (int b = 0; b < 6; ++b) {  // 6-stage WHT(q) + plain sum(d)
      float tq = __shfl_xor(qv, 1 << b, 64);
      qv = ((lane >> b) & 1) ? (tq - qv) : (qv + tq);
      dv += __shfl_xor(dv, 1 << b, 64);
    }
    // lane m holds Walsh_m(q); slots: 0=sum(d), 7=sum(q), s(1..6)=m=2^(s-1)
    if (lane == 0) { part[wv][r][0] = dv; part[wv][r][7] = qv; }
    else if (lane == 1)  part[wv][r][1] = qv;
    else if (lane == 2)  part[wv][r][2] = qv;
    else if (lane == 4)  part[wv][r][3] = qv;
    else if (lane == 8)  part[wv][r][4] = qv;
    else if (lane == 16) part[wv][r][5] = qv;
    else if (lane == 32) part[wv][r][6] = qv;
  }
  __syncthreads();

  {  // y[r][j]: j=0 from d-sums; j=1 from q-sums with wave sign (bit6); j>=2 Walsh slot 8-j
    int r = tid >> 3, jj = tid & 7;
    float y;
    if (jj == 0)      y = part[0][r][0] + part[1][r][0];
    else if (jj == 1) y = part[0][r][7] - part[1][r][7];
    else { int sl = 8 - jj; y = part[0][r][sl] + part[1][r][sl]; }
    ys[r][jj] = y;
  }
  __syncthreads();

  if (tid < 16) {
    float n = 0.f;
#pragma unroll
    for (int jj = 0; jj < 8; ++jj) { float v = ys[tid][jj]; n = fmaf(v, v, n); }
    n = sqrtf(n);
    inv_n[tid] = (n == 0.f) ? 0.f : 1.f / n;  // y==0 -> cv==0, matches ref guard
  }
  __syncthreads();

#pragma unroll
  for (int r = 0; r < 16; ++r) {
    float v = 0.f;
    if (tid < 8) { float t = ys[r][tid] * inv_n[r]; v = t * t; }
    size_t base = ((size_t)(row0 + r)) * 256;
    out[base + tid] = v;
    out[base + tid + 128] = 0.f;
  }
}

extern "C" void kernel_launch(void* const* d_in, const int* in_sizes, int n_in,
                              void* d_out, int out_size, void* d_ws, size_t ws_size,
                              hipStream_t stream) {
  const float* x = (const float*)d_in[0];
  const float* th1 = (const float*)d_in[1];
  const float* th2 = (const float*)d_in[2];
  const float* th3 = (const float*)d_in[3];
  float* out = (float*)d_out;
  float2* W = (float2*)d_ws;  // 256*256 float2 = 512 KB

  build_u<<<64, 256, 0, stream>>>(th1, th2, th3, W);
  pqc_main<<<2048, 128, 0, stream>>>(x, W, out);
}

// Round 2
// 142.398 us; speedup vs baseline: 1.6970x; 1.6970x over previous
//
#include <hip/hip_runtime.h>
#include <math.h>

// PQC autoencoder. Algebra: out = g(U x) where U = fixed 256x256 unitary from
// thetas (input normalization cancels). Kernel A builds V = [Re U; Im U]
// (512x256) as split-bf16 (hi+lo), pre-swizzled into MFMA B-fragment stream
// order. Kernel B: split-bf16 MFMA GEMM (32768x512x256, 3 cross terms) with
// fused |psi|^2 -> Walsh -> normalize epilogue.

#define DEV __device__ __forceinline__

typedef __attribute__((ext_vector_type(8))) short short8;   // 8 bf16
typedef __attribute__((ext_vector_type(4))) float f32x4;

DEV unsigned short bf_hi(float v) {
  unsigned u = __float_as_uint(v);
  unsigned r = (u + 0x7FFFu + ((u >> 16) & 1u)) >> 16;
  return (unsigned short)r;
}

// ---------------------------------------------------------------------------
// Kernel A: build V in swizzled fragment order.
// Vsw flat index = k*32768 + g*1024 + hl*512 + L*8 + jj
//   k = K-step (kk>>5), g = w*8 + t (w=i>>6, t covers 4 re + 4 im 16-col tiles)
//   L = quad*16 + (n&15) with quad = (kk>>3)&3, jj = kk&7, hl = 0 hi / 1 lo.
// ---------------------------------------------------------------------------

struct Psi4 { float re[4]; float im[4]; };

// amplitude a = (r<<6) | lane; qubit bit q: q<6 -> (lane>>q)&1; q==6 -> r&1; q==7 -> (r>>1)&1

template <int NQ>
DEV void ansatz(Psi4& s, const float2* __restrict__ tr, int lane) {
  int k = 0;
  for (int d = 0; d < 2; ++d) {
#pragma unroll
    for (int q = 0; q < NQ; ++q) {
      float2 gx = tr[k], gy = tr[k + 1], gz = tr[k + 2];
      k += 3;
      // RX: new = c*mine - i*s*partner
      float sn = gx.x, c = gx.y;
      if (q < 6) {
#pragma unroll
        for (int r = 0; r < 4; ++r) {
          float pre = __shfl_xor(s.re[r], 1 << q, 64);
          float pim = __shfl_xor(s.im[r], 1 << q, 64);
          float nr = c * s.re[r] + sn * pim;
          float ni = c * s.im[r] - sn * pre;
          s.re[r] = nr; s.im[r] = ni;
        }
      } else {
        const int b = (q == 6) ? 1 : 2;
        Psi4 t = s;
#pragma unroll
        for (int r = 0; r < 4; ++r) {
          s.re[r] = c * t.re[r] + sn * t.im[r ^ b];
          s.im[r] = c * t.im[r] - sn * t.re[r ^ b];
        }
      }
      // RY: new = c*mine + (mybit ? +s : -s)*partner
      sn = gy.x; c = gy.y;
      if (q < 6) {
#pragma unroll
        for (int r = 0; r < 4; ++r) {
          float pre = __shfl_xor(s.re[r], 1 << q, 64);
          float pim = __shfl_xor(s.im[r], 1 << q, 64);
          float sg = ((lane >> q) & 1) ? sn : -sn;
          float nr = c * s.re[r] + sg * pre;
          float ni = c * s.im[r] + sg * pim;
          s.re[r] = nr; s.im[r] = ni;
        }
      } else {
        const int b = (q == 6) ? 1 : 2;
        Psi4 t = s;
#pragma unroll
        for (int r = 0; r < 4; ++r) {
          int bit = (q == 6) ? (r & 1) : ((r >> 1) & 1);
          float sg = bit ? sn : -sn;
          s.re[r] = c * t.re[r] + sg * t.re[r ^ b];
          s.im[r] = c * t.im[r] + sg * t.im[r ^ b];
        }
      }
      // RZ: diag(e^{-it/2}, e^{+it/2})
      sn = gz.x; c = gz.y;
#pragma unroll
      for (int r = 0; r < 4; ++r) {
        int bit = (q < 6) ? ((lane >> q) & 1) : ((q == 6) ? (r & 1) : ((r >> 1) & 1));
        float sg = bit ? sn : -sn;
        float nr = c * s.re[r] - sg * s.im[r];
        float ni = c * s.im[r] + sg * s.re[r];
        s.re[r] = nr; s.im[r] = ni;
      }
    }
    // CX chain ctrl=q tgt=q+1
#pragma unroll
    for (int q = 0; q < NQ - 1; ++q) {
      const int t = q + 1;
      if (t < 6) {
        bool ctl = ((lane >> q) & 1) != 0;
#pragma unroll
        for (int r = 0; r < 4; ++r) {
          float pre = __shfl_xor(s.re[r], 1 << t, 64);
          float pim = __shfl_xor(s.im[r], 1 << t, 64);
          s.re[r] = ctl ? pre : s.re[r];
          s.im[r] = ctl ? pim : s.im[r];
        }
      } else if (t == 6) {
        bool ctl = ((lane >> 5) & 1) != 0;
        Psi4 tt = s;
#pragma unroll
        for (int r = 0; r < 4; ++r) {
          s.re[r] = ctl ? tt.re[r ^ 1] : tt.re[r];
          s.im[r] = ctl ? tt.im[r ^ 1] : tt.im[r];
        }
      } else {
        Psi4 tt = s;
#pragma unroll
        for (int r = 0; r < 4; ++r) {
          bool ctl = (r & 1) != 0;
          s.re[r] = ctl ? tt.re[r ^ 2] : tt.re[r];
          s.im[r] = ctl ? tt.im[r ^ 2] : tt.im[r];
        }
      }
    }
  }
}

DEV void store_v(unsigned short* __restrict__ Vsw, int n, int kk, float v) {
  int k = kk >> 5, rem = kk & 31, quad = rem >> 3, jj = rem & 7;
  int nn = n & 255;
  int w = (nn >> 6) & 3, t = (nn >> 4) & 3, cl = nn & 15;
  int g = w * 8 + ((n >= 256) ? 4 + t : t);
  int L = quad * 16 + cl;
  unsigned short hi = bf_hi(v);
  float hif = __uint_as_float(((unsigned)hi) << 16);
  unsigned short lo = bf_hi(v - hif);
  size_t base = (size_t)k * 32768 + (size_t)g * 1024 + (size_t)L * 8 + jj;
  Vsw[base] = hi;
  Vsw[base + 512] = lo;
}

__global__ void build_u(const float* __restrict__ th1, const float* __restrict__ th2,
                        const float* __restrict__ th3, unsigned short* __restrict__ Vsw) {
  __shared__ float2 tr[144];
  const int lane = threadIdx.x;  // 64 threads, 1 wave
  for (int i = lane; i < 138; i += 64) {
    float th = (i < 48) ? th1[i] : (i < 90) ? th2[i - 48] : th3[i - 90];
    float s, c;
    sincosf(0.5f * th, &s, &c);
    tr[i] = make_float2(s, c);
  }
  __syncthreads();

  const int j = blockIdx.x;  // basis column = K index
  Psi4 s;
#pragma unroll
  for (int r = 0; r < 4; ++r) {
    int a = (r << 6) | lane;
    s.re[r] = (a == j) ? 1.f : 0.f;
    s.im[r] = 0.f;
  }
  ansatz<8>(s, tr, lane);
  ansatz<7>(s, tr + 48, lane);
  ansatz<8>(s, tr + 90, lane);
#pragma unroll
  for (int r = 0; r < 4; ++r) {
    int a = (r << 6) | lane;
    store_v(Vsw, a, j, s.re[r]);
    store_v(Vsw, a + 256, j, s.im[r]);
  }
}

// ---------------------------------------------------------------------------
// Kernel B: 32 rows/block, 256 threads (4 waves). Wave w owns amplitude range
// i in [w*64, w*64+64) for both re and im -> fused epilogue stays in-wave.
// ---------------------------------------------------------------------------

__global__ __launch_bounds__(256, 2) void pqc_main(const float* __restrict__ x,
                                                   const unsigned short* __restrict__ Vsw,
                                                   float* __restrict__ out) {
  const int tid = threadIdx.x;
  const int w = tid >> 6;
  const int L = tid & 63;
  const int quad = L >> 4;
  const int c = L & 15;
  const int row0 = blockIdx.x * 32;

  __shared__ unsigned short Xh[32 * 264];  // padded stride 264 (2-way alias, free)
  __shared__ unsigned short Xl[32 * 264];
  __shared__ float part[4][32][8];
  __shared__ float ys[32][8];
  __shared__ float invn[32];

  // ---- stage X tile as bf16 hi/lo: 8192 floats = 2048 float4, 8/thread
  {
    const float4* xsrc = (const float4*)(x + (size_t)row0 * 256);
#pragma unroll
    for (int i = 0; i < 8; ++i) {
      int e = i * 256 + tid;          // float4 index
      int row = e >> 6;
      int col = (e & 63) * 4;
      float4 f = xsrc[e];
      ushort4 h, l;
      h.x = bf_hi(f.x); l.x = bf_hi(f.x - __uint_as_float(((unsigned)h.x) << 16));
      h.y = bf_hi(f.y); l.y = bf_hi(f.y - __uint_as_float(((unsigned)h.y) << 16));
      h.z = bf_hi(f.z); l.z = bf_hi(f.z - __uint_as_float(((unsigned)h.z) << 16));
      h.w = bf_hi(f.w); l.w = bf_hi(f.w - __uint_as_float(((unsigned)h.w) << 16));
      *(ushort4*)&Xh[row * 264 + col] = h;
      *(ushort4*)&Xl[row * 264 + col] = l;
    }
  }
  __syncthreads();

  // ---- MFMA K-loop
  f32x4 acc[2][8];
#pragma unroll
  for (int mt = 0; mt < 2; ++mt)
#pragma unroll
    for (int t = 0; t < 8; ++t) acc[mt][t] = (f32x4){0.f, 0.f, 0.f, 0.f};

  // A frag: lane holds A[m = mt*16 + c][k*32 + quad*8 + j]
  const int a_off0 = c * 264 + quad * 8;
  const int a_off1 = (16 + c) * 264 + quad * 8;
  // B frag: lane holds B[k*32 + quad*8 + j][n], swizzled stream order
  const unsigned short* pb = Vsw + (size_t)w * 8192 + (size_t)L * 8;

  for (int k = 0; k < 8; ++k) {
    short8 ah0 = *(const short8*)&Xh[a_off0 + k * 32];
    short8 ah1 = *(const short8*)&Xh[a_off1 + k * 32];
    short8 al0 = *(const short8*)&Xl[a_off0 + k * 32];
    short8 al1 = *(const short8*)&Xl[a_off1 + k * 32];
    const unsigned short* pk = pb + (size_t)k * 32768;
#pragma unroll
    for (int t = 0; t < 8; ++t) {
      short8 bh = *(const short8*)(pk + t * 1024);
      short8 bl = *(const short8*)(pk + t * 1024 + 512);
      acc[0][t] = __builtin_amdgcn_mfma_f32_16x16x32_bf16(ah0, bh, acc[0][t], 0, 0, 0);
      acc[0][t] = __builtin_amdgcn_mfma_f32_16x16x32_bf16(ah0, bl, acc[0][t], 0, 0, 0);
      acc[0][t] = __builtin_amdgcn_mfma_f32_16x16x32_bf16(al0, bh, acc[0][t], 0, 0, 0);
      acc[1][t] = __builtin_amdgcn_mfma_f32_16x16x32_bf16(ah1, bh, acc[1][t], 0, 0, 0);
      acc[1][t] = __builtin_amdgcn_mfma_f32_16x16x32_bf16(ah1, bl, acc[1][t], 0, 0, 0);
      acc[1][t] = __builtin_amdgcn_mfma_f32_16x16x32_bf16(al1, bh, acc[1][t], 0, 0, 0);
    }
  }

  // ---- epilogue: probs -> Walsh partials (in-wave), combine via LDS
  // D layout: row m = mt*16 + quad*4 + reg, col n = c. Tile t<4: re at
  // i = w*64 + t*16 + c; tile t+4: im at same i.
#pragma unroll
  for (int mt = 0; mt < 2; ++mt) {
#pragma unroll
    for (int r = 0; r < 4; ++r) {
      float p0 = acc[mt][0][r] * acc[mt][0][r] + acc[mt][4][r] * acc[mt][4][r];
      float p1 = acc[mt][1][r] * acc[mt][1][r] + acc[mt][5][r] * acc[mt][5][r];
      float p2 = acc[mt][2][r] * acc[mt][2][r] + acc[mt][6][r] * acc[mt][6][r];
      float p3 = acc[mt][3][r] * acc[mt][3][r] + acc[mt][7][r] * acc[mt][7][r];
      float s01 = p0 + p1, s23 = p2 + p3;
      float av = s01 + s23;            // plain over t  (feeds j=0,1,4..7)
      float bv = s01 - s23;            // sign bit5 (t>>1) -> j=2
      float cv = (p0 - p1) + (p2 - p3);  // sign bit4 (t&1) -> j=3
#pragma unroll
      for (int st = 0; st < 4; ++st) {  // butterflies over c (within quad)
        int msk = 1 << st;
        float ta = __shfl_xor(av, msk, 64);
        av = ((c >> st) & 1) ? (ta - av) : (av + ta);
        bv += __shfl_xor(bv, msk, 64);
        cv += __shfl_xor(cv, msk, 64);
      }
      int m = mt * 16 + quad * 4 + r;
      // after signed WHT: lane c holds Walsh_c; c=0 plain sum, c=2^b -> sign bit_b
      if (c == 0) {
        part[w][m][0] = ((w >> 1) & 1) ? -av : av;  // j=0: bit7(i) = w>>1
        part[w][m][1] = (w & 1) ? -av : av;         // j=1: bit6(i) = w&1
        part[w][m][2] = bv;
        part[w][m][3] = cv;
      } else if (c == 8) part[w][m][4] = av;   // j=4: bit3
      else if (c == 4) part[w][m][5] = av;     // j=5: bit2
      else if (c == 2) part[w][m][6] = av;     // j=6: bit1
      else if (c == 1) part[w][m][7] = av;     // j=7: bit0
    }
  }
  __syncthreads();

  {
    int m = tid >> 3, jj = tid & 7;
    ys[m][jj] = part[0][m][jj] + part[1][m][jj] + part[2][m][jj] + part[3][m][jj];
  }
  __syncthreads();

  if (tid < 32) {
    float n = 0.f;
#pragma unroll
    for (int jj = 0; jj < 8; ++jj) { float v = ys[tid][jj]; n = fmaf(v, v, n); }
    n = sqrtf(n);
    invn[tid] = (n == 0.f) ? 0.f : 1.f / n;
  }
  __syncthreads();

  // ---- write out: 32 rows x 64 float4 = 2048 float4, 8/thread
  float4* o4 = (float4*)(out + (size_t)row0 * 256);
#pragma unroll
  for (int i = 0; i < 8; ++i) {
    int e = i * 256 + tid;
    int row = e >> 6;
    int c4 = (e & 63) * 4;
    float4 v = make_float4(0.f, 0.f, 0.f, 0.f);
    if (c4 < 8) {
      float iv = invn[row];
      float t0 = ys[row][c4 + 0] * iv;
      float t1 = ys[row][c4 + 1] * iv;
      float t2 = ys[row][c4 + 2] * iv;
      float t3 = ys[row][c4 + 3] * iv;
      v = make_float4(t0 * t0, t1 * t1, t2 * t2, t3 * t3);
    }
    o4[e] = v;
  }
}

extern "C" void kernel_launch(void* const* d_in, const int* in_sizes, int n_in,
                              void* d_out, int out_size, void* d_ws, size_t ws_size,
                              hipStream_t stream) {
  const float* x = (const float*)d_in[0];
  const float* th1 = (const float*)d_in[1];
  const float* th2 = (const float*)d_in[2];
  const float* th3 = (const float*)d_in[3];
  float* out = (float*)d_out;
  unsigned short* Vsw = (unsigned short*)d_ws;  // 512 KB swizzled V (hi+lo)

  build_u<<<256, 64, 0, stream>>>(th1, th2, th3, Vsw);
  pqc_main<<<1024, 256, 0, stream>>>(x, Vsw, out);
}

// Round 3
// 129.852 us; speedup vs baseline: 1.8610x; 1.0966x over previous
//
#include <hip/hip_runtime.h>
#include <math.h>

// PQC autoencoder. out = g(U x), U = fixed 256x256 unitary from thetas
// (input normalization cancels: y/||y|| scale-invariant in x).
// Kernel A (build_u): fused-gate statevector sim per basis column ->
//   V = [Re U; Im U] split-bf16 hi/lo in MFMA-B-fragment stream order.
//   Chain compression: RZ*RY*RX merged per qubit; qubit-pairs fused to 4x4
//   (3 parallel shfl partners = 1 latency step); CX chain = prefix-XOR
//   permutation applied in ONE bpermute step.
// Kernel B (pqc_main): split-bf16 MFMA GEMM (32768 x 512 x 256, 3 cross
//   terms), A-frags straight from global (no LDS in main loop), fused
//   |psi|^2 -> Walsh -> normalize epilogue.

#define DEV __device__ __forceinline__

typedef __attribute__((ext_vector_type(8))) short short8;   // 8 bf16
typedef __attribute__((ext_vector_type(4))) float f32x4;

DEV float2 cmul(float2 a, float2 b) {
  return make_float2(a.x * b.x - a.y * b.y, a.x * b.y + a.y * b.x);
}
DEV float2 cadd(float2 a, float2 b) { return make_float2(a.x + b.x, a.y + b.y); }

DEV unsigned short bf_rne(float v) {
  unsigned u = __float_as_uint(v);
  return (unsigned short)((u + 0x7FFFu + ((u >> 16) & 1u)) >> 16);
}

// ---------------------------------------------------------------------------
// Kernel A
// ---------------------------------------------------------------------------

struct Psi4 { float re[4]; float im[4]; };
// amplitude a = (r<<6)|lane; bit q of a: q<6 -> lane bit q; q==6 -> r&1; q==7 -> r>>1

// fused 2-qubit gate on lane bits (Q, Q+1); M* = 2x2 complex [row*2+col]
template <int Q>
DEV void pair_gate(Psi4& s, const float2* __restrict__ Mlo,
                   const float2* __restrict__ Mhi, int lane) {
  const int b0 = (lane >> Q) & 1, b1 = (lane >> (Q + 1)) & 1;
  float2 lo_d = Mlo[b0 * 2 + b0];
  float2 lo_o = Mlo[b0 * 2 + (b0 ^ 1)];
  float2 hi_d = Mhi[b1 * 2 + b1];
  float2 hi_o = Mhi[b1 * 2 + (b1 ^ 1)];
  float2 c00 = cmul(hi_d, lo_d);   // own
  float2 c01 = cmul(hi_d, lo_o);   // partner xor m0
  float2 c10 = cmul(hi_o, lo_d);   // partner xor m1
  float2 c11 = cmul(hi_o, lo_o);   // partner xor m0|m1
  const int m0 = 1 << Q, m1 = 2 << Q;
#pragma unroll
  for (int r = 0; r < 4; ++r) {
    float ar = s.re[r], ai = s.im[r];
    float p0r = __shfl_xor(ar, m0, 64), p0i = __shfl_xor(ai, m0, 64);
    float p1r = __shfl_xor(ar, m1, 64), p1i = __shfl_xor(ai, m1, 64);
    float p2r = __shfl_xor(ar, m0 | m1, 64), p2i = __shfl_xor(ai, m0 | m1, 64);
    float nr = c00.x * ar - c00.y * ai + c01.x * p0r - c01.y * p0i
             + c10.x * p1r - c10.y * p1i + c11.x * p2r - c11.y * p2i;
    float ni = c00.x * ai + c00.y * ar + c01.x * p0i + c01.y * p0r
             + c10.x * p1i + c10.y * p1r + c11.x * p2i + c11.y * p2r;
    s.re[r] = nr; s.im[r] = ni;
  }
}

// fused 2-qubit gate on register bits (q6=bit0 of r, q7=bit1 of r)
DEV void regpair_gate(Psi4& s, const float2* __restrict__ Mlo,
                      const float2* __restrict__ Mhi) {
  float nr[4], ni[4];
#pragma unroll
  for (int r = 0; r < 4; ++r) {
    const int b0 = r & 1, b1 = (r >> 1) & 1;
    float2 c00 = cmul(Mhi[b1 * 2 + b1], Mlo[b0 * 2 + b0]);
    float2 c01 = cmul(Mhi[b1 * 2 + b1], Mlo[b0 * 2 + (b0 ^ 1)]);
    float2 c10 = cmul(Mhi[b1 * 2 + (b1 ^ 1)], Mlo[b0 * 2 + b0]);
    float2 c11 = cmul(Mhi[b1 * 2 + (b1 ^ 1)], Mlo[b0 * 2 + (b0 ^ 1)]);
    nr[r] = c00.x * s.re[r] - c00.y * s.im[r]
          + c01.x * s.re[r ^ 1] - c01.y * s.im[r ^ 1]
          + c10.x * s.re[r ^ 2] - c10.y * s.im[r ^ 2]
          + c11.x * s.re[r ^ 3] - c11.y * s.im[r ^ 3];
    ni[r] = c00.x * s.im[r] + c00.y * s.re[r]
          + c01.x * s.im[r ^ 1] + c01.y * s.re[r ^ 1]
          + c10.x * s.im[r ^ 2] + c10.y * s.re[r ^ 2]
          + c11.x * s.im[r ^ 3] + c11.y * s.re[r ^ 3];
  }
#pragma unroll
  for (int r = 0; r < 4; ++r) { s.re[r] = nr[r]; s.im[r] = ni[r]; }
}

// single gate on register bit0 (qubit 6 of the 7q ansatz)
DEV void reg0_gate(Psi4& s, const float2* __restrict__ M) {
  float nr[4], ni[4];
#pragma unroll
  for (int r = 0; r < 4; ++r) {
    const int b = r & 1;
    float2 d = M[b * 2 + b], o = M[b * 2 + (b ^ 1)];
    nr[r] = d.x * s.re[r] - d.y * s.im[r] + o.x * s.re[r ^ 1] - o.y * s.im[r ^ 1];
    ni[r] = d.x * s.im[r] + d.y * s.re[r] + o.x * s.im[r ^ 1] + o.y * s.re[r ^ 1];
  }
#pragma unroll
  for (int r = 0; r < 4; ++r) { s.re[r] = nr[r]; s.im[r] = ni[r]; }
}

// CX chain (ctrl q, tgt q+1, q=0..NQ-2) == prefix-XOR permutation.
// Inverse map: source bit s_k = a_k ^ a_{k-1} (k in chain), applied in one step.
template <bool FULL8>
DEV void perm_cx(Psi4& s, int lane) {
  const int slane = (lane ^ (lane << 1)) & 63;
  const bool L5 = ((lane >> 5) & 1) != 0;
  float nr[4], ni[4];
#pragma unroll
  for (int r = 0; r < 4; ++r) {
    const int r0 = r & 1, r1 = (r >> 1) & 1;
    const int hiBit = FULL8 ? (r1 ^ r0) : r1;  // source reg bit1
    const int sA = (hiBit << 1) | r0;          // source reg when dest L5==0
    const int sB = sA ^ 1;                     // when dest L5==1 (s6 = r0^L5)
    float aRe = __shfl(s.re[sA], slane, 64);
    float aIm = __shfl(s.im[sA], slane, 64);
    float bRe = __shfl(s.re[sB], slane, 64);
    float bIm = __shfl(s.im[sB], slane, 64);
    nr[r] = L5 ? bRe : aRe;
    ni[r] = L5 ? bIm : aIm;
  }
#pragma unroll
  for (int r = 0; r < 4; ++r) { s.re[r] = nr[r]; s.im[r] = ni[r]; }
}

template <int NQ>
DEV void ansatz_f(Psi4& s, const float2* __restrict__ Mg, int lane) {
#pragma unroll
  for (int d = 0; d < 2; ++d) {
    const float2* Md = Mg + d * NQ * 4;
    pair_gate<0>(s, Md + 0, Md + 4, lane);
    pair_gate<2>(s, Md + 8, Md + 12, lane);
    pair_gate<4>(s, Md + 16, Md + 20, lane);
    if (NQ == 8) regpair_gate(s, Md + 24, Md + 28);
    else reg0_gate(s, Md + 24);
    perm_cx<NQ == 8>(s, lane);
  }
}

// Vsw layout (validated R2): idx = k*32768 + g*1024 + hl*512 + L*8 + jj
DEV void store_v(unsigned short* __restrict__ Vsw, int n, int kk, float v) {
  int k = kk >> 5, rem = kk & 31, quad = rem >> 3, jj = rem & 7;
  int nn = n & 255;
  int w = (nn >> 6) & 3, t = (nn >> 4) & 3, cl = nn & 15;
  int g = w * 8 + ((n >= 256) ? 4 + t : t);
  int L = quad * 16 + cl;
  unsigned short hi = bf_rne(v);
  float hif = __uint_as_float(((unsigned)hi) << 16);
  unsigned short lo = bf_rne(v - hif);
  size_t base = (size_t)k * 32768 + (size_t)g * 1024 + (size_t)L * 8 + jj;
  Vsw[base] = hi;
  Vsw[base + 512] = lo;
}

__global__ void build_u(const float* __restrict__ th1, const float* __restrict__ th2,
                        const float* __restrict__ th3, unsigned short* __restrict__ Vsw) {
  __shared__ float2 Mg[46 * 4];  // merged RZ*RY*RX per (ansatz, depth, qubit)
  const int tid = threadIdx.x;
  if (tid < 46) {
    float thx, thy, thz;
    if (tid < 16)      { thx = th1[tid * 3]; thy = th1[tid * 3 + 1]; thz = th1[tid * 3 + 2]; }
    else if (tid < 30) { int u = (tid - 16) * 3; thx = th2[u]; thy = th2[u + 1]; thz = th2[u + 2]; }
    else               { int u = (tid - 30) * 3; thx = th3[u]; thy = th3[u + 1]; thz = th3[u + 2]; }
    float sx, cx_, sy, cy_, sz, cz_;
    sincosf(0.5f * thx, &sx, &cx_);
    sincosf(0.5f * thy, &sy, &cy_);
    sincosf(0.5f * thz, &sz, &cz_);
    float2 rx[4] = {{cx_, 0}, {0, -sx}, {0, -sx}, {cx_, 0}};
    float2 ry[4] = {{cy_, 0}, {-sy, 0}, {sy, 0}, {cy_, 0}};
    float2 A0 = cadd(cmul(ry[0], rx[0]), cmul(ry[1], rx[2]));
    float2 A1 = cadd(cmul(ry[0], rx[1]), cmul(ry[1], rx[3]));
    float2 A2 = cadd(cmul(ry[2], rx[0]), cmul(ry[3], rx[2]));
    float2 A3 = cadd(cmul(ry[2], rx[1]), cmul(ry[3], rx[3]));
    float2 ezm = make_float2(cz_, -sz), ezp = make_float2(cz_, sz);
    Mg[tid * 4 + 0] = cmul(ezm, A0);
    Mg[tid * 4 + 1] = cmul(ezm, A1);
    Mg[tid * 4 + 2] = cmul(ezp, A2);
    Mg[tid * 4 + 3] = cmul(ezp, A3);
  }
  __syncthreads();

  const int lane = tid & 63;
  const int j = blockIdx.x * 4 + (tid >> 6);  // basis column = K index
  Psi4 s;
#pragma unroll
  for (int r = 0; r < 4; ++r) {
    int a = (r << 6) | lane;
    s.re[r] = (a == j) ? 1.f : 0.f;
    s.im[r] = 0.f;
  }
  ansatz_f<8>(s, Mg, lane);             // gates 0..15
  ansatz_f<7>(s, Mg + 16 * 4, lane);    // gates 16..29
  ansatz_f<8>(s, Mg + 30 * 4, lane);    // gates 30..45
#pragma unroll
  for (int r = 0; r < 4; ++r) {
    int a = (r << 6) | lane;
    store_v(Vsw, a, j, s.re[r]);
    store_v(Vsw, a + 256, j, s.im[r]);
  }
}

// ---------------------------------------------------------------------------
// Kernel B: 64 rows/block, 512 threads (8 waves = 4 B-slices x 2 row-halves).
// No LDS in main loop: A-frags from global (L1-shared across w-slices),
// B-frags stream from Vsw in swizzled order (L2-resident, 512 KB).
// ---------------------------------------------------------------------------

DEV void split8(float4 f0, float4 f1, short8& h, short8& l) {
  float v0 = f0.x, v1 = f0.y, v2 = f0.z, v3 = f0.w;
  float v4 = f1.x, v5 = f1.y, v6 = f1.z, v7 = f1.w;
#define SPLIT1(i, v)                                            \
  {                                                             \
    unsigned u = __float_as_uint(v);                            \
    h[i] = (short)(u >> 16); /* trunc hi */                     \
    float hf = __uint_as_float(u & 0xFFFF0000u);                \
    l[i] = (short)(__float_as_uint((v) - hf) >> 16);            \
  }
  SPLIT1(0, v0) SPLIT1(1, v1) SPLIT1(2, v2) SPLIT1(3, v3)
  SPLIT1(4, v4) SPLIT1(5, v5) SPLIT1(6, v6) SPLIT1(7, v7)
#undef SPLIT1
}

__global__ __launch_bounds__(512, 4) void pqc_main(const float* __restrict__ x,
                                                   const unsigned short* __restrict__ Vsw,
                                                   float* __restrict__ out) {
  const int tid = threadIdx.x;
  const int ww = tid >> 6;
  const int w = ww & 3;        // B-slice (amp range w*64..w*64+64, re+im)
  const int h = ww >> 2;       // row half (32 rows each)
  const int L = tid & 63;
  const int quad = L >> 4;
  const int c = L & 15;
  const int row0 = blockIdx.x * 64;

  __shared__ float part[4][64][8];
  __shared__ float ys[64][8];
  __shared__ float invn[64];

  f32x4 acc[2][8];
#pragma unroll
  for (int mt = 0; mt < 2; ++mt)
#pragma unroll
    for (int t = 0; t < 8; ++t) acc[mt][t] = (f32x4){0.f, 0.f, 0.f, 0.f};

  // A source rows: lane holds A[m = mt*16+c][k*32 + quad*8 + (0..7)]
  const float* xr0 = x + (size_t)(row0 + h * 32 + c) * 256 + quad * 8;
  const float* xr1 = xr0 + 16 * 256;
  const unsigned short* pb = Vsw + (size_t)w * 8192 + (size_t)L * 8;

#pragma unroll
  for (int k = 0; k < 8; ++k) {
    float4 a00 = *(const float4*)(xr0 + k * 32);
    float4 a01 = *(const float4*)(xr0 + k * 32 + 4);
    float4 a10 = *(const float4*)(xr1 + k * 32);
    float4 a11 = *(const float4*)(xr1 + k * 32 + 4);
    short8 ah0, al0, ah1, al1;
    split8(a00, a01, ah0, al0);
    split8(a10, a11, ah1, al1);
    const unsigned short* pk = pb + (size_t)k * 32768;
#pragma unroll
    for (int t = 0; t < 8; ++t) {
      short8 bh = *(const short8*)(pk + t * 1024);
      short8 bl = *(const short8*)(pk + t * 1024 + 512);
      acc[0][t] = __builtin_amdgcn_mfma_f32_16x16x32_bf16(ah0, bh, acc[0][t], 0, 0, 0);
      acc[0][t] = __builtin_amdgcn_mfma_f32_16x16x32_bf16(ah0, bl, acc[0][t], 0, 0, 0);
      acc[0][t] = __builtin_amdgcn_mfma_f32_16x16x32_bf16(al0, bh, acc[0][t], 0, 0, 0);
      acc[1][t] = __builtin_amdgcn_mfma_f32_16x16x32_bf16(ah1, bh, acc[1][t], 0, 0, 0);
      acc[1][t] = __builtin_amdgcn_mfma_f32_16x16x32_bf16(ah1, bl, acc[1][t], 0, 0, 0);
      acc[1][t] = __builtin_amdgcn_mfma_f32_16x16x32_bf16(al1, bh, acc[1][t], 0, 0, 0);
    }
  }

  // Epilogue (validated R2): D row = mt*16 + quad*4 + r, col = c.
  // tile t<4: re of amp i = w*64 + t*16 + c; tile t+4: im of same i.
#pragma unroll
  for (int mt = 0; mt < 2; ++mt) {
#pragma unroll
    for (int r = 0; r < 4; ++r) {
      float p0 = acc[mt][0][r] * acc[mt][0][r] + acc[mt][4][r] * acc[mt][4][r];
      float p1 = acc[mt][1][r] * acc[mt][1][r] + acc[mt][5][r] * acc[mt][5][r];
      float p2 = acc[mt][2][r] * acc[mt][2][r] + acc[mt][6][r] * acc[mt][6][r];
      float p3 = acc[mt][3][r] * acc[mt][3][r] + acc[mt][7][r] * acc[mt][7][r];
      float s01 = p0 + p1, s23 = p2 + p3;
      float av = s01 + s23;               // -> j=0,1,4..7
      float bv = s01 - s23;               // sign bit5 (t>>1) -> j=2
      float cv = (p0 - p1) + (p2 - p3);   // sign bit4 (t&1) -> j=3
#pragma unroll
      for (int st = 0; st < 4; ++st) {    // signed WHT over c bits
        int msk = 1 << st;
        float ta = __shfl_xor(av, msk, 64);
        av = ((c >> st) & 1) ? (ta - av) : (av + ta);
        bv += __shfl_xor(bv, msk, 64);
        cv += __shfl_xor(cv, msk, 64);
      }
      int m = h * 32 + mt * 16 + quad * 4 + r;
      if (c == 0) {
        part[w][m][0] = ((w >> 1) & 1) ? -av : av;  // j=0: bit7(i)
        part[w][m][1] = (w & 1) ? -av : av;         // j=1: bit6(i)
        part[w][m][2] = bv;
        part[w][m][3] = cv;
      } else if (c == 8) part[w][m][4] = av;   // j=4: bit3
      else if (c == 4) part[w][m][5] = av;     // j=5: bit2
      else if (c == 2) part[w][m][6] = av;     // j=6: bit1
      else if (c == 1) part[w][m][7] = av;     // j=7: bit0
    }
  }
  __syncthreads();

  {
    int m = tid >> 3, jj = tid & 7;
    ys[m][jj] = part[0][m][jj] + part[1][m][jj] + part[2][m][jj] + part[3][m][jj];
  }
  __syncthreads();

  if (tid < 64) {
    float n = 0.f;
#pragma unroll
    for (int jj = 0; jj < 8; ++jj) { float v = ys[tid][jj]; n = fmaf(v, v, n); }
    n = sqrtf(n);
    invn[tid] = (n == 0.f) ? 0.f : 1.f / n;
  }
  __syncthreads();

  // write out: 64 rows x 64 float4 = 4096 float4, 8 per thread
  float4* o4 = (float4*)(out + (size_t)row0 * 256);
#pragma unroll
  for (int i = 0; i < 8; ++i) {
    int e = i * 512 + tid;
    int row = e >> 6;
    int c4 = (e & 63) * 4;
    float4 v = make_float4(0.f, 0.f, 0.f, 0.f);
    if (c4 < 8) {
      float iv = invn[row];
      float t0 = ys[row][c4 + 0] * iv;
      float t1 = ys[row][c4 + 1] * iv;
      float t2 = ys[row][c4 + 2] * iv;
      float t3 = ys[row][c4 + 3] * iv;
      v = make_float4(t0 * t0, t1 * t1, t2 * t2, t3 * t3);
    }
    o4[e] = v;
  }
}

extern "C" void kernel_launch(void* const* d_in, const int* in_sizes, int n_in,
                              void* d_out, int out_size, void* d_ws, size_t ws_size,
                              hipStream_t stream) {
  const float* x = (const float*)d_in[0];
  const float* th1 = (const float*)d_in[1];
  const float* th2 = (const float*)d_in[2];
  const float* th3 = (const float*)d_in[3];
  float* out = (float*)d_out;
  unsigned short* Vsw = (unsigned short*)d_ws;  // 512 KB swizzled V (hi+lo)

  build_u<<<64, 256, 0, stream>>>(th1, th2, th3, Vsw);
  pqc_main<<<512, 512, 0, stream>>>(x, Vsw, out);
}

// Round 4
// 128.774 us; speedup vs baseline: 1.8766x; 1.0084x over previous
//
#include <hip/hip_runtime.h>
#include <math.h>

// PQC autoencoder. out = g(U x), U = fixed 256x256 unitary from thetas
// (input normalization cancels: y/||y|| scale-invariant in x).
// Kernel A (build_u, ~2-4 us): fused-gate statevector sim -> V = [Re U; Im U]
//   split-bf16 hi/lo in MFMA-B-fragment stream order (validated R2/R3).
// Kernel B (pqc_main): split-bf16 MFMA GEMM (32768 x 512 x 256, 3 terms),
//   64 rows/wave (12 MFMA per B-load-pair), explicit B t+1 / A k+1 register
//   prefetch, launch_bounds(256,2) for scheduler headroom. Fused
//   |psi|^2 -> Walsh -> normalize epilogue (validated R2/R3).

#define DEV __device__ __forceinline__

typedef __attribute__((ext_vector_type(8))) short short8;   // 8 bf16
typedef __attribute__((ext_vector_type(4))) float f32x4;

DEV float2 cmul(float2 a, float2 b) {
  return make_float2(a.x * b.x - a.y * b.y, a.x * b.y + a.y * b.x);
}
DEV float2 cadd(float2 a, float2 b) { return make_float2(a.x + b.x, a.y + b.y); }

DEV unsigned short bf_rne(float v) {
  unsigned u = __float_as_uint(v);
  return (unsigned short)((u + 0x7FFFu + ((u >> 16) & 1u)) >> 16);
}

// ---------------------------------------------------------------------------
// Kernel A
// ---------------------------------------------------------------------------

struct Psi4 { float re[4]; float im[4]; };
// amplitude a = (r<<6)|lane; bit q of a: q<6 -> lane bit q; q==6 -> r&1; q==7 -> r>>1

template <int Q>
DEV void pair_gate(Psi4& s, const float2* __restrict__ Mlo,
                   const float2* __restrict__ Mhi, int lane) {
  const int b0 = (lane >> Q) & 1, b1 = (lane >> (Q + 1)) & 1;
  float2 lo_d = Mlo[b0 * 2 + b0];
  float2 lo_o = Mlo[b0 * 2 + (b0 ^ 1)];
  float2 hi_d = Mhi[b1 * 2 + b1];
  float2 hi_o = Mhi[b1 * 2 + (b1 ^ 1)];
  float2 c00 = cmul(hi_d, lo_d);
  float2 c01 = cmul(hi_d, lo_o);
  float2 c10 = cmul(hi_o, lo_d);
  float2 c11 = cmul(hi_o, lo_o);
  const int m0 = 1 << Q, m1 = 2 << Q;
#pragma unroll
  for (int r = 0; r < 4; ++r) {
    float ar = s.re[r], ai = s.im[r];
    float p0r = __shfl_xor(ar, m0, 64), p0i = __shfl_xor(ai, m0, 64);
    float p1r = __shfl_xor(ar, m1, 64), p1i = __shfl_xor(ai, m1, 64);
    float p2r = __shfl_xor(ar, m0 | m1, 64), p2i = __shfl_xor(ai, m0 | m1, 64);
    float nr = c00.x * ar - c00.y * ai + c01.x * p0r - c01.y * p0i
             + c10.x * p1r - c10.y * p1i + c11.x * p2r - c11.y * p2i;
    float ni = c00.x * ai + c00.y * ar + c01.x * p0i + c01.y * p0r
             + c10.x * p1i + c10.y * p1r + c11.x * p2i + c11.y * p2r;
    s.re[r] = nr; s.im[r] = ni;
  }
}

DEV void regpair_gate(Psi4& s, const float2* __restrict__ Mlo,
                      const float2* __restrict__ Mhi) {
  float nr[4], ni[4];
#pragma unroll
  for (int r = 0; r < 4; ++r) {
    const int b0 = r & 1, b1 = (r >> 1) & 1;
    float2 c00 = cmul(Mhi[b1 * 2 + b1], Mlo[b0 * 2 + b0]);
    float2 c01 = cmul(Mhi[b1 * 2 + b1], Mlo[b0 * 2 + (b0 ^ 1)]);
    float2 c10 = cmul(Mhi[b1 * 2 + (b1 ^ 1)], Mlo[b0 * 2 + b0]);
    float2 c11 = cmul(Mhi[b1 * 2 + (b1 ^ 1)], Mlo[b0 * 2 + (b0 ^ 1)]);
    nr[r] = c00.x * s.re[r] - c00.y * s.im[r]
          + c01.x * s.re[r ^ 1] - c01.y * s.im[r ^ 1]
          + c10.x * s.re[r ^ 2] - c10.y * s.im[r ^ 2]
          + c11.x * s.re[r ^ 3] - c11.y * s.im[r ^ 3];
    ni[r] = c00.x * s.im[r] + c00.y * s.re[r]
          + c01.x * s.im[r ^ 1] + c01.y * s.re[r ^ 1]
          + c10.x * s.im[r ^ 2] + c10.y * s.re[r ^ 2]
          + c11.x * s.im[r ^ 3] + c11.y * s.re[r ^ 3];
  }
#pragma unroll
  for (int r = 0; r < 4; ++r) { s.re[r] = nr[r]; s.im[r] = ni[r]; }
}

DEV void reg0_gate(Psi4& s, const float2* __restrict__ M) {
  float nr[4], ni[4];
#pragma unroll
  for (int r = 0; r < 4; ++r) {
    const int b = r & 1;
    float2 d = M[b * 2 + b], o = M[b * 2 + (b ^ 1)];
    nr[r] = d.x * s.re[r] - d.y * s.im[r] + o.x * s.re[r ^ 1] - o.y * s.im[r ^ 1];
    ni[r] = d.x * s.im[r] + d.y * s.re[r] + o.x * s.im[r ^ 1] + o.y * s.re[r ^ 1];
  }
#pragma unroll
  for (int r = 0; r < 4; ++r) { s.re[r] = nr[r]; s.im[r] = ni[r]; }
}

template <bool FULL8>
DEV void perm_cx(Psi4& s, int lane) {
  const int slane = (lane ^ (lane << 1)) & 63;
  const bool L5 = ((lane >> 5) & 1) != 0;
  float nr[4], ni[4];
#pragma unroll
  for (int r = 0; r < 4; ++r) {
    const int r0 = r & 1, r1 = (r >> 1) & 1;
    const int hiBit = FULL8 ? (r1 ^ r0) : r1;
    const int sA = (hiBit << 1) | r0;
    const int sB = sA ^ 1;
    float aRe = __shfl(s.re[sA], slane, 64);
    float aIm = __shfl(s.im[sA], slane, 64);
    float bRe = __shfl(s.re[sB], slane, 64);
    float bIm = __shfl(s.im[sB], slane, 64);
    nr[r] = L5 ? bRe : aRe;
    ni[r] = L5 ? bIm : aIm;
  }
#pragma unroll
  for (int r = 0; r < 4; ++r) { s.re[r] = nr[r]; s.im[r] = ni[r]; }
}

template <int NQ>
DEV void ansatz_f(Psi4& s, const float2* __restrict__ Mg, int lane) {
#pragma unroll
  for (int d = 0; d < 2; ++d) {
    const float2* Md = Mg + d * NQ * 4;
    pair_gate<0>(s, Md + 0, Md + 4, lane);
    pair_gate<2>(s, Md + 8, Md + 12, lane);
    pair_gate<4>(s, Md + 16, Md + 20, lane);
    if (NQ == 8) regpair_gate(s, Md + 24, Md + 28);
    else reg0_gate(s, Md + 24);
    perm_cx<NQ == 8>(s, lane);
  }
}

// Vsw layout (validated): idx = k*32768 + g*1024 + hl*512 + L*8 + jj
DEV void store_v(unsigned short* __restrict__ Vsw, int n, int kk, float v) {
  int k = kk >> 5, rem = kk & 31, quad = rem >> 3, jj = rem & 7;
  int nn = n & 255;
  int w = (nn >> 6) & 3, t = (nn >> 4) & 3, cl = nn & 15;
  int g = w * 8 + ((n >= 256) ? 4 + t : t);
  int L = quad * 16 + cl;
  unsigned short hi = bf_rne(v);
  float hif = __uint_as_float(((unsigned)hi) << 16);
  unsigned short lo = bf_rne(v - hif);
  size_t base = (size_t)k * 32768 + (size_t)g * 1024 + (size_t)L * 8 + jj;
  Vsw[base] = hi;
  Vsw[base + 512] = lo;
}

__global__ void build_u(const float* __restrict__ th1, const float* __restrict__ th2,
                        const float* __restrict__ th3, unsigned short* __restrict__ Vsw) {
  __shared__ float2 Mg[46 * 4];
  const int tid = threadIdx.x;
  if (tid < 46) {
    float thx, thy, thz;
    if (tid < 16)      { thx = th1[tid * 3]; thy = th1[tid * 3 + 1]; thz = th1[tid * 3 + 2]; }
    else if (tid < 30) { int u = (tid - 16) * 3; thx = th2[u]; thy = th2[u + 1]; thz = th2[u + 2]; }
    else               { int u = (tid - 30) * 3; thx = th3[u]; thy = th3[u + 1]; thz = th3[u + 2]; }
    float sx, cx_, sy, cy_, sz, cz_;
    sincosf(0.5f * thx, &sx, &cx_);
    sincosf(0.5f * thy, &sy, &cy_);
    sincosf(0.5f * thz, &sz, &cz_);
    float2 rx[4] = {{cx_, 0}, {0, -sx}, {0, -sx}, {cx_, 0}};
    float2 ry[4] = {{cy_, 0}, {-sy, 0}, {sy, 0}, {cy_, 0}};
    float2 A0 = cadd(cmul(ry[0], rx[0]), cmul(ry[1], rx[2]));
    float2 A1 = cadd(cmul(ry[0], rx[1]), cmul(ry[1], rx[3]));
    float2 A2 = cadd(cmul(ry[2], rx[0]), cmul(ry[3], rx[2]));
    float2 A3 = cadd(cmul(ry[2], rx[1]), cmul(ry[3], rx[3]));
    float2 ezm = make_float2(cz_, -sz), ezp = make_float2(cz_, sz);
    Mg[tid * 4 + 0] = cmul(ezm, A0);
    Mg[tid * 4 + 1] = cmul(ezm, A1);
    Mg[tid * 4 + 2] = cmul(ezp, A2);
    Mg[tid * 4 + 3] = cmul(ezp, A3);
  }
  __syncthreads();

  const int lane = tid & 63;
  const int j = blockIdx.x * 4 + (tid >> 6);
  Psi4 s;
#pragma unroll
  for (int r = 0; r < 4; ++r) {
    int a = (r << 6) | lane;
    s.re[r] = (a == j) ? 1.f : 0.f;
    s.im[r] = 0.f;
  }
  ansatz_f<8>(s, Mg, lane);
  ansatz_f<7>(s, Mg + 16 * 4, lane);
  ansatz_f<8>(s, Mg + 30 * 4, lane);
#pragma unroll
  for (int r = 0; r < 4; ++r) {
    int a = (r << 6) | lane;
    store_v(Vsw, a, j, s.re[r]);
    store_v(Vsw, a + 256, j, s.im[r]);
  }
}

// ---------------------------------------------------------------------------
// Kernel B: 256 threads (4 waves), 64 rows/block. Each wave owns ONE B-slice
// (w) for ALL 64 rows (mt=0..3) -> 12 MFMA per B-load-pair, B L2 traffic
// 1 MB/CU. Explicit register prefetch: B one t-step ahead, A one k-step ahead.
// ---------------------------------------------------------------------------

DEV void split8(float4 f0, float4 f1, short8& h, short8& l) {
#define SPLIT1(i, v)                                            \
  {                                                             \
    unsigned u = __float_as_uint(v);                            \
    h[i] = (short)(u >> 16); /* trunc hi */                     \
    float hf = __uint_as_float(u & 0xFFFF0000u);                \
    l[i] = (short)(__float_as_uint((v) - hf) >> 16);            \
  }
  SPLIT1(0, f0.x) SPLIT1(1, f0.y) SPLIT1(2, f0.z) SPLIT1(3, f0.w)
  SPLIT1(4, f1.x) SPLIT1(5, f1.y) SPLIT1(6, f1.z) SPLIT1(7, f1.w)
#undef SPLIT1
}

__global__ __launch_bounds__(256, 2) void pqc_main(const float* __restrict__ x,
                                                   const unsigned short* __restrict__ Vsw,
                                                   float* __restrict__ out) {
  const int tid = threadIdx.x;
  const int w = tid >> 6;       // B-slice (amp range w*64..w*64+64, re+im)
  const int L = tid & 63;
  const int quad = L >> 4;
  const int c = L & 15;
  const int row0 = blockIdx.x * 64;

  __shared__ float part[4][64][8];
  __shared__ float ys[64][8];
  __shared__ float invn[64];

  f32x4 acc[4][8];
#pragma unroll
  for (int mt = 0; mt < 4; ++mt)
#pragma unroll
    for (int t = 0; t < 8; ++t) acc[mt][t] = (f32x4){0.f, 0.f, 0.f, 0.f};

  // A: lane holds A[m = mt*16 + c][k*32 + quad*8 + (0..7)]
  const float* xbase = x + (size_t)(row0 + c) * 256 + quad * 8;
  const unsigned short* pb = Vsw + (size_t)w * 8192 + (size_t)L * 8;

  // preload A(k=0) raw and B(k=0,t=0)
  float4 araw[4][2];
#pragma unroll
  for (int mt = 0; mt < 4; ++mt) {
    araw[mt][0] = *(const float4*)(xbase + mt * 4096);
    araw[mt][1] = *(const float4*)(xbase + mt * 4096 + 4);
  }
  short8 bh = *(const short8*)(pb);
  short8 bl = *(const short8*)(pb + 512);

#pragma unroll
  for (int k = 0; k < 8; ++k) {
    // split current A, then immediately prefetch next k's raw A
    short8 ah[4], al[4];
#pragma unroll
    for (int mt = 0; mt < 4; ++mt) split8(araw[mt][0], araw[mt][1], ah[mt], al[mt]);
    if (k < 7) {
#pragma unroll
      for (int mt = 0; mt < 4; ++mt) {
        araw[mt][0] = *(const float4*)(xbase + mt * 4096 + (k + 1) * 32);
        araw[mt][1] = *(const float4*)(xbase + mt * 4096 + (k + 1) * 32 + 4);
      }
    }
    const unsigned short* pk = pb + (size_t)k * 32768;
#pragma unroll
    for (int t = 0; t < 8; ++t) {
      short8 nbh, nbl;
      if (t < 7) {
        nbh = *(const short8*)(pk + (t + 1) * 1024);
        nbl = *(const short8*)(pk + (t + 1) * 1024 + 512);
      } else if (k < 7) {
        nbh = *(const short8*)(pk + 32768);
        nbl = *(const short8*)(pk + 32768 + 512);
      }
#pragma unroll
      for (int mt = 0; mt < 4; ++mt) {
        acc[mt][t] = __builtin_amdgcn_mfma_f32_16x16x32_bf16(ah[mt], bh, acc[mt][t], 0, 0, 0);
        acc[mt][t] = __builtin_amdgcn_mfma_f32_16x16x32_bf16(ah[mt], bl, acc[mt][t], 0, 0, 0);
        acc[mt][t] = __builtin_amdgcn_mfma_f32_16x16x32_bf16(al[mt], bh, acc[mt][t], 0, 0, 0);
      }
      if (t < 7 || k < 7) { bh = nbh; bl = nbl; }
    }
  }

  // Epilogue (validated): D row = mt*16 + quad*4 + r, col = c.
  // tile t<4: re of amp i = w*64 + t*16 + c; tile t+4: im of same i.
#pragma unroll
  for (int mt = 0; mt < 4; ++mt) {
#pragma unroll
    for (int r = 0; r < 4; ++r) {
      float p0 = acc[mt][0][r] * acc[mt][0][r] + acc[mt][4][r] * acc[mt][4][r];
      float p1 = acc[mt][1][r] * acc[mt][1][r] + acc[mt][5][r] * acc[mt][5][r];
      float p2 = acc[mt][2][r] * acc[mt][2][r] + acc[mt][6][r] * acc[mt][6][r];
      float p3 = acc[mt][3][r] * acc[mt][3][r] + acc[mt][7][r] * acc[mt][7][r];
      float s01 = p0 + p1, s23 = p2 + p3;
      float av = s01 + s23;               // -> j=0,1,4..7
      float bv = s01 - s23;               // sign bit5 (t>>1) -> j=2
      float cv = (p0 - p1) + (p2 - p3);   // sign bit4 (t&1) -> j=3
#pragma unroll
      for (int st = 0; st < 4; ++st) {    // signed WHT over c bits
        int msk = 1 << st;
        float ta = __shfl_xor(av, msk, 64);
        av = ((c >> st) & 1) ? (ta - av) : (av + ta);
        bv += __shfl_xor(bv, msk, 64);
        cv += __shfl_xor(cv, msk, 64);
      }
      int m = mt * 16 + quad * 4 + r;
      if (c == 0) {
        part[w][m][0] = ((w >> 1) & 1) ? -av : av;  // j=0: bit7(i)
        part[w][m][1] = (w & 1) ? -av : av;         // j=1: bit6(i)
        part[w][m][2] = bv;
        part[w][m][3] = cv;
      } else if (c == 8) part[w][m][4] = av;   // j=4: bit3
      else if (c == 4) part[w][m][5] = av;     // j=5: bit2
      else if (c == 2) part[w][m][6] = av;     // j=6: bit1
      else if (c == 1) part[w][m][7] = av;     // j=7: bit0
    }
  }
  __syncthreads();

#pragma unroll
  for (int s = 0; s < 2; ++s) {
    int e = s * 256 + tid;
    int m = e >> 3, jj = e & 7;
    ys[m][jj] = part[0][m][jj] + part[1][m][jj] + part[2][m][jj] + part[3][m][jj];
  }
  __syncthreads();

  if (tid < 64) {
    float n = 0.f;
#pragma unroll
    for (int jj = 0; jj < 8; ++jj) { float v = ys[tid][jj]; n = fmaf(v, v, n); }
    n = sqrtf(n);
    invn[tid] = (n == 0.f) ? 0.f : 1.f / n;
  }
  __syncthreads();

  // write out: 64 rows x 64 float4 = 4096 float4, 16 per thread
  float4* o4 = (float4*)(out + (size_t)row0 * 256);
#pragma unroll
  for (int i = 0; i < 16; ++i) {
    int e = i * 256 + tid;
    int row = e >> 6;
    int c4 = (e & 63) * 4;
    float4 v = make_float4(0.f, 0.f, 0.f, 0.f);
    if (c4 < 8) {
      float iv = invn[row];
      float t0 = ys[row][c4 + 0] * iv;
      float t1 = ys[row][c4 + 1] * iv;
      float t2 = ys[row][c4 + 2] * iv;
      float t3 = ys[row][c4 + 3] * iv;
      v = make_float4(t0 * t0, t1 * t1, t2 * t2, t3 * t3);
    }
    o4[e] = v;
  }
}

extern "C" void kernel_launch(void* const* d_in, const int* in_sizes, int n_in,
                              void* d_out, int out_size, void* d_ws, size_t ws_size,
                              hipStream_t stream) {
  const float* x = (const float*)d_in[0];
  const float* th1 = (const float*)d_in[1];
  const float* th2 = (const float*)d_in[2];
  const float* th3 = (const float*)d_in[3];
  float* out = (float*)d_out;
  unsigned short* Vsw = (unsigned short*)d_ws;  // 512 KB swizzled V (hi+lo)

  build_u<<<64, 256, 0, stream>>>(th1, th2, th3, Vsw);
  pqc_main<<<512, 256, 0, stream>>>(x, Vsw, out);
}

// Round 5
// 126.929 us; speedup vs baseline: 1.9038x; 1.0145x over previous
//
#include <hip/hip_runtime.h>
#include <math.h>

// PQC autoencoder. out = g(U x), U = fixed 256x256 unitary from thetas
// (input normalization cancels: y/||y|| scale-invariant in x).
// Kernel A (build_u, ~2-4 us): fused-gate statevector sim -> V = [Re U; Im U]
//   split-bf16 hi/lo in MFMA-B-fragment stream order (validated R2-R4).
// Kernel B (pqc_main): split-bf16 MFMA GEMM (32768 x 512 x 256, 3 terms).
//   R5: 8 waves/block, 64 rows; wave = (w-slice, re|im half), n=64/wave ->
//   acc=64 AGPR; A split ONCE per block into LDS in A-frag stream order;
//   launch_bounds(512,4) -> 4 waves/SIMD. Fused Walsh epilogue (8 partials,
//   LDS overlaid on dead A-tile).

#define DEV __device__ __forceinline__

typedef __attribute__((ext_vector_type(8))) short short8;   // 8 bf16
typedef __attribute__((ext_vector_type(4))) float f32x4;

DEV float2 cmul(float2 a, float2 b) {
  return make_float2(a.x * b.x - a.y * b.y, a.x * b.y + a.y * b.x);
}
DEV float2 cadd(float2 a, float2 b) { return make_float2(a.x + b.x, a.y + b.y); }

DEV unsigned short bf_rne(float v) {
  unsigned u = __float_as_uint(v);
  return (unsigned short)((u + 0x7FFFu + ((u >> 16) & 1u)) >> 16);
}

// ---------------------------------------------------------------------------
// Kernel A (unchanged, validated)
// ---------------------------------------------------------------------------

struct Psi4 { float re[4]; float im[4]; };
// amplitude a = (r<<6)|lane; bit q of a: q<6 -> lane bit q; q==6 -> r&1; q==7 -> r>>1

template <int Q>
DEV void pair_gate(Psi4& s, const float2* __restrict__ Mlo,
                   const float2* __restrict__ Mhi, int lane) {
  const int b0 = (lane >> Q) & 1, b1 = (lane >> (Q + 1)) & 1;
  float2 lo_d = Mlo[b0 * 2 + b0];
  float2 lo_o = Mlo[b0 * 2 + (b0 ^ 1)];
  float2 hi_d = Mhi[b1 * 2 + b1];
  float2 hi_o = Mhi[b1 * 2 + (b1 ^ 1)];
  float2 c00 = cmul(hi_d, lo_d);
  float2 c01 = cmul(hi_d, lo_o);
  float2 c10 = cmul(hi_o, lo_d);
  float2 c11 = cmul(hi_o, lo_o);
  const int m0 = 1 << Q, m1 = 2 << Q;
#pragma unroll
  for (int r = 0; r < 4; ++r) {
    float ar = s.re[r], ai = s.im[r];
    float p0r = __shfl_xor(ar, m0, 64), p0i = __shfl_xor(ai, m0, 64);
    float p1r = __shfl_xor(ar, m1, 64), p1i = __shfl_xor(ai, m1, 64);
    float p2r = __shfl_xor(ar, m0 | m1, 64), p2i = __shfl_xor(ai, m0 | m1, 64);
    float nr = c00.x * ar - c00.y * ai + c01.x * p0r - c01.y * p0i
             + c10.x * p1r - c10.y * p1i + c11.x * p2r - c11.y * p2i;
    float ni = c00.x * ai + c00.y * ar + c01.x * p0i + c01.y * p0r
             + c10.x * p1i + c10.y * p1r + c11.x * p2i + c11.y * p2r;
    s.re[r] = nr; s.im[r] = ni;
  }
}

DEV void regpair_gate(Psi4& s, const float2* __restrict__ Mlo,
                      const float2* __restrict__ Mhi) {
  float nr[4], ni[4];
#pragma unroll
  for (int r = 0; r < 4; ++r) {
    const int b0 = r & 1, b1 = (r >> 1) & 1;
    float2 c00 = cmul(Mhi[b1 * 2 + b1], Mlo[b0 * 2 + b0]);
    float2 c01 = cmul(Mhi[b1 * 2 + b1], Mlo[b0 * 2 + (b0 ^ 1)]);
    float2 c10 = cmul(Mhi[b1 * 2 + (b1 ^ 1)], Mlo[b0 * 2 + b0]);
    float2 c11 = cmul(Mhi[b1 * 2 + (b1 ^ 1)], Mlo[b0 * 2 + (b0 ^ 1)]);
    nr[r] = c00.x * s.re[r] - c00.y * s.im[r]
          + c01.x * s.re[r ^ 1] - c01.y * s.im[r ^ 1]
          + c10.x * s.re[r ^ 2] - c10.y * s.im[r ^ 2]
          + c11.x * s.re[r ^ 3] - c11.y * s.im[r ^ 3];
    ni[r] = c00.x * s.im[r] + c00.y * s.re[r]
          + c01.x * s.im[r ^ 1] + c01.y * s.re[r ^ 1]
          + c10.x * s.im[r ^ 2] + c10.y * s.re[r ^ 2]
          + c11.x * s.im[r ^ 3] + c11.y * s.re[r ^ 3];
  }
#pragma unroll
  for (int r = 0; r < 4; ++r) { s.re[r] = nr[r]; s.im[r] = ni[r]; }
}

DEV void reg0_gate(Psi4& s, const float2* __restrict__ M) {
  float nr[4], ni[4];
#pragma unroll
  for (int r = 0; r < 4; ++r) {
    const int b = r & 1;
    float2 d = M[b * 2 + b], o = M[b * 2 + (b ^ 1)];
    nr[r] = d.x * s.re[r] - d.y * s.im[r] + o.x * s.re[r ^ 1] - o.y * s.im[r ^ 1];
    ni[r] = d.x * s.im[r] + d.y * s.re[r] + o.x * s.im[r ^ 1] + o.y * s.re[r ^ 1];
  }
#pragma unroll
  for (int r = 0; r < 4; ++r) { s.re[r] = nr[r]; s.im[r] = ni[r]; }
}

template <bool FULL8>
DEV void perm_cx(Psi4& s, int lane) {
  const int slane = (lane ^ (lane << 1)) & 63;
  const bool L5 = ((lane >> 5) & 1) != 0;
  float nr[4], ni[4];
#pragma unroll
  for (int r = 0; r < 4; ++r) {
    const int r0 = r & 1, r1 = (r >> 1) & 1;
    const int hiBit = FULL8 ? (r1 ^ r0) : r1;
    const int sA = (hiBit << 1) | r0;
    const int sB = sA ^ 1;
    float aRe = __shfl(s.re[sA], slane, 64);
    float aIm = __shfl(s.im[sA], slane, 64);
    float bRe = __shfl(s.re[sB], slane, 64);
    float bIm = __shfl(s.im[sB], slane, 64);
    nr[r] = L5 ? bRe : aRe;
    ni[r] = L5 ? bIm : aIm;
  }
#pragma unroll
  for (int r = 0; r < 4; ++r) { s.re[r] = nr[r]; s.im[r] = ni[r]; }
}

template <int NQ>
DEV void ansatz_f(Psi4& s, const float2* __restrict__ Mg, int lane) {
#pragma unroll
  for (int d = 0; d < 2; ++d) {
    const float2* Md = Mg + d * NQ * 4;
    pair_gate<0>(s, Md + 0, Md + 4, lane);
    pair_gate<2>(s, Md + 8, Md + 12, lane);
    pair_gate<4>(s, Md + 16, Md + 20, lane);
    if (NQ == 8) regpair_gate(s, Md + 24, Md + 28);
    else reg0_gate(s, Md + 24);
    perm_cx<NQ == 8>(s, lane);
  }
}

// Vsw layout (validated): idx = k*32768 + g*1024 + hl*512 + L*8 + jj
// g = w*8 + t, t in [0,4) re tiles / [4,8) im tiles; L = quad*16 + (n&15)
DEV void store_v(unsigned short* __restrict__ Vsw, int n, int kk, float v) {
  int k = kk >> 5, rem = kk & 31, quad = rem >> 3, jj = rem & 7;
  int nn = n & 255;
  int w = (nn >> 6) & 3, t = (nn >> 4) & 3, cl = nn & 15;
  int g = w * 8 + ((n >= 256) ? 4 + t : t);
  int L = quad * 16 + cl;
  unsigned short hi = bf_rne(v);
  float hif = __uint_as_float(((unsigned)hi) << 16);
  unsigned short lo = bf_rne(v - hif);
  size_t base = (size_t)k * 32768 + (size_t)g * 1024 + (size_t)L * 8 + jj;
  Vsw[base] = hi;
  Vsw[base + 512] = lo;
}

__global__ void build_u(const float* __restrict__ th1, const float* __restrict__ th2,
                        const float* __restrict__ th3, unsigned short* __restrict__ Vsw) {
  __shared__ float2 Mg[46 * 4];
  const int tid = threadIdx.x;
  if (tid < 46) {
    float thx, thy, thz;
    if (tid < 16)      { thx = th1[tid * 3]; thy = th1[tid * 3 + 1]; thz = th1[tid * 3 + 2]; }
    else if (tid < 30) { int u = (tid - 16) * 3; thx = th2[u]; thy = th2[u + 1]; thz = th2[u + 2]; }
    else               { int u = (tid - 30) * 3; thx = th3[u]; thy = th3[u + 1]; thz = th3[u + 2]; }
    float sx, cx_, sy, cy_, sz, cz_;
    sincosf(0.5f * thx, &sx, &cx_);
    sincosf(0.5f * thy, &sy, &cy_);
    sincosf(0.5f * thz, &sz, &cz_);
    float2 rx[4] = {{cx_, 0}, {0, -sx}, {0, -sx}, {cx_, 0}};
    float2 ry[4] = {{cy_, 0}, {-sy, 0}, {sy, 0}, {cy_, 0}};
    float2 A0 = cadd(cmul(ry[0], rx[0]), cmul(ry[1], rx[2]));
    float2 A1 = cadd(cmul(ry[0], rx[1]), cmul(ry[1], rx[3]));
    float2 A2 = cadd(cmul(ry[2], rx[0]), cmul(ry[3], rx[2]));
    float2 A3 = cadd(cmul(ry[2], rx[1]), cmul(ry[3], rx[3]));
    float2 ezm = make_float2(cz_, -sz), ezp = make_float2(cz_, sz);
    Mg[tid * 4 + 0] = cmul(ezm, A0);
    Mg[tid * 4 + 1] = cmul(ezm, A1);
    Mg[tid * 4 + 2] = cmul(ezp, A2);
    Mg[tid * 4 + 3] = cmul(ezp, A3);
  }
  __syncthreads();

  const int lane = tid & 63;
  const int j = blockIdx.x * 4 + (tid >> 6);
  Psi4 s;
#pragma unroll
  for (int r = 0; r < 4; ++r) {
    int a = (r << 6) | lane;
    s.re[r] = (a == j) ? 1.f : 0.f;
    s.im[r] = 0.f;
  }
  ansatz_f<8>(s, Mg, lane);
  ansatz_f<7>(s, Mg + 16 * 4, lane);
  ansatz_f<8>(s, Mg + 30 * 4, lane);
#pragma unroll
  for (int r = 0; r < 4; ++r) {
    int a = (r << 6) | lane;
    store_v(Vsw, a, j, s.re[r]);
    store_v(Vsw, a + 256, j, s.im[r]);
  }
}

// ---------------------------------------------------------------------------
// Kernel B: 512 threads (8 waves), 64 rows/block. Wave ww: w = ww>>1 (amp
// slice), half = ww&1 (re tiles t=0..3 | im tiles t=4..7), n=64 cols/wave ->
// acc = 4mt x 4tt x f32x4 = 64 AGPR. A-tile split once into LDS in A-frag
// stream order (canonical conflict-free ds_read_b128).
// ---------------------------------------------------------------------------

__global__ __launch_bounds__(512, 4) void pqc_main(const float* __restrict__ x,
                                                   const unsigned short* __restrict__ Vsw,
                                                   float* __restrict__ out) {
  const int tid = threadIdx.x;
  const int ww = tid >> 6;
  const int w = ww >> 1;        // amp slice: i in [w*64, w*64+64)
  const int half = ww & 1;      // 0 = re tiles, 1 = im tiles
  const int L = tid & 63;
  const int quad = L >> 4;
  const int c = L & 15;
  const int row0 = blockIdx.x * 64;

  // A2[hl][k][mt][L*8 + j] : lane L of frag (mt,k) reads 16B at L*16
  __shared__ unsigned short A2[2][8][4][512];   // 64 KB
  __shared__ float ys[64][8];
  __shared__ float invn[64];
  float* part = (float*)&A2[0][0][0][0];        // overlay after k-loop (16 KB)

  // ---- stage A: 64 rows x 256 cols -> split bf16 hi/lo in frag order
  {
    const float4* xsrc = (const float4*)(x + (size_t)row0 * 256);
#pragma unroll
    for (int i = 0; i < 8; ++i) {
      int e = i * 512 + tid;          // float4 index in tile
      int row = e >> 6;               // 64 float4 per row
      int kk = (e & 63) * 4;
      float4 f = xsrc[e];
      ushort4 h, l;
#define SPLIT1(fld, v)                                           \
      {                                                          \
        unsigned u = __float_as_uint(v);                         \
        h.fld = (unsigned short)(u >> 16); /* trunc hi */        \
        float hf = __uint_as_float(u & 0xFFFF0000u);             \
        l.fld = (unsigned short)(__float_as_uint((v) - hf) >> 16); \
      }
      SPLIT1(x, f.x) SPLIT1(y, f.y) SPLIT1(z, f.z) SPLIT1(w, f.w)
#undef SPLIT1
      int mt = row >> 4, cc = row & 15;
      int k = kk >> 5, q = (kk >> 3) & 3, j = kk & 7;
      int idx = (q * 16 + cc) * 8 + j;
      *(ushort4*)&A2[0][k][mt][idx] = h;
      *(ushort4*)&A2[1][k][mt][idx] = l;
    }
  }
  __syncthreads();

  // ---- MFMA K-loop
  f32x4 acc[4][4];
#pragma unroll
  for (int mt = 0; mt < 4; ++mt)
#pragma unroll
    for (int tt = 0; tt < 4; ++tt) acc[mt][tt] = (f32x4){0.f, 0.f, 0.f, 0.f};

  const unsigned short* pb = Vsw + (size_t)w * 8192 + (size_t)half * 4096 + (size_t)L * 8;

#pragma unroll
  for (int k = 0; k < 8; ++k) {
    short8 ah[4], al[4];
#pragma unroll
    for (int mt = 0; mt < 4; ++mt) {
      ah[mt] = *(const short8*)&A2[0][k][mt][L * 8];
      al[mt] = *(const short8*)&A2[1][k][mt][L * 8];
    }
    const unsigned short* pk = pb + (size_t)k * 32768;
#pragma unroll
    for (int tt = 0; tt < 4; ++tt) {
      short8 bh = *(const short8*)(pk + tt * 1024);
      short8 bl = *(const short8*)(pk + tt * 1024 + 512);
      // term-outer / mt-inner: 4 independent MFMAs between same-acc deps
#pragma unroll
      for (int mt = 0; mt < 4; ++mt)
        acc[mt][tt] = __builtin_amdgcn_mfma_f32_16x16x32_bf16(ah[mt], bh, acc[mt][tt], 0, 0, 0);
#pragma unroll
      for (int mt = 0; mt < 4; ++mt)
        acc[mt][tt] = __builtin_amdgcn_mfma_f32_16x16x32_bf16(ah[mt], bl, acc[mt][tt], 0, 0, 0);
#pragma unroll
      for (int mt = 0; mt < 4; ++mt)
        acc[mt][tt] = __builtin_amdgcn_mfma_f32_16x16x32_bf16(al[mt], bh, acc[mt][tt], 0, 0, 0);
    }
  }
  __syncthreads();   // A2 dead; part overlay becomes valid

  // ---- epilogue: partial probs (re^2 or im^2) -> signed Walsh, 8 partials.
  // D layout: row m = mt*16 + quad*4 + r, col = c; tile tt covers amps
  // i = w*64 + tt*16 + c (this wave contributes re^2 or im^2 of psi_i).
#pragma unroll
  for (int mt = 0; mt < 4; ++mt) {
#pragma unroll
    for (int r = 0; r < 4; ++r) {
      float p0 = acc[mt][0][r] * acc[mt][0][r];
      float p1 = acc[mt][1][r] * acc[mt][1][r];
      float p2 = acc[mt][2][r] * acc[mt][2][r];
      float p3 = acc[mt][3][r] * acc[mt][3][r];
      float s01 = p0 + p1, s23 = p2 + p3;
      float av = s01 + s23;               // -> j=0,1,4..7
      float bv = s01 - s23;               // sign bit5 (tt>>1) -> j=2
      float cv = (p0 - p1) + (p2 - p3);   // sign bit4 (tt&1) -> j=3
#pragma unroll
      for (int st = 0; st < 4; ++st) {    // signed WHT over c bits
        int msk = 1 << st;
        float ta = __shfl_xor(av, msk, 64);
        av = ((c >> st) & 1) ? (ta - av) : (av + ta);
        bv += __shfl_xor(bv, msk, 64);
        cv += __shfl_xor(cv, msk, 64);
      }
      int m = mt * 16 + quad * 4 + r;
      float* pm = part + (ww * 64 + m) * 8;
      if (c == 0) {
        pm[0] = ((w >> 1) & 1) ? -av : av;  // j=0: bit7(i)
        pm[1] = (w & 1) ? -av : av;         // j=1: bit6(i)
        pm[2] = bv;
        pm[3] = cv;
      } else if (c == 8) pm[4] = av;   // j=4: bit3
      else if (c == 4) pm[5] = av;     // j=5: bit2
      else if (c == 2) pm[6] = av;     // j=6: bit1
      else if (c == 1) pm[7] = av;     // j=7: bit0
    }
  }
  __syncthreads();

  {
    int m = tid >> 3, jj = tid & 7;
    float s = 0.f;
#pragma unroll
    for (int p = 0; p < 8; ++p) s += part[(p * 64 + m) * 8 + jj];
    ys[m][jj] = s;
  }
  __syncthreads();

  if (tid < 64) {
    float n = 0.f;
#pragma unroll
    for (int jj = 0; jj < 8; ++jj) { float v = ys[tid][jj]; n = fmaf(v, v, n); }
    n = sqrtf(n);
    invn[tid] = (n == 0.f) ? 0.f : 1.f / n;
  }
  __syncthreads();

  // ---- write out: 64 rows x 64 float4 = 4096 float4, 8 per thread
  float4* o4 = (float4*)(out + (size_t)row0 * 256);
#pragma unroll
  for (int i = 0; i < 8; ++i) {
    int e = i * 512 + tid;
    int row = e >> 6;
    int c4 = (e & 63) * 4;
    float4 v = make_float4(0.f, 0.f, 0.f, 0.f);
    if (c4 < 8) {
      float iv = invn[row];
      float t0 = ys[row][c4 + 0] * iv;
      float t1 = ys[row][c4 + 1] * iv;
      float t2 = ys[row][c4 + 2] * iv;
      float t3 = ys[row][c4 + 3] * iv;
      v = make_float4(t0 * t0, t1 * t1, t2 * t2, t3 * t3);
    }
    o4[e] = v;
  }
}

extern "C" void kernel_launch(void* const* d_in, const int* in_sizes, int n_in,
                              void* d_out, int out_size, void* d_ws, size_t ws_size,
                              hipStream_t stream) {
  const float* x = (const float*)d_in[0];
  const float* th1 = (const float*)d_in[1];
  const float* th2 = (const float*)d_in[2];
  const float* th3 = (const float*)d_in[3];
  float* out = (float*)d_out;
  unsigned short* Vsw = (unsigned short*)d_ws;  // 512 KB swizzled V (hi+lo)

  build_u<<<64, 256, 0, stream>>>(th1, th2, th3, Vsw);
  pqc_main<<<512, 512, 0, stream>>>(x, Vsw, out);
}

// Round 6
// 126.153 us; speedup vs baseline: 1.9155x; 1.0061x over previous
//
#include <hip/hip_runtime.h>
#include <math.h>

// PQC autoencoder. out = g(U x), U = fixed 256x256 unitary from thetas
// (input normalization cancels: y/||y|| scale-invariant in x).
// Kernel A (build_u, ~2 us): fused-gate statevector sim -> V = [Re U; Im U]
//   split-bf16 hi/lo in MFMA-B-fragment stream order (validated R2-R5).
// Kernel B (pqc_main): split-bf16 MFMA GEMM (32768 x 512 x 256, 3 terms).
//   R6: 256 blocks x 512 thr (1 block/CU), 128 rows/block, wave=(w,half),
//   mt=8 -> 24 MFMA per B-pair (full-latency ILP cover), B L2 traffic
//   256 KB/CU, launch_bounds(512,2) -> no spill (acc 128 AGPR + ~110 VGPR).
//   A split once into LDS (128 KB) in A-frag order; Walsh epilogue overlay.

#define DEV __device__ __forceinline__

typedef __attribute__((ext_vector_type(8))) short short8;   // 8 bf16
typedef __attribute__((ext_vector_type(4))) float f32x4;

DEV float2 cmul(float2 a, float2 b) {
  return make_float2(a.x * b.x - a.y * b.y, a.x * b.y + a.y * b.x);
}
DEV float2 cadd(float2 a, float2 b) { return make_float2(a.x + b.x, a.y + b.y); }

DEV unsigned short bf_rne(float v) {
  unsigned u = __float_as_uint(v);
  return (unsigned short)((u + 0x7FFFu + ((u >> 16) & 1u)) >> 16);
}

// ---------------------------------------------------------------------------
// Kernel A (unchanged, validated)
// ---------------------------------------------------------------------------

struct Psi4 { float re[4]; float im[4]; };
// amplitude a = (r<<6)|lane; bit q of a: q<6 -> lane bit q; q==6 -> r&1; q==7 -> r>>1

template <int Q>
DEV void pair_gate(Psi4& s, const float2* __restrict__ Mlo,
                   const float2* __restrict__ Mhi, int lane) {
  const int b0 = (lane >> Q) & 1, b1 = (lane >> (Q + 1)) & 1;
  float2 lo_d = Mlo[b0 * 2 + b0];
  float2 lo_o = Mlo[b0 * 2 + (b0 ^ 1)];
  float2 hi_d = Mhi[b1 * 2 + b1];
  float2 hi_o = Mhi[b1 * 2 + (b1 ^ 1)];
  float2 c00 = cmul(hi_d, lo_d);
  float2 c01 = cmul(hi_d, lo_o);
  float2 c10 = cmul(hi_o, lo_d);
  float2 c11 = cmul(hi_o, lo_o);
  const int m0 = 1 << Q, m1 = 2 << Q;
#pragma unroll
  for (int r = 0; r < 4; ++r) {
    float ar = s.re[r], ai = s.im[r];
    float p0r = __shfl_xor(ar, m0, 64), p0i = __shfl_xor(ai, m0, 64);
    float p1r = __shfl_xor(ar, m1, 64), p1i = __shfl_xor(ai, m1, 64);
    float p2r = __shfl_xor(ar, m0 | m1, 64), p2i = __shfl_xor(ai, m0 | m1, 64);
    float nr = c00.x * ar - c00.y * ai + c01.x * p0r - c01.y * p0i
             + c10.x * p1r - c10.y * p1i + c11.x * p2r - c11.y * p2i;
    float ni = c00.x * ai + c00.y * ar + c01.x * p0i + c01.y * p0r
             + c10.x * p1i + c10.y * p1r + c11.x * p2i + c11.y * p2r;
    s.re[r] = nr; s.im[r] = ni;
  }
}

DEV void regpair_gate(Psi4& s, const float2* __restrict__ Mlo,
                      const float2* __restrict__ Mhi) {
  float nr[4], ni[4];
#pragma unroll
  for (int r = 0; r < 4; ++r) {
    const int b0 = r & 1, b1 = (r >> 1) & 1;
    float2 c00 = cmul(Mhi[b1 * 2 + b1], Mlo[b0 * 2 + b0]);
    float2 c01 = cmul(Mhi[b1 * 2 + b1], Mlo[b0 * 2 + (b0 ^ 1)]);
    float2 c10 = cmul(Mhi[b1 * 2 + (b1 ^ 1)], Mlo[b0 * 2 + b0]);
    float2 c11 = cmul(Mhi[b1 * 2 + (b1 ^ 1)], Mlo[b0 * 2 + (b0 ^ 1)]);
    nr[r] = c00.x * s.re[r] - c00.y * s.im[r]
          + c01.x * s.re[r ^ 1] - c01.y * s.im[r ^ 1]
          + c10.x * s.re[r ^ 2] - c10.y * s.im[r ^ 2]
          + c11.x * s.re[r ^ 3] - c11.y * s.im[r ^ 3];
    ni[r] = c00.x * s.im[r] + c00.y * s.re[r]
          + c01.x * s.im[r ^ 1] + c01.y * s.re[r ^ 1]
          + c10.x * s.im[r ^ 2] + c10.y * s.re[r ^ 2]
          + c11.x * s.im[r ^ 3] + c11.y * s.re[r ^ 3];
  }
#pragma unroll
  for (int r = 0; r < 4; ++r) { s.re[r] = nr[r]; s.im[r] = ni[r]; }
}

DEV void reg0_gate(Psi4& s, const float2* __restrict__ M) {
  float nr[4], ni[4];
#pragma unroll
  for (int r = 0; r < 4; ++r) {
    const int b = r & 1;
    float2 d = M[b * 2 + b], o = M[b * 2 + (b ^ 1)];
    nr[r] = d.x * s.re[r] - d.y * s.im[r] + o.x * s.re[r ^ 1] - o.y * s.im[r ^ 1];
    ni[r] = d.x * s.im[r] + d.y * s.re[r] + o.x * s.im[r ^ 1] + o.y * s.re[r ^ 1];
  }
#pragma unroll
  for (int r = 0; r < 4; ++r) { s.re[r] = nr[r]; s.im[r] = ni[r]; }
}

template <bool FULL8>
DEV void perm_cx(Psi4& s, int lane) {
  const int slane = (lane ^ (lane << 1)) & 63;
  const bool L5 = ((lane >> 5) & 1) != 0;
  float nr[4], ni[4];
#pragma unroll
  for (int r = 0; r < 4; ++r) {
    const int r0 = r & 1, r1 = (r >> 1) & 1;
    const int hiBit = FULL8 ? (r1 ^ r0) : r1;
    const int sA = (hiBit << 1) | r0;
    const int sB = sA ^ 1;
    float aRe = __shfl(s.re[sA], slane, 64);
    float aIm = __shfl(s.im[sA], slane, 64);
    float bRe = __shfl(s.re[sB], slane, 64);
    float bIm = __shfl(s.im[sB], slane, 64);
    nr[r] = L5 ? bRe : aRe;
    ni[r] = L5 ? bIm : aIm;
  }
#pragma unroll
  for (int r = 0; r < 4; ++r) { s.re[r] = nr[r]; s.im[r] = ni[r]; }
}

template <int NQ>
DEV void ansatz_f(Psi4& s, const float2* __restrict__ Mg, int lane) {
#pragma unroll
  for (int d = 0; d < 2; ++d) {
    const float2* Md = Mg + d * NQ * 4;
    pair_gate<0>(s, Md + 0, Md + 4, lane);
    pair_gate<2>(s, Md + 8, Md + 12, lane);
    pair_gate<4>(s, Md + 16, Md + 20, lane);
    if (NQ == 8) regpair_gate(s, Md + 24, Md + 28);
    else reg0_gate(s, Md + 24);
    perm_cx<NQ == 8>(s, lane);
  }
}

// Vsw layout (validated): idx = k*32768 + g*1024 + hl*512 + L*8 + jj
// g = w*8 + t, t in [0,4) re tiles / [4,8) im tiles; L = quad*16 + (n&15)
DEV void store_v(unsigned short* __restrict__ Vsw, int n, int kk, float v) {
  int k = kk >> 5, rem = kk & 31, quad = rem >> 3, jj = rem & 7;
  int nn = n & 255;
  int w = (nn >> 6) & 3, t = (nn >> 4) & 3, cl = nn & 15;
  int g = w * 8 + ((n >= 256) ? 4 + t : t);
  int L = quad * 16 + cl;
  unsigned short hi = bf_rne(v);
  float hif = __uint_as_float(((unsigned)hi) << 16);
  unsigned short lo = bf_rne(v - hif);
  size_t base = (size_t)k * 32768 + (size_t)g * 1024 + (size_t)L * 8 + jj;
  Vsw[base] = hi;
  Vsw[base + 512] = lo;
}

__global__ void build_u(const float* __restrict__ th1, const float* __restrict__ th2,
                        const float* __restrict__ th3, unsigned short* __restrict__ Vsw) {
  __shared__ float2 Mg[46 * 4];
  const int tid = threadIdx.x;
  if (tid < 46) {
    float thx, thy, thz;
    if (tid < 16)      { thx = th1[tid * 3]; thy = th1[tid * 3 + 1]; thz = th1[tid * 3 + 2]; }
    else if (tid < 30) { int u = (tid - 16) * 3; thx = th2[u]; thy = th2[u + 1]; thz = th2[u + 2]; }
    else               { int u = (tid - 30) * 3; thx = th3[u]; thy = th3[u + 1]; thz = th3[u + 2]; }
    float sx, cx_, sy, cy_, sz, cz_;
    sincosf(0.5f * thx, &sx, &cx_);
    sincosf(0.5f * thy, &sy, &cy_);
    sincosf(0.5f * thz, &sz, &cz_);
    float2 rx[4] = {{cx_, 0}, {0, -sx}, {0, -sx}, {cx_, 0}};
    float2 ry[4] = {{cy_, 0}, {-sy, 0}, {sy, 0}, {cy_, 0}};
    float2 A0 = cadd(cmul(ry[0], rx[0]), cmul(ry[1], rx[2]));
    float2 A1 = cadd(cmul(ry[0], rx[1]), cmul(ry[1], rx[3]));
    float2 A2 = cadd(cmul(ry[2], rx[0]), cmul(ry[3], rx[2]));
    float2 A3 = cadd(cmul(ry[2], rx[1]), cmul(ry[3], rx[3]));
    float2 ezm = make_float2(cz_, -sz), ezp = make_float2(cz_, sz);
    Mg[tid * 4 + 0] = cmul(ezm, A0);
    Mg[tid * 4 + 1] = cmul(ezm, A1);
    Mg[tid * 4 + 2] = cmul(ezp, A2);
    Mg[tid * 4 + 3] = cmul(ezp, A3);
  }
  __syncthreads();

  const int lane = tid & 63;
  const int j = blockIdx.x * 4 + (tid >> 6);
  Psi4 s;
#pragma unroll
  for (int r = 0; r < 4; ++r) {
    int a = (r << 6) | lane;
    s.re[r] = (a == j) ? 1.f : 0.f;
    s.im[r] = 0.f;
  }
  ansatz_f<8>(s, Mg, lane);
  ansatz_f<7>(s, Mg + 16 * 4, lane);
  ansatz_f<8>(s, Mg + 30 * 4, lane);
#pragma unroll
  for (int r = 0; r < 4; ++r) {
    int a = (r << 6) | lane;
    store_v(Vsw, a, j, s.re[r]);
    store_v(Vsw, a + 256, j, s.im[r]);
  }
}

// ---------------------------------------------------------------------------
// Kernel B: 256 blocks x 512 threads (8 waves), 128 rows/block (1 block/CU).
// Wave ww: w = ww>>1 (amp slice), half = ww&1 (re|im tiles), n=64 cols/wave;
// mt = 8 row-tiles -> acc = 8x4 f32x4 = 128 AGPR, 24 MFMA per B-pair load.
// ---------------------------------------------------------------------------

__global__ __launch_bounds__(512, 2) void pqc_main(const float* __restrict__ x,
                                                   const unsigned short* __restrict__ Vsw,
                                                   float* __restrict__ out) {
  const int tid = threadIdx.x;
  const int ww = tid >> 6;
  const int w = ww >> 1;        // amp slice: i in [w*64, w*64+64)
  const int half = ww & 1;      // 0 = re tiles, 1 = im tiles
  const int L = tid & 63;
  const int quad = L >> 4;
  const int c = L & 15;
  const int row0 = blockIdx.x * 128;

  // A2[hl][k][mt][L*8 + j] : lane L of frag (mt,k) reads 16B at L*16
  __shared__ unsigned short A2[2][8][8][512];   // 128 KB
  __shared__ float ys[128][8];
  __shared__ float invn[128];
  float* part = (float*)&A2[0][0][0][0];        // overlay after k-loop (32 KB)

  // ---- stage A: 128 rows x 256 cols -> split bf16 hi/lo in frag order
  {
    const float4* xsrc = (const float4*)(x + (size_t)row0 * 256);
#pragma unroll
    for (int i = 0; i < 16; ++i) {
      int e = i * 512 + tid;          // float4 index in tile
      int row = e >> 6;               // 64 float4 per row
      int kk = (e & 63) * 4;
      float4 f = xsrc[e];
      ushort4 h, l;
#define SPLIT1(fld, v)                                           \
      {                                                          \
        unsigned u = __float_as_uint(v);                         \
        h.fld = (unsigned short)(u >> 16); /* trunc hi */        \
        float hf = __uint_as_float(u & 0xFFFF0000u);             \
        l.fld = (unsigned short)(__float_as_uint((v) - hf) >> 16); \
      }
      SPLIT1(x, f.x) SPLIT1(y, f.y) SPLIT1(z, f.z) SPLIT1(w, f.w)
#undef SPLIT1
      int mt = row >> 4, cc = row & 15;
      int k = kk >> 5, q = (kk >> 3) & 3, j = kk & 7;
      int idx = (q * 16 + cc) * 8 + j;
      *(ushort4*)&A2[0][k][mt][idx] = h;
      *(ushort4*)&A2[1][k][mt][idx] = l;
    }
  }
  __syncthreads();

  // ---- MFMA K-loop
  f32x4 acc[8][4];
#pragma unroll
  for (int mt = 0; mt < 8; ++mt)
#pragma unroll
    for (int tt = 0; tt < 4; ++tt) acc[mt][tt] = (f32x4){0.f, 0.f, 0.f, 0.f};

  const unsigned short* pb = Vsw + (size_t)w * 8192 + (size_t)half * 4096 + (size_t)L * 8;

#pragma unroll 1   // cap unroll: compiler pipelines 1 k-iter deep, no reg blowup
  for (int k = 0; k < 8; ++k) {
    short8 ah[8], al[8];
#pragma unroll
    for (int mt = 0; mt < 8; ++mt) {
      ah[mt] = *(const short8*)&A2[0][k][mt][L * 8];
      al[mt] = *(const short8*)&A2[1][k][mt][L * 8];
    }
    const unsigned short* pk = pb + (size_t)k * 32768;
#pragma unroll
    for (int tt = 0; tt < 4; ++tt) {
      short8 bh = *(const short8*)(pk + tt * 1024);
      short8 bl = *(const short8*)(pk + tt * 1024 + 512);
      // 8 independent MFMAs per term group (distinct acc) -> deep ILP
#pragma unroll
      for (int mt = 0; mt < 8; ++mt)
        acc[mt][tt] = __builtin_amdgcn_mfma_f32_16x16x32_bf16(ah[mt], bh, acc[mt][tt], 0, 0, 0);
#pragma unroll
      for (int mt = 0; mt < 8; ++mt)
        acc[mt][tt] = __builtin_amdgcn_mfma_f32_16x16x32_bf16(al[mt], bh, acc[mt][tt], 0, 0, 0);
#pragma unroll
      for (int mt = 0; mt < 8; ++mt)
        acc[mt][tt] = __builtin_amdgcn_mfma_f32_16x16x32_bf16(ah[mt], bl, acc[mt][tt], 0, 0, 0);
    }
  }
  __syncthreads();   // A2 dead; part overlay becomes valid

  // ---- epilogue: partial probs (re^2 or im^2) -> signed Walsh, 8 partials.
  // D layout: row m = mt*16 + quad*4 + r, col = c; tile tt covers amps
  // i = w*64 + tt*16 + c (this wave contributes re^2 or im^2 of psi_i).
#pragma unroll
  for (int mt = 0; mt < 8; ++mt) {
#pragma unroll
    for (int r = 0; r < 4; ++r) {
      float p0 = acc[mt][0][r] * acc[mt][0][r];
      float p1 = acc[mt][1][r] * acc[mt][1][r];
      float p2 = acc[mt][2][r] * acc[mt][2][r];
      float p3 = acc[mt][3][r] * acc[mt][3][r];
      float s01 = p0 + p1, s23 = p2 + p3;
      float av = s01 + s23;               // -> j=0,1,4..7
      float bv = s01 - s23;               // sign bit5 (tt>>1) -> j=2
      float cv = (p0 - p1) + (p2 - p3);   // sign bit4 (tt&1) -> j=3
#pragma unroll
      for (int st = 0; st < 4; ++st) {    // signed WHT over c bits
        int msk = 1 << st;
        float ta = __shfl_xor(av, msk, 64);
        av = ((c >> st) & 1) ? (ta - av) : (av + ta);
        bv += __shfl_xor(bv, msk, 64);
        cv += __shfl_xor(cv, msk, 64);
      }
      int m = mt * 16 + quad * 4 + r;
      float* pm = part + (ww * 128 + m) * 8;
      if (c == 0) {
        pm[0] = ((w >> 1) & 1) ? -av : av;  // j=0: bit7(i)
        pm[1] = (w & 1) ? -av : av;         // j=1: bit6(i)
        pm[2] = bv;
        pm[3] = cv;
      } else if (c == 8) pm[4] = av;   // j=4: bit3
      else if (c == 4) pm[5] = av;     // j=5: bit2
      else if (c == 2) pm[6] = av;     // j=6: bit1
      else if (c == 1) pm[7] = av;     // j=7: bit0
    }
  }
  __syncthreads();

#pragma unroll
  for (int s = 0; s < 2; ++s) {
    int e = s * 512 + tid;
    int m = e >> 3, jj = e & 7;
    float acc_y = 0.f;
#pragma unroll
    for (int p = 0; p < 8; ++p) acc_y += part[(p * 128 + m) * 8 + jj];
    ys[m][jj] = acc_y;
  }
  __syncthreads();

  if (tid < 128) {
    float n = 0.f;
#pragma unroll
    for (int jj = 0; jj < 8; ++jj) { float v = ys[tid][jj]; n = fmaf(v, v, n); }
    n = sqrtf(n);
    invn[tid] = (n == 0.f) ? 0.f : 1.f / n;
  }
  __syncthreads();

  // ---- write out: 128 rows x 64 float4 = 8192 float4, 16 per thread
  float4* o4 = (float4*)(out + (size_t)row0 * 256);
#pragma unroll
  for (int i = 0; i < 16; ++i) {
    int e = i * 512 + tid;
    int row = e >> 6;
    int c4 = (e & 63) * 4;
    float4 v = make_float4(0.f, 0.f, 0.f, 0.f);
    if (c4 < 8) {
      float iv = invn[row];
      float t0 = ys[row][c4 + 0] * iv;
      float t1 = ys[row][c4 + 1] * iv;
      float t2 = ys[row][c4 + 2] * iv;
      float t3 = ys[row][c4 + 3] * iv;
      v = make_float4(t0 * t0, t1 * t1, t2 * t2, t3 * t3);
    }
    o4[e] = v;
  }
}

extern "C" void kernel_launch(void* const* d_in, const int* in_sizes, int n_in,
                              void* d_out, int out_size, void* d_ws, size_t ws_size,
                              hipStream_t stream) {
  const float* x = (const float*)d_in[0];
  const float* th1 = (const float*)d_in[1];
  const float* th2 = (const float*)d_in[2];
  const float* th3 = (const float*)d_in[3];
  float* out = (float*)d_out;
  unsigned short* Vsw = (unsigned short*)d_ws;  // 512 KB swizzled V (hi+lo)

  build_u<<<64, 256, 0, stream>>>(th1, th2, th3, Vsw);
  pqc_main<<<256, 512, 0, stream>>>(x, Vsw, out);
}

// Round 7
// 122.608 us; speedup vs baseline: 1.9709x; 1.0289x over previous
//
#include <hip/hip_runtime.h>
#include <math.h>

// PQC autoencoder. out = g(U x), U = fixed 256x256 unitary from thetas
// (input normalization cancels: y/||y|| scale-invariant in x).
// Kernel A (build_u, ~2 us): fused-gate statevector sim -> V = [Re U; Im U]
//   split-bf16 hi/lo in MFMA-B-fragment stream order (validated R2-R6).
// Kernel B (pqc_main): split-bf16 MFMA GEMM (32768 x 512 x 256, 3 terms).
//   R7: LDS-pipe decongestion. (1) Walsh epilogue via DPP (VALU pipe) instead
//   of ds_bpermute shfl_xor -- removes ~18K cyc/CU from the CU-shared LDS
//   pipe. (2) staging remap + cc^(2q) XOR swizzle kills the 16-way staging
//   write bank conflicts (1.97M -> ~0); reads stay dense-1KB b128.

#define DEV __device__ __forceinline__

typedef __attribute__((ext_vector_type(8))) short short8;   // 8 bf16
typedef __attribute__((ext_vector_type(4))) float f32x4;

DEV float2 cmul(float2 a, float2 b) {
  return make_float2(a.x * b.x - a.y * b.y, a.x * b.y + a.y * b.x);
}
DEV float2 cadd(float2 a, float2 b) { return make_float2(a.x + b.x, a.y + b.y); }

DEV unsigned short bf_rne(float v) {
  unsigned u = __float_as_uint(v);
  return (unsigned short)((u + 0x7FFFu + ((u >> 16) & 1u)) >> 16);
}

// ---- DPP cross-lane (VALU pipe, rows of 16) ------------------------------
template <int CTRL>
DEV float dppf(float v) {
  return __int_as_float(__builtin_amdgcn_mov_dpp(__float_as_int(v), CTRL, 0xF, 0xF, true));
}
DEV float px1(float v) { return dppf<0xB1>(v); }                  // lane^1 (quad_perm 1,0,3,2)
DEV float px2(float v) { return dppf<0x4E>(v); }                  // lane^2 (quad_perm 2,3,0,1)
DEV float px4(float v) { return dppf<0x1B>(dppf<0x141>(v)); }     // ^7 then ^3 = ^4
DEV float px8(float v) { return dppf<0x141>(dppf<0x140>(v)); }    // ^15 then ^7 = ^8
DEV float fsgn(float v, int m) { return __int_as_float(__float_as_int(v) ^ m); }

// ---------------------------------------------------------------------------
// Kernel A (unchanged, validated)
// ---------------------------------------------------------------------------

struct Psi4 { float re[4]; float im[4]; };
// amplitude a = (r<<6)|lane; bit q of a: q<6 -> lane bit q; q==6 -> r&1; q==7 -> r>>1

template <int Q>
DEV void pair_gate(Psi4& s, const float2* __restrict__ Mlo,
                   const float2* __restrict__ Mhi, int lane) {
  const int b0 = (lane >> Q) & 1, b1 = (lane >> (Q + 1)) & 1;
  float2 lo_d = Mlo[b0 * 2 + b0];
  float2 lo_o = Mlo[b0 * 2 + (b0 ^ 1)];
  float2 hi_d = Mhi[b1 * 2 + b1];
  float2 hi_o = Mhi[b1 * 2 + (b1 ^ 1)];
  float2 c00 = cmul(hi_d, lo_d);
  float2 c01 = cmul(hi_d, lo_o);
  float2 c10 = cmul(hi_o, lo_d);
  float2 c11 = cmul(hi_o, lo_o);
  const int m0 = 1 << Q, m1 = 2 << Q;
#pragma unroll
  for (int r = 0; r < 4; ++r) {
    float ar = s.re[r], ai = s.im[r];
    float p0r = __shfl_xor(ar, m0, 64), p0i = __shfl_xor(ai, m0, 64);
    float p1r = __shfl_xor(ar, m1, 64), p1i = __shfl_xor(ai, m1, 64);
    float p2r = __shfl_xor(ar, m0 | m1, 64), p2i = __shfl_xor(ai, m0 | m1, 64);
    float nr = c00.x * ar - c00.y * ai + c01.x * p0r - c01.y * p0i
             + c10.x * p1r - c10.y * p1i + c11.x * p2r - c11.y * p2i;
    float ni = c00.x * ai + c00.y * ar + c01.x * p0i + c01.y * p0r
             + c10.x * p1i + c10.y * p1r + c11.x * p2i + c11.y * p2r;
    s.re[r] = nr; s.im[r] = ni;
  }
}

DEV void regpair_gate(Psi4& s, const float2* __restrict__ Mlo,
                      const float2* __restrict__ Mhi) {
  float nr[4], ni[4];
#pragma unroll
  for (int r = 0; r < 4; ++r) {
    const int b0 = r & 1, b1 = (r >> 1) & 1;
    float2 c00 = cmul(Mhi[b1 * 2 + b1], Mlo[b0 * 2 + b0]);
    float2 c01 = cmul(Mhi[b1 * 2 + b1], Mlo[b0 * 2 + (b0 ^ 1)]);
    float2 c10 = cmul(Mhi[b1 * 2 + (b1 ^ 1)], Mlo[b0 * 2 + b0]);
    float2 c11 = cmul(Mhi[b1 * 2 + (b1 ^ 1)], Mlo[b0 * 2 + (b0 ^ 1)]);
    nr[r] = c00.x * s.re[r] - c00.y * s.im[r]
          + c01.x * s.re[r ^ 1] - c01.y * s.im[r ^ 1]
          + c10.x * s.re[r ^ 2] - c10.y * s.im[r ^ 2]
          + c11.x * s.re[r ^ 3] - c11.y * s.im[r ^ 3];
    ni[r] = c00.x * s.im[r] + c00.y * s.re[r]
          + c01.x * s.im[r ^ 1] + c01.y * s.re[r ^ 1]
          + c10.x * s.im[r ^ 2] + c10.y * s.re[r ^ 2]
          + c11.x * s.im[r ^ 3] + c11.y * s.re[r ^ 3];
  }
#pragma unroll
  for (int r = 0; r < 4; ++r) { s.re[r] = nr[r]; s.im[r] = ni[r]; }
}

DEV void reg0_gate(Psi4& s, const float2* __restrict__ M) {
  float nr[4], ni[4];
#pragma unroll
  for (int r = 0; r < 4; ++r) {
    const int b = r & 1;
    float2 d = M[b * 2 + b], o = M[b * 2 + (b ^ 1)];
    nr[r] = d.x * s.re[r] - d.y * s.im[r] + o.x * s.re[r ^ 1] - o.y * s.im[r ^ 1];
    ni[r] = d.x * s.im[r] + d.y * s.re[r] + o.x * s.im[r ^ 1] + o.y * s.re[r ^ 1];
  }
#pragma unroll
  for (int r = 0; r < 4; ++r) { s.re[r] = nr[r]; s.im[r] = ni[r]; }
}

template <bool FULL8>
DEV void perm_cx(Psi4& s, int lane) {
  const int slane = (lane ^ (lane << 1)) & 63;
  const bool L5 = ((lane >> 5) & 1) != 0;
  float nr[4], ni[4];
#pragma unroll
  for (int r = 0; r < 4; ++r) {
    const int r0 = r & 1, r1 = (r >> 1) & 1;
    const int hiBit = FULL8 ? (r1 ^ r0) : r1;
    const int sA = (hiBit << 1) | r0;
    const int sB = sA ^ 1;
    float aRe = __shfl(s.re[sA], slane, 64);
    float aIm = __shfl(s.im[sA], slane, 64);
    float bRe = __shfl(s.re[sB], slane, 64);
    float bIm = __shfl(s.im[sB], slane, 64);
    nr[r] = L5 ? bRe : aRe;
    ni[r] = L5 ? bIm : aIm;
  }
#pragma unroll
  for (int r = 0; r < 4; ++r) { s.re[r] = nr[r]; s.im[r] = ni[r]; }
}

template <int NQ>
DEV void ansatz_f(Psi4& s, const float2* __restrict__ Mg, int lane) {
#pragma unroll
  for (int d = 0; d < 2; ++d) {
    const float2* Md = Mg + d * NQ * 4;
    pair_gate<0>(s, Md + 0, Md + 4, lane);
    pair_gate<2>(s, Md + 8, Md + 12, lane);
    pair_gate<4>(s, Md + 16, Md + 20, lane);
    if (NQ == 8) regpair_gate(s, Md + 24, Md + 28);
    else reg0_gate(s, Md + 24);
    perm_cx<NQ == 8>(s, lane);
  }
}

// Vsw layout (validated): idx = k*32768 + g*1024 + hl*512 + L*8 + jj
// g = w*8 + t, t in [0,4) re tiles / [4,8) im tiles; L = quad*16 + (n&15)
DEV void store_v(unsigned short* __restrict__ Vsw, int n, int kk, float v) {
  int k = kk >> 5, rem = kk & 31, quad = rem >> 3, jj = rem & 7;
  int nn = n & 255;
  int w = (nn >> 6) & 3, t = (nn >> 4) & 3, cl = nn & 15;
  int g = w * 8 + ((n >= 256) ? 4 + t : t);
  int L = quad * 16 + cl;
  unsigned short hi = bf_rne(v);
  float hif = __uint_as_float(((unsigned)hi) << 16);
  unsigned short lo = bf_rne(v - hif);
  size_t base = (size_t)k * 32768 + (size_t)g * 1024 + (size_t)L * 8 + jj;
  Vsw[base] = hi;
  Vsw[base + 512] = lo;
}

__global__ void build_u(const float* __restrict__ th1, const float* __restrict__ th2,
                        const float* __restrict__ th3, unsigned short* __restrict__ Vsw) {
  __shared__ float2 Mg[46 * 4];
  const int tid = threadIdx.x;
  if (tid < 46) {
    float thx, thy, thz;
    if (tid < 16)      { thx = th1[tid * 3]; thy = th1[tid * 3 + 1]; thz = th1[tid * 3 + 2]; }
    else if (tid < 30) { int u = (tid - 16) * 3; thx = th2[u]; thy = th2[u + 1]; thz = th2[u + 2]; }
    else               { int u = (tid - 30) * 3; thx = th3[u]; thy = th3[u + 1]; thz = th3[u + 2]; }
    float sx, cx_, sy, cy_, sz, cz_;
    sincosf(0.5f * thx, &sx, &cx_);
    sincosf(0.5f * thy, &sy, &cy_);
    sincosf(0.5f * thz, &sz, &cz_);
    float2 rx[4] = {{cx_, 0}, {0, -sx}, {0, -sx}, {cx_, 0}};
    float2 ry[4] = {{cy_, 0}, {-sy, 0}, {sy, 0}, {cy_, 0}};
    float2 A0 = cadd(cmul(ry[0], rx[0]), cmul(ry[1], rx[2]));
    float2 A1 = cadd(cmul(ry[0], rx[1]), cmul(ry[1], rx[3]));
    float2 A2 = cadd(cmul(ry[2], rx[0]), cmul(ry[3], rx[2]));
    float2 A3 = cadd(cmul(ry[2], rx[1]), cmul(ry[3], rx[3]));
    float2 ezm = make_float2(cz_, -sz), ezp = make_float2(cz_, sz);
    Mg[tid * 4 + 0] = cmul(ezm, A0);
    Mg[tid * 4 + 1] = cmul(ezm, A1);
    Mg[tid * 4 + 2] = cmul(ezp, A2);
    Mg[tid * 4 + 3] = cmul(ezp, A3);
  }
  __syncthreads();

  const int lane = tid & 63;
  const int j = blockIdx.x * 4 + (tid >> 6);
  Psi4 s;
#pragma unroll
  for (int r = 0; r < 4; ++r) {
    int a = (r << 6) | lane;
    s.re[r] = (a == j) ? 1.f : 0.f;
    s.im[r] = 0.f;
  }
  ansatz_f<8>(s, Mg, lane);
  ansatz_f<7>(s, Mg + 16 * 4, lane);
  ansatz_f<8>(s, Mg + 30 * 4, lane);
#pragma unroll
  for (int r = 0; r < 4; ++r) {
    int a = (r << 6) | lane;
    store_v(Vsw, a, j, s.re[r]);
    store_v(Vsw, a + 256, j, s.im[r]);
  }
}

// ---------------------------------------------------------------------------
// Kernel B: 256 blocks x 512 threads (8 waves), 128 rows/block (1 block/CU).
// Wave ww: w = ww>>1 (amp slice), half = ww&1 (re|im tiles), n=64 cols/wave;
// mt = 8 row-tiles -> acc = 8x4 f32x4 = 128 AGPR, 24 MFMA per B-pair load.
// A2 index swizzle: col slot = (quad*16 + (cc ^ 2*quad)) on write AND read.
// ---------------------------------------------------------------------------

__global__ __launch_bounds__(512, 2) void pqc_main(const float* __restrict__ x,
                                                   const unsigned short* __restrict__ Vsw,
                                                   float* __restrict__ out) {
  const int tid = threadIdx.x;
  const int ww = tid >> 6;
  const int w = ww >> 1;        // amp slice: i in [w*64, w*64+64)
  const int half = ww & 1;      // 0 = re tiles, 1 = im tiles
  const int L = tid & 63;
  const int quad = L >> 4;
  const int c = L & 15;
  const int row0 = blockIdx.x * 128;

  // A2[hl][k][mt][slot*8 + j], slot = quad*16 + (cc ^ 2*quad)
  __shared__ unsigned short A2[2][8][8][512];   // 128 KB
  __shared__ float ys[128][8];
  __shared__ float invn[128];
  float* part = (float*)&A2[0][0][0][0];        // overlay after k-loop (32 KB)

  // ---- stage A: lane covers 8 rows x its wave's k-column group.
  // Global: 8 lanes with same r8 read 8 consecutive float4 (128 B chunks).
  // LDS write banks spread by cc (8 values) -> ~4-way worst (was 16-way).
  {
    const float4* xsrc = (const float4*)(x + (size_t)row0 * 256);
    const int r8 = L & 7;            // row within group of 8
    const int kf = L >> 3;           // fine col 0..7 within wave's k-group
    const int q = kf >> 1;
    const int jj0 = (kf & 1) * 4;
#pragma unroll
    for (int i = 0; i < 16; ++i) {
      int row = i * 8 + r8;
      float4 f = xsrc[row * 64 + ww * 8 + kf];
      ushort4 h, l;
#define SPLIT1(fld, v)                                           \
      {                                                          \
        unsigned u = __float_as_uint(v);                         \
        h.fld = (unsigned short)(u >> 16); /* trunc hi */        \
        float hf = __uint_as_float(u & 0xFFFF0000u);             \
        l.fld = (unsigned short)(__float_as_uint((v) - hf) >> 16); \
      }
      SPLIT1(x, f.x) SPLIT1(y, f.y) SPLIT1(z, f.z) SPLIT1(w, f.w)
#undef SPLIT1
      int mt = row >> 4, cc = row & 15;
      int idx = (q * 16 + (cc ^ (q << 1))) * 8 + jj0;
      *(ushort4*)&A2[0][ww][mt][idx] = h;
      *(ushort4*)&A2[1][ww][mt][idx] = l;
    }
  }
  __syncthreads();

  // ---- MFMA K-loop
  f32x4 acc[8][4];
#pragma unroll
  for (int mt = 0; mt < 8; ++mt)
#pragma unroll
    for (int tt = 0; tt < 4; ++tt) acc[mt][tt] = (f32x4){0.f, 0.f, 0.f, 0.f};

  const unsigned short* pb = Vsw + (size_t)w * 8192 + (size_t)half * 4096 + (size_t)L * 8;
  const int sL8 = (quad * 16 + (c ^ (quad << 1))) * 8;   // swizzled A slot

#pragma unroll 1   // cap unroll: compiler pipelines 1 k-iter deep, no reg blowup
  for (int k = 0; k < 8; ++k) {
    short8 ah[8], al[8];
#pragma unroll
    for (int mt = 0; mt < 8; ++mt) {
      ah[mt] = *(const short8*)&A2[0][k][mt][sL8];
      al[mt] = *(const short8*)&A2[1][k][mt][sL8];
    }
    const unsigned short* pk = pb + (size_t)k * 32768;
#pragma unroll
    for (int tt = 0; tt < 4; ++tt) {
      short8 bh = *(const short8*)(pk + tt * 1024);
      short8 bl = *(const short8*)(pk + tt * 1024 + 512);
#pragma unroll
      for (int mt = 0; mt < 8; ++mt)
        acc[mt][tt] = __builtin_amdgcn_mfma_f32_16x16x32_bf16(ah[mt], bh, acc[mt][tt], 0, 0, 0);
#pragma unroll
      for (int mt = 0; mt < 8; ++mt)
        acc[mt][tt] = __builtin_amdgcn_mfma_f32_16x16x32_bf16(al[mt], bh, acc[mt][tt], 0, 0, 0);
#pragma unroll
      for (int mt = 0; mt < 8; ++mt)
        acc[mt][tt] = __builtin_amdgcn_mfma_f32_16x16x32_bf16(ah[mt], bl, acc[mt][tt], 0, 0, 0);
    }
  }
  __syncthreads();   // A2 dead; part overlay becomes valid

  // ---- epilogue: partial probs (re^2 or im^2) -> signed Walsh via DPP
  // (VALU pipe -- no LDS traffic until the final part[] stores).
  const int m1 = (c & 1) << 31;
  const int m2 = (c & 2) << 30;
  const int m4 = (c & 4) << 29;
  const int m8 = (c & 8) << 28;
#pragma unroll
  for (int mt = 0; mt < 8; ++mt) {
#pragma unroll
    for (int r = 0; r < 4; ++r) {
      float p0 = acc[mt][0][r] * acc[mt][0][r];
      float p1 = acc[mt][1][r] * acc[mt][1][r];
      float p2 = acc[mt][2][r] * acc[mt][2][r];
      float p3 = acc[mt][3][r] * acc[mt][3][r];
      float s01 = p0 + p1, s23 = p2 + p3;
      float av = s01 + s23;               // -> j=0,1,4..7
      float bv = s01 - s23;               // sign bit5 (tt>>1) -> j=2
      float cv = (p0 - p1) + (p2 - p3);   // sign bit4 (tt&1) -> j=3
      // signed WHT over c bits via DPP: av = pxK(av) + sign_flip(av)
      av = px1(av) + fsgn(av, m1);
      bv += px1(bv);  cv += px1(cv);
      av = px2(av) + fsgn(av, m2);
      bv += px2(bv);  cv += px2(cv);
      av = px4(av) + fsgn(av, m4);
      bv += px4(bv);  cv += px4(cv);
      av = px8(av) + fsgn(av, m8);
      bv += px8(bv);  cv += px8(cv);
      int m = mt * 16 + quad * 4 + r;
      float* pm = part + (ww * 128 + m) * 8;
      if (c == 0) {
        pm[0] = ((w >> 1) & 1) ? -av : av;  // j=0: bit7(i)
        pm[1] = (w & 1) ? -av : av;         // j=1: bit6(i)
        pm[2] = bv;
        pm[3] = cv;
      } else if (c == 8) pm[4] = av;   // j=4: bit3
      else if (c == 4) pm[5] = av;     // j=5: bit2
      else if (c == 2) pm[6] = av;     // j=6: bit1
      else if (c == 1) pm[7] = av;     // j=7: bit0
    }
  }
  __syncthreads();

#pragma unroll
  for (int s = 0; s < 2; ++s) {
    int e = s * 512 + tid;
    int m = e >> 3, jj = e & 7;
    float acc_y = 0.f;
#pragma unroll
    for (int p = 0; p < 8; ++p) acc_y += part[(p * 128 + m) * 8 + jj];
    ys[m][jj] = acc_y;
  }
  __syncthreads();

  if (tid < 128) {
    float n = 0.f;
#pragma unroll
    for (int jj = 0; jj < 8; ++jj) { float v = ys[tid][jj]; n = fmaf(v, v, n); }
    n = sqrtf(n);
    invn[tid] = (n == 0.f) ? 0.f : 1.f / n;
  }
  __syncthreads();

  // ---- write out: 128 rows x 64 float4 = 8192 float4, 16 per thread
  float4* o4 = (float4*)(out + (size_t)row0 * 256);
#pragma unroll
  for (int i = 0; i < 16; ++i) {
    int e = i * 512 + tid;
    int row = e >> 6;
    int c4 = (e & 63) * 4;
    float4 v = make_float4(0.f, 0.f, 0.f, 0.f);
    if (c4 < 8) {
      float iv = invn[row];
      float t0 = ys[row][c4 + 0] * iv;
      float t1 = ys[row][c4 + 1] * iv;
      float t2 = ys[row][c4 + 2] * iv;
      float t3 = ys[row][c4 + 3] * iv;
      v = make_float4(t0 * t0, t1 * t1, t2 * t2, t3 * t3);
    }
    o4[e] = v;
  }
}

extern "C" void kernel_launch(void* const* d_in, const int* in_sizes, int n_in,
                              void* d_out, int out_size, void* d_ws, size_t ws_size,
                              hipStream_t stream) {
  const float* x = (const float*)d_in[0];
  const float* th1 = (const float*)d_in[1];
  const float* th2 = (const float*)d_in[2];
  const float* th3 = (const float*)d_in[3];
  float* out = (float*)d_out;
  unsigned short* Vsw = (unsigned short*)d_ws;  // 512 KB swizzled V (hi+lo)

  build_u<<<64, 256, 0, stream>>>(th1, th2, th3, Vsw);
  pqc_main<<<256, 512, 0, stream>>>(x, Vsw, out);
}

// Round 8
// 117.864 us; speedup vs baseline: 2.0503x; 1.0402x over previous
//
#include <hip/hip_runtime.h>
#include <math.h>

// PQC autoencoder. out = g(U x), U = fixed 256x256 unitary from thetas
// (input normalization cancels: y/||y|| scale-invariant in x).
// Kernel A (build_u, ~2 us): fused-gate statevector sim -> V = [Re U; Im U]
//   split-bf16 hi/lo in MFMA-B-fragment stream order (validated R2-R7).
// Kernel B (pqc_main): split-bf16 MFMA GEMM (32768 x 512 x 256, 3 terms).
//   R8 = R5 shape + R7 fixes: 64 rows/block, 512 thr, grid 512 -> 2 blocks/CU
//   so one block's HBM staging overlaps the other's k-loop (the serial
//   head/tail was the R6/R7 44us invariant). Conflict-free swizzled staging,
//   DPP Walsh epilogue, unroll-1 k-loop. acc 64 AGPR + ~70 VGPR -> 4 waves/EU.

#define DEV __device__ __forceinline__

typedef __attribute__((ext_vector_type(8))) short short8;   // 8 bf16
typedef __attribute__((ext_vector_type(4))) float f32x4;

DEV float2 cmul(float2 a, float2 b) {
  return make_float2(a.x * b.x - a.y * b.y, a.x * b.y + a.y * b.x);
}
DEV float2 cadd(float2 a, float2 b) { return make_float2(a.x + b.x, a.y + b.y); }

DEV unsigned short bf_rne(float v) {
  unsigned u = __float_as_uint(v);
  return (unsigned short)((u + 0x7FFFu + ((u >> 16) & 1u)) >> 16);
}

// ---- DPP cross-lane (VALU pipe, rows of 16) ------------------------------
template <int CTRL>
DEV float dppf(float v) {
  return __int_as_float(__builtin_amdgcn_mov_dpp(__float_as_int(v), CTRL, 0xF, 0xF, true));
}
DEV float px1(float v) { return dppf<0xB1>(v); }                  // lane^1
DEV float px2(float v) { return dppf<0x4E>(v); }                  // lane^2
DEV float px4(float v) { return dppf<0x1B>(dppf<0x141>(v)); }     // ^7 then ^3 = ^4
DEV float px8(float v) { return dppf<0x141>(dppf<0x140>(v)); }    // ^15 then ^7 = ^8
DEV float fsgn(float v, int m) { return __int_as_float(__float_as_int(v) ^ m); }

// ---------------------------------------------------------------------------
// Kernel A (unchanged, validated)
// ---------------------------------------------------------------------------

struct Psi4 { float re[4]; float im[4]; };
// amplitude a = (r<<6)|lane; bit q of a: q<6 -> lane bit q; q==6 -> r&1; q==7 -> r>>1

template <int Q>
DEV void pair_gate(Psi4& s, const float2* __restrict__ Mlo,
                   const float2* __restrict__ Mhi, int lane) {
  const int b0 = (lane >> Q) & 1, b1 = (lane >> (Q + 1)) & 1;
  float2 lo_d = Mlo[b0 * 2 + b0];
  float2 lo_o = Mlo[b0 * 2 + (b0 ^ 1)];
  float2 hi_d = Mhi[b1 * 2 + b1];
  float2 hi_o = Mhi[b1 * 2 + (b1 ^ 1)];
  float2 c00 = cmul(hi_d, lo_d);
  float2 c01 = cmul(hi_d, lo_o);
  float2 c10 = cmul(hi_o, lo_d);
  float2 c11 = cmul(hi_o, lo_o);
  const int m0 = 1 << Q, m1 = 2 << Q;
#pragma unroll
  for (int r = 0; r < 4; ++r) {
    float ar = s.re[r], ai = s.im[r];
    float p0r = __shfl_xor(ar, m0, 64), p0i = __shfl_xor(ai, m0, 64);
    float p1r = __shfl_xor(ar, m1, 64), p1i = __shfl_xor(ai, m1, 64);
    float p2r = __shfl_xor(ar, m0 | m1, 64), p2i = __shfl_xor(ai, m0 | m1, 64);
    float nr = c00.x * ar - c00.y * ai + c01.x * p0r - c01.y * p0i
             + c10.x * p1r - c10.y * p1i + c11.x * p2r - c11.y * p2i;
    float ni = c00.x * ai + c00.y * ar + c01.x * p0i + c01.y * p0r
             + c10.x * p1i + c10.y * p1r + c11.x * p2i + c11.y * p2r;
    s.re[r] = nr; s.im[r] = ni;
  }
}

DEV void regpair_gate(Psi4& s, const float2* __restrict__ Mlo,
                      const float2* __restrict__ Mhi) {
  float nr[4], ni[4];
#pragma unroll
  for (int r = 0; r < 4; ++r) {
    const int b0 = r & 1, b1 = (r >> 1) & 1;
    float2 c00 = cmul(Mhi[b1 * 2 + b1], Mlo[b0 * 2 + b0]);
    float2 c01 = cmul(Mhi[b1 * 2 + b1], Mlo[b0 * 2 + (b0 ^ 1)]);
    float2 c10 = cmul(Mhi[b1 * 2 + (b1 ^ 1)], Mlo[b0 * 2 + b0]);
    float2 c11 = cmul(Mhi[b1 * 2 + (b1 ^ 1)], Mlo[b0 * 2 + (b0 ^ 1)]);
    nr[r] = c00.x * s.re[r] - c00.y * s.im[r]
          + c01.x * s.re[r ^ 1] - c01.y * s.im[r ^ 1]
          + c10.x * s.re[r ^ 2] - c10.y * s.im[r ^ 2]
          + c11.x * s.re[r ^ 3] - c11.y * s.im[r ^ 3];
    ni[r] = c00.x * s.im[r] + c00.y * s.re[r]
          + c01.x * s.im[r ^ 1] + c01.y * s.re[r ^ 1]
          + c10.x * s.im[r ^ 2] + c10.y * s.re[r ^ 2]
          + c11.x * s.im[r ^ 3] + c11.y * s.re[r ^ 3];
  }
#pragma unroll
  for (int r = 0; r < 4; ++r) { s.re[r] = nr[r]; s.im[r] = ni[r]; }
}

DEV void reg0_gate(Psi4& s, const float2* __restrict__ M) {
  float nr[4], ni[4];
#pragma unroll
  for (int r = 0; r < 4; ++r) {
    const int b = r & 1;
    float2 d = M[b * 2 + b], o = M[b * 2 + (b ^ 1)];
    nr[r] = d.x * s.re[r] - d.y * s.im[r] + o.x * s.re[r ^ 1] - o.y * s.im[r ^ 1];
    ni[r] = d.x * s.im[r] + d.y * s.re[r] + o.x * s.im[r ^ 1] + o.y * s.re[r ^ 1];
  }
#pragma unroll
  for (int r = 0; r < 4; ++r) { s.re[r] = nr[r]; s.im[r] = ni[r]; }
}

template <bool FULL8>
DEV void perm_cx(Psi4& s, int lane) {
  const int slane = (lane ^ (lane << 1)) & 63;
  const bool L5 = ((lane >> 5) & 1) != 0;
  float nr[4], ni[4];
#pragma unroll
  for (int r = 0; r < 4; ++r) {
    const int r0 = r & 1, r1 = (r >> 1) & 1;
    const int hiBit = FULL8 ? (r1 ^ r0) : r1;
    const int sA = (hiBit << 1) | r0;
    const int sB = sA ^ 1;
    float aRe = __shfl(s.re[sA], slane, 64);
    float aIm = __shfl(s.im[sA], slane, 64);
    float bRe = __shfl(s.re[sB], slane, 64);
    float bIm = __shfl(s.im[sB], slane, 64);
    nr[r] = L5 ? bRe : aRe;
    ni[r] = L5 ? bIm : aIm;
  }
#pragma unroll
  for (int r = 0; r < 4; ++r) { s.re[r] = nr[r]; s.im[r] = ni[r]; }
}

template <int NQ>
DEV void ansatz_f(Psi4& s, const float2* __restrict__ Mg, int lane) {
#pragma unroll
  for (int d = 0; d < 2; ++d) {
    const float2* Md = Mg + d * NQ * 4;
    pair_gate<0>(s, Md + 0, Md + 4, lane);
    pair_gate<2>(s, Md + 8, Md + 12, lane);
    pair_gate<4>(s, Md + 16, Md + 20, lane);
    if (NQ == 8) regpair_gate(s, Md + 24, Md + 28);
    else reg0_gate(s, Md + 24);
    perm_cx<NQ == 8>(s, lane);
  }
}

// Vsw layout (validated): idx = k*32768 + g*1024 + hl*512 + L*8 + jj
// g = w*8 + t, t in [0,4) re tiles / [4,8) im tiles; L = quad*16 + (n&15)
DEV void store_v(unsigned short* __restrict__ Vsw, int n, int kk, float v) {
  int k = kk >> 5, rem = kk & 31, quad = rem >> 3, jj = rem & 7;
  int nn = n & 255;
  int w = (nn >> 6) & 3, t = (nn >> 4) & 3, cl = nn & 15;
  int g = w * 8 + ((n >= 256) ? 4 + t : t);
  int L = quad * 16 + cl;
  unsigned short hi = bf_rne(v);
  float hif = __uint_as_float(((unsigned)hi) << 16);
  unsigned short lo = bf_rne(v - hif);
  size_t base = (size_t)k * 32768 + (size_t)g * 1024 + (size_t)L * 8 + jj;
  Vsw[base] = hi;
  Vsw[base + 512] = lo;
}

__global__ void build_u(const float* __restrict__ th1, const float* __restrict__ th2,
                        const float* __restrict__ th3, unsigned short* __restrict__ Vsw) {
  __shared__ float2 Mg[46 * 4];
  const int tid = threadIdx.x;
  if (tid < 46) {
    float thx, thy, thz;
    if (tid < 16)      { thx = th1[tid * 3]; thy = th1[tid * 3 + 1]; thz = th1[tid * 3 + 2]; }
    else if (tid < 30) { int u = (tid - 16) * 3; thx = th2[u]; thy = th2[u + 1]; thz = th2[u + 2]; }
    else               { int u = (tid - 30) * 3; thx = th3[u]; thy = th3[u + 1]; thz = th3[u + 2]; }
    float sx, cx_, sy, cy_, sz, cz_;
    sincosf(0.5f * thx, &sx, &cx_);
    sincosf(0.5f * thy, &sy, &cy_);
    sincosf(0.5f * thz, &sz, &cz_);
    float2 rx[4] = {{cx_, 0}, {0, -sx}, {0, -sx}, {cx_, 0}};
    float2 ry[4] = {{cy_, 0}, {-sy, 0}, {sy, 0}, {cy_, 0}};
    float2 A0 = cadd(cmul(ry[0], rx[0]), cmul(ry[1], rx[2]));
    float2 A1 = cadd(cmul(ry[0], rx[1]), cmul(ry[1], rx[3]));
    float2 A2 = cadd(cmul(ry[2], rx[0]), cmul(ry[3], rx[2]));
    float2 A3 = cadd(cmul(ry[2], rx[1]), cmul(ry[3], rx[3]));
    float2 ezm = make_float2(cz_, -sz), ezp = make_float2(cz_, sz);
    Mg[tid * 4 + 0] = cmul(ezm, A0);
    Mg[tid * 4 + 1] = cmul(ezm, A1);
    Mg[tid * 4 + 2] = cmul(ezp, A2);
    Mg[tid * 4 + 3] = cmul(ezp, A3);
  }
  __syncthreads();

  const int lane = tid & 63;
  const int j = blockIdx.x * 4 + (tid >> 6);
  Psi4 s;
#pragma unroll
  for (int r = 0; r < 4; ++r) {
    int a = (r << 6) | lane;
    s.re[r] = (a == j) ? 1.f : 0.f;
    s.im[r] = 0.f;
  }
  ansatz_f<8>(s, Mg, lane);
  ansatz_f<7>(s, Mg + 16 * 4, lane);
  ansatz_f<8>(s, Mg + 30 * 4, lane);
#pragma unroll
  for (int r = 0; r < 4; ++r) {
    int a = (r << 6) | lane;
    store_v(Vsw, a, j, s.re[r]);
    store_v(Vsw, a + 256, j, s.im[r]);
  }
}

// ---------------------------------------------------------------------------
// Kernel B: 512 blocks x 512 threads (8 waves), 64 rows/block, 2 blocks/CU.
// Wave ww: w = ww>>1 (amp slice), half = ww&1 (re|im tiles), n=64 cols/wave;
// mt = 4 row-tiles -> acc = 4x4 f32x4 = 64 AGPR (+ ~70 arch VGPR -> 4 w/EU).
// A2 col slot swizzle (cc ^ 2*quad) on write AND read: conflict-free.
// ---------------------------------------------------------------------------

__global__ __launch_bounds__(512, 4) void pqc_main(const float* __restrict__ x,
                                                   const unsigned short* __restrict__ Vsw,
                                                   float* __restrict__ out) {
  const int tid = threadIdx.x;
  const int ww = tid >> 6;
  const int w = ww >> 1;        // amp slice: i in [w*64, w*64+64)
  const int half = ww & 1;      // 0 = re tiles, 1 = im tiles
  const int L = tid & 63;
  const int quad = L >> 4;
  const int c = L & 15;
  const int row0 = blockIdx.x * 64;

  // A2[hl][k][mt][slot*8 + j], slot = quad*16 + (cc ^ 2*quad)
  __shared__ unsigned short A2[2][8][4][512];   // 64 KB
  __shared__ float ys[64][8];
  __shared__ float invn[64];
  float* part = (float*)&A2[0][0][0][0];        // overlay after k-loop (16 KB)

  // ---- stage A: 64 rows x 256 cols; lane covers 8 rows (r8) x wave k-group.
  {
    const float4* xsrc = (const float4*)(x + (size_t)row0 * 256);
    const int r8 = L & 7;            // row within group of 8
    const int kf = L >> 3;           // fine col 0..7 within wave's k-group
    const int q = kf >> 1;
    const int jj0 = (kf & 1) * 4;
#pragma unroll
    for (int i = 0; i < 8; ++i) {
      int row = i * 8 + r8;
      float4 f = xsrc[row * 64 + ww * 8 + kf];
      ushort4 h, l;
#define SPLIT1(fld, v)                                           \
      {                                                          \
        unsigned u = __float_as_uint(v);                         \
        h.fld = (unsigned short)(u >> 16); /* trunc hi */        \
        float hf = __uint_as_float(u & 0xFFFF0000u);             \
        l.fld = (unsigned short)(__float_as_uint((v) - hf) >> 16); \
      }
      SPLIT1(x, f.x) SPLIT1(y, f.y) SPLIT1(z, f.z) SPLIT1(w, f.w)
#undef SPLIT1
      int mt = row >> 4, cc = row & 15;
      int idx = (q * 16 + (cc ^ (q << 1))) * 8 + jj0;
      *(ushort4*)&A2[0][ww][mt][idx] = h;
      *(ushort4*)&A2[1][ww][mt][idx] = l;
    }
  }
  __syncthreads();

  // ---- MFMA K-loop
  f32x4 acc[4][4];
#pragma unroll
  for (int mt = 0; mt < 4; ++mt)
#pragma unroll
    for (int tt = 0; tt < 4; ++tt) acc[mt][tt] = (f32x4){0.f, 0.f, 0.f, 0.f};

  const unsigned short* pb = Vsw + (size_t)w * 8192 + (size_t)half * 4096 + (size_t)L * 8;
  const int sL8 = (quad * 16 + (c ^ (quad << 1))) * 8;   // swizzled A slot

#pragma unroll 1   // cap unroll: pipeline 1 k-iter deep, keep regs in budget
  for (int k = 0; k < 8; ++k) {
    short8 ah[4], al[4];
#pragma unroll
    for (int mt = 0; mt < 4; ++mt) {
      ah[mt] = *(const short8*)&A2[0][k][mt][sL8];
      al[mt] = *(const short8*)&A2[1][k][mt][sL8];
    }
    const unsigned short* pk = pb + (size_t)k * 32768;
#pragma unroll
    for (int tt = 0; tt < 4; ++tt) {
      short8 bh = *(const short8*)(pk + tt * 1024);
      short8 bl = *(const short8*)(pk + tt * 1024 + 512);
#pragma unroll
      for (int mt = 0; mt < 4; ++mt)
        acc[mt][tt] = __builtin_amdgcn_mfma_f32_16x16x32_bf16(ah[mt], bh, acc[mt][tt], 0, 0, 0);
#pragma unroll
      for (int mt = 0; mt < 4; ++mt)
        acc[mt][tt] = __builtin_amdgcn_mfma_f32_16x16x32_bf16(al[mt], bh, acc[mt][tt], 0, 0, 0);
#pragma unroll
      for (int mt = 0; mt < 4; ++mt)
        acc[mt][tt] = __builtin_amdgcn_mfma_f32_16x16x32_bf16(ah[mt], bl, acc[mt][tt], 0, 0, 0);
    }
  }
  __syncthreads();   // A2 dead; part overlay becomes valid

  // ---- epilogue: partial probs (re^2 or im^2) -> signed Walsh via DPP.
  // D layout: row m = mt*16 + quad*4 + r, col = c; tile tt covers amps
  // i = w*64 + tt*16 + c.
  const int m1 = (c & 1) << 31;
  const int m2 = (c & 2) << 30;
  const int m4 = (c & 4) << 29;
  const int m8 = (c & 8) << 28;
#pragma unroll
  for (int mt = 0; mt < 4; ++mt) {
#pragma unroll
    for (int r = 0; r < 4; ++r) {
      float p0 = acc[mt][0][r] * acc[mt][0][r];
      float p1 = acc[mt][1][r] * acc[mt][1][r];
      float p2 = acc[mt][2][r] * acc[mt][2][r];
      float p3 = acc[mt][3][r] * acc[mt][3][r];
      float s01 = p0 + p1, s23 = p2 + p3;
      float av = s01 + s23;               // -> j=0,1,4..7
      float bv = s01 - s23;               // sign bit5 (tt>>1) -> j=2
      float cv = (p0 - p1) + (p2 - p3);   // sign bit4 (tt&1) -> j=3
      av = px1(av) + fsgn(av, m1);
      bv += px1(bv);  cv += px1(cv);
      av = px2(av) + fsgn(av, m2);
      bv += px2(bv);  cv += px2(cv);
      av = px4(av) + fsgn(av, m4);
      bv += px4(bv);  cv += px4(cv);
      av = px8(av) + fsgn(av, m8);
      bv += px8(bv);  cv += px8(cv);
      int m = mt * 16 + quad * 4 + r;
      float* pm = part + (ww * 64 + m) * 8;
      if (c == 0) {
        pm[0] = ((w >> 1) & 1) ? -av : av;  // j=0: bit7(i)
        pm[1] = (w & 1) ? -av : av;         // j=1: bit6(i)
        pm[2] = bv;
        pm[3] = cv;
      } else if (c == 8) pm[4] = av;   // j=4: bit3
      else if (c == 4) pm[5] = av;     // j=5: bit2
      else if (c == 2) pm[6] = av;     // j=6: bit1
      else if (c == 1) pm[7] = av;     // j=7: bit0
    }
  }
  __syncthreads();

  {
    int m = tid >> 3, jj = tid & 7;
    float acc_y = 0.f;
#pragma unroll
    for (int p = 0; p < 8; ++p) acc_y += part[(p * 64 + m) * 8 + jj];
    ys[m][jj] = acc_y;
  }
  __syncthreads();

  if (tid < 64) {
    float n = 0.f;
#pragma unroll
    for (int jj = 0; jj < 8; ++jj) { float v = ys[tid][jj]; n = fmaf(v, v, n); }
    n = sqrtf(n);
    invn[tid] = (n == 0.f) ? 0.f : 1.f / n;
  }
  __syncthreads();

  // ---- write out: 64 rows x 64 float4 = 4096 float4, 8 per thread
  float4* o4 = (float4*)(out + (size_t)row0 * 256);
#pragma unroll
  for (int i = 0; i < 8; ++i) {
    int e = i * 512 + tid;
    int row = e >> 6;
    int c4 = (e & 63) * 4;
    float4 v = make_float4(0.f, 0.f, 0.f, 0.f);
    if (c4 < 8) {
      float iv = invn[row];
      float t0 = ys[row][c4 + 0] * iv;
      float t1 = ys[row][c4 + 1] * iv;
      float t2 = ys[row][c4 + 2] * iv;
      float t3 = ys[row][c4 + 3] * iv;
      v = make_float4(t0 * t0, t1 * t1, t2 * t2, t3 * t3);
    }
    o4[e] = v;
  }
}

extern "C" void kernel_launch(void* const* d_in, const int* in_sizes, int n_in,
                              void* d_out, int out_size, void* d_ws, size_t ws_size,
                              hipStream_t stream) {
  const float* x = (const float*)d_in[0];
  const float* th1 = (const float*)d_in[1];
  const float* th2 = (const float*)d_in[2];
  const float* th3 = (const float*)d_in[3];
  float* out = (float*)d_out;
  unsigned short* Vsw = (unsigned short*)d_ws;  // 512 KB swizzled V (hi+lo)

  build_u<<<64, 256, 0, stream>>>(th1, th2, th3, Vsw);
  pqc_main<<<512, 512, 0, stream>>>(x, Vsw, out);
}

// Round 9
// 114.985 us; speedup vs baseline: 2.1016x; 1.0250x over previous
//
#include <hip/hip_runtime.h>
#include <math.h>

// PQC autoencoder. out = g(U x), U = fixed 256x256 unitary from thetas
// (input normalization cancels: y/||y|| scale-invariant in x).
// Kernel A (build_u, ~2 us): fused-gate statevector sim -> V = [Re U; Im U]
//   split-bf16 hi/lo in MFMA-B-fragment stream order (validated R2-R8).
// Kernel B (pqc_main): 2-TERM split-bf16 MFMA GEMM (32768 x 512 x 256):
//   psi ~= A_hi*(B_hi + B_lo), A_hi = RNE bf16 of x (al*bh term dropped;
//   adds ~2e-3 absmax vs 19.6e-3 threshold). R8 shape kept: 64 rows/block,
//   512 thr, grid 512 -> 2 blocks/CU; conflict-free swizzled staging (hi
//   only, 32 KB), DPP Walsh epilogue, unroll-1 k-loop.

#define DEV __device__ __forceinline__

typedef __attribute__((ext_vector_type(8))) short short8;   // 8 bf16
typedef __attribute__((ext_vector_type(4))) float f32x4;

DEV float2 cmul(float2 a, float2 b) {
  return make_float2(a.x * b.x - a.y * b.y, a.x * b.y + a.y * b.x);
}
DEV float2 cadd(float2 a, float2 b) { return make_float2(a.x + b.x, a.y + b.y); }

DEV unsigned short bf_rne(float v) {
  unsigned u = __float_as_uint(v);
  return (unsigned short)((u + 0x7FFFu + ((u >> 16) & 1u)) >> 16);
}

// ---- DPP cross-lane (VALU pipe, rows of 16) ------------------------------
template <int CTRL>
DEV float dppf(float v) {
  return __int_as_float(__builtin_amdgcn_mov_dpp(__float_as_int(v), CTRL, 0xF, 0xF, true));
}
DEV float px1(float v) { return dppf<0xB1>(v); }                  // lane^1
DEV float px2(float v) { return dppf<0x4E>(v); }                  // lane^2
DEV float px4(float v) { return dppf<0x1B>(dppf<0x141>(v)); }     // ^7 then ^3 = ^4
DEV float px8(float v) { return dppf<0x141>(dppf<0x140>(v)); }    // ^15 then ^7 = ^8
DEV float fsgn(float v, int m) { return __int_as_float(__float_as_int(v) ^ m); }

// ---------------------------------------------------------------------------
// Kernel A (unchanged, validated)
// ---------------------------------------------------------------------------

struct Psi4 { float re[4]; float im[4]; };
// amplitude a = (r<<6)|lane; bit q of a: q<6 -> lane bit q; q==6 -> r&1; q==7 -> r>>1

template <int Q>
DEV void pair_gate(Psi4& s, const float2* __restrict__ Mlo,
                   const float2* __restrict__ Mhi, int lane) {
  const int b0 = (lane >> Q) & 1, b1 = (lane >> (Q + 1)) & 1;
  float2 lo_d = Mlo[b0 * 2 + b0];
  float2 lo_o = Mlo[b0 * 2 + (b0 ^ 1)];
  float2 hi_d = Mhi[b1 * 2 + b1];
  float2 hi_o = Mhi[b1 * 2 + (b1 ^ 1)];
  float2 c00 = cmul(hi_d, lo_d);
  float2 c01 = cmul(hi_d, lo_o);
  float2 c10 = cmul(hi_o, lo_d);
  float2 c11 = cmul(hi_o, lo_o);
  const int m0 = 1 << Q, m1 = 2 << Q;
#pragma unroll
  for (int r = 0; r < 4; ++r) {
    float ar = s.re[r], ai = s.im[r];
    float p0r = __shfl_xor(ar, m0, 64), p0i = __shfl_xor(ai, m0, 64);
    float p1r = __shfl_xor(ar, m1, 64), p1i = __shfl_xor(ai, m1, 64);
    float p2r = __shfl_xor(ar, m0 | m1, 64), p2i = __shfl_xor(ai, m0 | m1, 64);
    float nr = c00.x * ar - c00.y * ai + c01.x * p0r - c01.y * p0i
             + c10.x * p1r - c10.y * p1i + c11.x * p2r - c11.y * p2i;
    float ni = c00.x * ai + c00.y * ar + c01.x * p0i + c01.y * p0r
             + c10.x * p1i + c10.y * p1r + c11.x * p2i + c11.y * p2r;
    s.re[r] = nr; s.im[r] = ni;
  }
}

DEV void regpair_gate(Psi4& s, const float2* __restrict__ Mlo,
                      const float2* __restrict__ Mhi) {
  float nr[4], ni[4];
#pragma unroll
  for (int r = 0; r < 4; ++r) {
    const int b0 = r & 1, b1 = (r >> 1) & 1;
    float2 c00 = cmul(Mhi[b1 * 2 + b1], Mlo[b0 * 2 + b0]);
    float2 c01 = cmul(Mhi[b1 * 2 + b1], Mlo[b0 * 2 + (b0 ^ 1)]);
    float2 c10 = cmul(Mhi[b1 * 2 + (b1 ^ 1)], Mlo[b0 * 2 + b0]);
    float2 c11 = cmul(Mhi[b1 * 2 + (b1 ^ 1)], Mlo[b0 * 2 + (b0 ^ 1)]);
    nr[r] = c00.x * s.re[r] - c00.y * s.im[r]
          + c01.x * s.re[r ^ 1] - c01.y * s.im[r ^ 1]
          + c10.x * s.re[r ^ 2] - c10.y * s.im[r ^ 2]
          + c11.x * s.re[r ^ 3] - c11.y * s.im[r ^ 3];
    ni[r] = c00.x * s.im[r] + c00.y * s.re[r]
          + c01.x * s.im[r ^ 1] + c01.y * s.re[r ^ 1]
          + c10.x * s.im[r ^ 2] + c10.y * s.re[r ^ 2]
          + c11.x * s.im[r ^ 3] + c11.y * s.re[r ^ 3];
  }
#pragma unroll
  for (int r = 0; r < 4; ++r) { s.re[r] = nr[r]; s.im[r] = ni[r]; }
}

DEV void reg0_gate(Psi4& s, const float2* __restrict__ M) {
  float nr[4], ni[4];
#pragma unroll
  for (int r = 0; r < 4; ++r) {
    const int b = r & 1;
    float2 d = M[b * 2 + b], o = M[b * 2 + (b ^ 1)];
    nr[r] = d.x * s.re[r] - d.y * s.im[r] + o.x * s.re[r ^ 1] - o.y * s.im[r ^ 1];
    ni[r] = d.x * s.im[r] + d.y * s.re[r] + o.x * s.im[r ^ 1] + o.y * s.re[r ^ 1];
  }
#pragma unroll
  for (int r = 0; r < 4; ++r) { s.re[r] = nr[r]; s.im[r] = ni[r]; }
}

template <bool FULL8>
DEV void perm_cx(Psi4& s, int lane) {
  const int slane = (lane ^ (lane << 1)) & 63;
  const bool L5 = ((lane >> 5) & 1) != 0;
  float nr[4], ni[4];
#pragma unroll
  for (int r = 0; r < 4; ++r) {
    const int r0 = r & 1, r1 = (r >> 1) & 1;
    const int hiBit = FULL8 ? (r1 ^ r0) : r1;
    const int sA = (hiBit << 1) | r0;
    const int sB = sA ^ 1;
    float aRe = __shfl(s.re[sA], slane, 64);
    float aIm = __shfl(s.im[sA], slane, 64);
    float bRe = __shfl(s.re[sB], slane, 64);
    float bIm = __shfl(s.im[sB], slane, 64);
    nr[r] = L5 ? bRe : aRe;
    ni[r] = L5 ? bIm : aIm;
  }
#pragma unroll
  for (int r = 0; r < 4; ++r) { s.re[r] = nr[r]; s.im[r] = ni[r]; }
}

template <int NQ>
DEV void ansatz_f(Psi4& s, const float2* __restrict__ Mg, int lane) {
#pragma unroll
  for (int d = 0; d < 2; ++d) {
    const float2* Md = Mg + d * NQ * 4;
    pair_gate<0>(s, Md + 0, Md + 4, lane);
    pair_gate<2>(s, Md + 8, Md + 12, lane);
    pair_gate<4>(s, Md + 16, Md + 20, lane);
    if (NQ == 8) regpair_gate(s, Md + 24, Md + 28);
    else reg0_gate(s, Md + 24);
    perm_cx<NQ == 8>(s, lane);
  }
}

// Vsw layout (validated): idx = k*32768 + g*1024 + hl*512 + L*8 + jj
// g = w*8 + t, t in [0,4) re tiles / [4,8) im tiles; L = quad*16 + (n&15)
DEV void store_v(unsigned short* __restrict__ Vsw, int n, int kk, float v) {
  int k = kk >> 5, rem = kk & 31, quad = rem >> 3, jj = rem & 7;
  int nn = n & 255;
  int w = (nn >> 6) & 3, t = (nn >> 4) & 3, cl = nn & 15;
  int g = w * 8 + ((n >= 256) ? 4 + t : t);
  int L = quad * 16 + cl;
  unsigned short hi = bf_rne(v);
  float hif = __uint_as_float(((unsigned)hi) << 16);
  unsigned short lo = bf_rne(v - hif);
  size_t base = (size_t)k * 32768 + (size_t)g * 1024 + (size_t)L * 8 + jj;
  Vsw[base] = hi;
  Vsw[base + 512] = lo;
}

__global__ void build_u(const float* __restrict__ th1, const float* __restrict__ th2,
                        const float* __restrict__ th3, unsigned short* __restrict__ Vsw) {
  __shared__ float2 Mg[46 * 4];
  const int tid = threadIdx.x;
  if (tid < 46) {
    float thx, thy, thz;
    if (tid < 16)      { thx = th1[tid * 3]; thy = th1[tid * 3 + 1]; thz = th1[tid * 3 + 2]; }
    else if (tid < 30) { int u = (tid - 16) * 3; thx = th2[u]; thy = th2[u + 1]; thz = th2[u + 2]; }
    else               { int u = (tid - 30) * 3; thx = th3[u]; thy = th3[u + 1]; thz = th3[u + 2]; }
    float sx, cx_, sy, cy_, sz, cz_;
    sincosf(0.5f * thx, &sx, &cx_);
    sincosf(0.5f * thy, &sy, &cy_);
    sincosf(0.5f * thz, &sz, &cz_);
    float2 rx[4] = {{cx_, 0}, {0, -sx}, {0, -sx}, {cx_, 0}};
    float2 ry[4] = {{cy_, 0}, {-sy, 0}, {sy, 0}, {cy_, 0}};
    float2 A0 = cadd(cmul(ry[0], rx[0]), cmul(ry[1], rx[2]));
    float2 A1 = cadd(cmul(ry[0], rx[1]), cmul(ry[1], rx[3]));
    float2 A2 = cadd(cmul(ry[2], rx[0]), cmul(ry[3], rx[2]));
    float2 A3 = cadd(cmul(ry[2], rx[1]), cmul(ry[3], rx[3]));
    float2 ezm = make_float2(cz_, -sz), ezp = make_float2(cz_, sz);
    Mg[tid * 4 + 0] = cmul(ezm, A0);
    Mg[tid * 4 + 1] = cmul(ezm, A1);
    Mg[tid * 4 + 2] = cmul(ezp, A2);
    Mg[tid * 4 + 3] = cmul(ezp, A3);
  }
  __syncthreads();

  const int lane = tid & 63;
  const int j = blockIdx.x * 4 + (tid >> 6);
  Psi4 s;
#pragma unroll
  for (int r = 0; r < 4; ++r) {
    int a = (r << 6) | lane;
    s.re[r] = (a == j) ? 1.f : 0.f;
    s.im[r] = 0.f;
  }
  ansatz_f<8>(s, Mg, lane);
  ansatz_f<7>(s, Mg + 16 * 4, lane);
  ansatz_f<8>(s, Mg + 30 * 4, lane);
#pragma unroll
  for (int r = 0; r < 4; ++r) {
    int a = (r << 6) | lane;
    store_v(Vsw, a, j, s.re[r]);
    store_v(Vsw, a + 256, j, s.im[r]);
  }
}

// ---------------------------------------------------------------------------
// Kernel B: 512 blocks x 512 threads (8 waves), 64 rows/block, 2 blocks/CU.
// Wave ww: w = ww>>1 (amp slice), half = ww&1 (re|im tiles), n=64 cols/wave;
// mt = 4 row-tiles -> acc = 4x4 f32x4 = 64 AGPR. 2-term: A_hi (RNE) only.
// A2 col slot swizzle (cc ^ 2*quad) on write AND read: conflict-free.
// ---------------------------------------------------------------------------

__global__ __launch_bounds__(512, 4) void pqc_main(const float* __restrict__ x,
                                                   const unsigned short* __restrict__ Vsw,
                                                   float* __restrict__ out) {
  const int tid = threadIdx.x;
  const int ww = tid >> 6;
  const int w = ww >> 1;        // amp slice: i in [w*64, w*64+64)
  const int half = ww & 1;      // 0 = re tiles, 1 = im tiles
  const int L = tid & 63;
  const int quad = L >> 4;
  const int c = L & 15;
  const int row0 = blockIdx.x * 64;

  // A2[k][mt][slot*8 + j], slot = quad*16 + (cc ^ 2*quad)  (hi only, 32 KB)
  __shared__ unsigned short A2[8][4][512];
  __shared__ float ys[64][8];
  __shared__ float invn[64];
  float* part = (float*)&A2[0][0][0];        // overlay after k-loop (16 KB)

  // ---- stage A: 64 rows x 256 cols; lane covers 8 rows (r8) x wave k-group.
  {
    const float4* xsrc = (const float4*)(x + (size_t)row0 * 256);
    const int r8 = L & 7;            // row within group of 8
    const int kf = L >> 3;           // fine col 0..7 within wave's k-group
    const int q = kf >> 1;
    const int jj0 = (kf & 1) * 4;
#pragma unroll
    for (int i = 0; i < 8; ++i) {
      int row = i * 8 + r8;
      float4 f = xsrc[row * 64 + ww * 8 + kf];
      ushort4 h;
      h.x = bf_rne(f.x); h.y = bf_rne(f.y); h.z = bf_rne(f.z); h.w = bf_rne(f.w);
      int mt = row >> 4, cc = row & 15;
      int idx = (q * 16 + (cc ^ (q << 1))) * 8 + jj0;
      *(ushort4*)&A2[ww][mt][idx] = h;
    }
  }
  __syncthreads();

  // ---- MFMA K-loop (2 terms: ah*bh + ah*bl)
  f32x4 acc[4][4];
#pragma unroll
  for (int mt = 0; mt < 4; ++mt)
#pragma unroll
    for (int tt = 0; tt < 4; ++tt) acc[mt][tt] = (f32x4){0.f, 0.f, 0.f, 0.f};

  const unsigned short* pb = Vsw + (size_t)w * 8192 + (size_t)half * 4096 + (size_t)L * 8;
  const int sL8 = (quad * 16 + (c ^ (quad << 1))) * 8;   // swizzled A slot

#pragma unroll 1   // cap unroll: pipeline 1 k-iter deep, keep regs in budget
  for (int k = 0; k < 8; ++k) {
    short8 ah[4];
#pragma unroll
    for (int mt = 0; mt < 4; ++mt)
      ah[mt] = *(const short8*)&A2[k][mt][sL8];
    const unsigned short* pk = pb + (size_t)k * 32768;
#pragma unroll
    for (int tt = 0; tt < 4; ++tt) {
      short8 bh = *(const short8*)(pk + tt * 1024);
      short8 bl = *(const short8*)(pk + tt * 1024 + 512);
#pragma unroll
      for (int mt = 0; mt < 4; ++mt)
        acc[mt][tt] = __builtin_amdgcn_mfma_f32_16x16x32_bf16(ah[mt], bh, acc[mt][tt], 0, 0, 0);
#pragma unroll
      for (int mt = 0; mt < 4; ++mt)
        acc[mt][tt] = __builtin_amdgcn_mfma_f32_16x16x32_bf16(ah[mt], bl, acc[mt][tt], 0, 0, 0);
    }
  }
  __syncthreads();   // A2 dead; part overlay becomes valid

  // ---- epilogue: partial probs (re^2 or im^2) -> signed Walsh via DPP.
  // D layout: row m = mt*16 + quad*4 + r, col = c; tile tt covers amps
  // i = w*64 + tt*16 + c.
  const int m1 = (c & 1) << 31;
  const int m2 = (c & 2) << 30;
  const int m4 = (c & 4) << 29;
  const int m8 = (c & 8) << 28;
#pragma unroll
  for (int mt = 0; mt < 4; ++mt) {
#pragma unroll
    for (int r = 0; r < 4; ++r) {
      float p0 = acc[mt][0][r] * acc[mt][0][r];
      float p1 = acc[mt][1][r] * acc[mt][1][r];
      float p2 = acc[mt][2][r] * acc[mt][2][r];
      float p3 = acc[mt][3][r] * acc[mt][3][r];
      float s01 = p0 + p1, s23 = p2 + p3;
      float av = s01 + s23;               // -> j=0,1,4..7
      float bv = s01 - s23;               // sign bit5 (tt>>1) -> j=2
      float cv = (p0 - p1) + (p2 - p3);   // sign bit4 (tt&1) -> j=3
      av = px1(av) + fsgn(av, m1);
      bv += px1(bv);  cv += px1(cv);
      av = px2(av) + fsgn(av, m2);
      bv += px2(bv);  cv += px2(cv);
      av = px4(av) + fsgn(av, m4);
      bv += px4(bv);  cv += px4(cv);
      av = px8(av) + fsgn(av, m8);
      bv += px8(bv);  cv += px8(cv);
      int m = mt * 16 + quad * 4 + r;
      float* pm = part + (ww * 64 + m) * 8;
      if (c == 0) {
        pm[0] = ((w >> 1) & 1) ? -av : av;  // j=0: bit7(i)
        pm[1] = (w & 1) ? -av : av;         // j=1: bit6(i)
        pm[2] = bv;
        pm[3] = cv;
      } else if (c == 8) pm[4] = av;   // j=4: bit3
      else if (c == 4) pm[5] = av;     // j=5: bit2
      else if (c == 2) pm[6] = av;     // j=6: bit1
      else if (c == 1) pm[7] = av;     // j=7: bit0
    }
  }
  __syncthreads();

  {
    int m = tid >> 3, jj = tid & 7;
    float acc_y = 0.f;
#pragma unroll
    for (int p = 0; p < 8; ++p) acc_y += part[(p * 64 + m) * 8 + jj];
    ys[m][jj] = acc_y;
  }
  __syncthreads();

  if (tid < 64) {
    float n = 0.f;
#pragma unroll
    for (int jj = 0; jj < 8; ++jj) { float v = ys[tid][jj]; n = fmaf(v, v, n); }
    n = sqrtf(n);
    invn[tid] = (n == 0.f) ? 0.f : 1.f / n;
  }
  __syncthreads();

  // ---- write out: 64 rows x 64 float4 = 4096 float4, 8 per thread
  float4* o4 = (float4*)(out + (size_t)row0 * 256);
#pragma unroll
  for (int i = 0; i < 8; ++i) {
    int e = i * 512 + tid;
    int row = e >> 6;
    int c4 = (e & 63) * 4;
    float4 v = make_float4(0.f, 0.f, 0.f, 0.f);
    if (c4 < 8) {
      float iv = invn[row];
      float t0 = ys[row][c4 + 0] * iv;
      float t1 = ys[row][c4 + 1] * iv;
      float t2 = ys[row][c4 + 2] * iv;
      float t3 = ys[row][c4 + 3] * iv;
      v = make_float4(t0 * t0, t1 * t1, t2 * t2, t3 * t3);
    }
    o4[e] = v;
  }
}

extern "C" void kernel_launch(void* const* d_in, const int* in_sizes, int n_in,
                              void* d_out, int out_size, void* d_ws, size_t ws_size,
                              hipStream_t stream) {
  const float* x = (const float*)d_in[0];
  const float* th1 = (const float*)d_in[1];
  const float* th2 = (const float*)d_in[2];
  const float* th3 = (const float*)d_in[3];
  float* out = (float*)d_out;
  unsigned short* Vsw = (unsigned short*)d_ws;  // 512 KB swizzled V (hi+lo)

  build_u<<<64, 256, 0, stream>>>(th1, th2, th3, Vsw);
  pqc_main<<<512, 512, 0, stream>>>(x, Vsw, out);
}

// Round 10
// 108.869 us; speedup vs baseline: 2.2197x; 1.0562x over previous
//
#include <hip/hip_runtime.h>
#include <math.h>

// PQC autoencoder. out = g(U x), U = fixed 256x256 unitary from thetas
// (input normalization cancels: y/||y|| scale-invariant in x).
// Kernel A (build_u, ~2 us): fused-gate statevector sim -> V = [Re U; Im U]
//   as RNE bf16 (single term) in MFMA-B-fragment stream order.
// Kernel B (pqc_main): SINGLE-TERM bf16 MFMA GEMM (32768 x 512 x 256):
//   psi ~= A_hi * B_hi, both RNE-rounded (R9 measured: each dropped residual
//   term adds ~4e-3 absmax; threshold 19.6e-3). B stream halves to 256 KB
//   (L2/L1-resident), MFMA floor ~3.4 us. R8 shape: 64 rows/block, 512 thr,
//   grid 512 -> 2 blocks/CU; conflict-free swizzled staging, DPP Walsh
//   epilogue, unroll-1 k-loop.

#define DEV __device__ __forceinline__

typedef __attribute__((ext_vector_type(8))) short short8;   // 8 bf16
typedef __attribute__((ext_vector_type(4))) float f32x4;

DEV float2 cmul(float2 a, float2 b) {
  return make_float2(a.x * b.x - a.y * b.y, a.x * b.y + a.y * b.x);
}
DEV float2 cadd(float2 a, float2 b) { return make_float2(a.x + b.x, a.y + b.y); }

DEV unsigned short bf_rne(float v) {
  unsigned u = __float_as_uint(v);
  return (unsigned short)((u + 0x7FFFu + ((u >> 16) & 1u)) >> 16);
}

// ---- DPP cross-lane (VALU pipe, rows of 16) ------------------------------
template <int CTRL>
DEV float dppf(float v) {
  return __int_as_float(__builtin_amdgcn_mov_dpp(__float_as_int(v), CTRL, 0xF, 0xF, true));
}
DEV float px1(float v) { return dppf<0xB1>(v); }                  // lane^1
DEV float px2(float v) { return dppf<0x4E>(v); }                  // lane^2
DEV float px4(float v) { return dppf<0x1B>(dppf<0x141>(v)); }     // ^7 then ^3 = ^4
DEV float px8(float v) { return dppf<0x141>(dppf<0x140>(v)); }    // ^15 then ^7 = ^8
DEV float fsgn(float v, int m) { return __int_as_float(__float_as_int(v) ^ m); }

// ---------------------------------------------------------------------------
// Kernel A (gate math unchanged, validated R2-R9)
// ---------------------------------------------------------------------------

struct Psi4 { float re[4]; float im[4]; };
// amplitude a = (r<<6)|lane; bit q of a: q<6 -> lane bit q; q==6 -> r&1; q==7 -> r>>1

template <int Q>
DEV void pair_gate(Psi4& s, const float2* __restrict__ Mlo,
                   const float2* __restrict__ Mhi, int lane) {
  const int b0 = (lane >> Q) & 1, b1 = (lane >> (Q + 1)) & 1;
  float2 lo_d = Mlo[b0 * 2 + b0];
  float2 lo_o = Mlo[b0 * 2 + (b0 ^ 1)];
  float2 hi_d = Mhi[b1 * 2 + b1];
  float2 hi_o = Mhi[b1 * 2 + (b1 ^ 1)];
  float2 c00 = cmul(hi_d, lo_d);
  float2 c01 = cmul(hi_d, lo_o);
  float2 c10 = cmul(hi_o, lo_d);
  float2 c11 = cmul(hi_o, lo_o);
  const int m0 = 1 << Q, m1 = 2 << Q;
#pragma unroll
  for (int r = 0; r < 4; ++r) {
    float ar = s.re[r], ai = s.im[r];
    float p0r = __shfl_xor(ar, m0, 64), p0i = __shfl_xor(ai, m0, 64);
    float p1r = __shfl_xor(ar, m1, 64), p1i = __shfl_xor(ai, m1, 64);
    float p2r = __shfl_xor(ar, m0 | m1, 64), p2i = __shfl_xor(ai, m0 | m1, 64);
    float nr = c00.x * ar - c00.y * ai + c01.x * p0r - c01.y * p0i
             + c10.x * p1r - c10.y * p1i + c11.x * p2r - c11.y * p2i;
    float ni = c00.x * ai + c00.y * ar + c01.x * p0i + c01.y * p0r
             + c10.x * p1i + c10.y * p1r + c11.x * p2i + c11.y * p2r;
    s.re[r] = nr; s.im[r] = ni;
  }
}

DEV void regpair_gate(Psi4& s, const float2* __restrict__ Mlo,
                      const float2* __restrict__ Mhi) {
  float nr[4], ni[4];
#pragma unroll
  for (int r = 0; r < 4; ++r) {
    const int b0 = r & 1, b1 = (r >> 1) & 1;
    float2 c00 = cmul(Mhi[b1 * 2 + b1], Mlo[b0 * 2 + b0]);
    float2 c01 = cmul(Mhi[b1 * 2 + b1], Mlo[b0 * 2 + (b0 ^ 1)]);
    float2 c10 = cmul(Mhi[b1 * 2 + (b1 ^ 1)], Mlo[b0 * 2 + b0]);
    float2 c11 = cmul(Mhi[b1 * 2 + (b1 ^ 1)], Mlo[b0 * 2 + (b0 ^ 1)]);
    nr[r] = c00.x * s.re[r] - c00.y * s.im[r]
          + c01.x * s.re[r ^ 1] - c01.y * s.im[r ^ 1]
          + c10.x * s.re[r ^ 2] - c10.y * s.im[r ^ 2]
          + c11.x * s.re[r ^ 3] - c11.y * s.im[r ^ 3];
    ni[r] = c00.x * s.im[r] + c00.y * s.re[r]
          + c01.x * s.im[r ^ 1] + c01.y * s.re[r ^ 1]
          + c10.x * s.im[r ^ 2] + c10.y * s.re[r ^ 2]
          + c11.x * s.im[r ^ 3] + c11.y * s.re[r ^ 3];
  }
#pragma unroll
  for (int r = 0; r < 4; ++r) { s.re[r] = nr[r]; s.im[r] = ni[r]; }
}

DEV void reg0_gate(Psi4& s, const float2* __restrict__ M) {
  float nr[4], ni[4];
#pragma unroll
  for (int r = 0; r < 4; ++r) {
    const int b = r & 1;
    float2 d = M[b * 2 + b], o = M[b * 2 + (b ^ 1)];
    nr[r] = d.x * s.re[r] - d.y * s.im[r] + o.x * s.re[r ^ 1] - o.y * s.im[r ^ 1];
    ni[r] = d.x * s.im[r] + d.y * s.re[r] + o.x * s.im[r ^ 1] + o.y * s.re[r ^ 1];
  }
#pragma unroll
  for (int r = 0; r < 4; ++r) { s.re[r] = nr[r]; s.im[r] = ni[r]; }
}

template <bool FULL8>
DEV void perm_cx(Psi4& s, int lane) {
  const int slane = (lane ^ (lane << 1)) & 63;
  const bool L5 = ((lane >> 5) & 1) != 0;
  float nr[4], ni[4];
#pragma unroll
  for (int r = 0; r < 4; ++r) {
    const int r0 = r & 1, r1 = (r >> 1) & 1;
    const int hiBit = FULL8 ? (r1 ^ r0) : r1;
    const int sA = (hiBit << 1) | r0;
    const int sB = sA ^ 1;
    float aRe = __shfl(s.re[sA], slane, 64);
    float aIm = __shfl(s.im[sA], slane, 64);
    float bRe = __shfl(s.re[sB], slane, 64);
    float bIm = __shfl(s.im[sB], slane, 64);
    nr[r] = L5 ? bRe : aRe;
    ni[r] = L5 ? bIm : aIm;
  }
#pragma unroll
  for (int r = 0; r < 4; ++r) { s.re[r] = nr[r]; s.im[r] = ni[r]; }
}

template <int NQ>
DEV void ansatz_f(Psi4& s, const float2* __restrict__ Mg, int lane) {
#pragma unroll
  for (int d = 0; d < 2; ++d) {
    const float2* Md = Mg + d * NQ * 4;
    pair_gate<0>(s, Md + 0, Md + 4, lane);
    pair_gate<2>(s, Md + 8, Md + 12, lane);
    pair_gate<4>(s, Md + 16, Md + 20, lane);
    if (NQ == 8) regpair_gate(s, Md + 24, Md + 28);
    else reg0_gate(s, Md + 24);
    perm_cx<NQ == 8>(s, lane);
  }
}

// Vsw layout (single-term): idx = k*16384 + g*512 + L*8 + jj
// g = w*8 + half*4 + t; half=0 re tiles, 1 im tiles; L = quad*16 + (n&15)
DEV void store_v(unsigned short* __restrict__ Vsw, int n, int kk, float v) {
  int k = kk >> 5, rem = kk & 31, quad = rem >> 3, jj = rem & 7;
  int nn = n & 255;
  int w = (nn >> 6) & 3, t = (nn >> 4) & 3, cl = nn & 15;
  int g = w * 8 + ((n >= 256) ? 4 + t : t);
  int L = quad * 16 + cl;
  size_t base = (size_t)k * 16384 + (size_t)g * 512 + (size_t)L * 8 + jj;
  Vsw[base] = bf_rne(v);
}

__global__ void build_u(const float* __restrict__ th1, const float* __restrict__ th2,
                        const float* __restrict__ th3, unsigned short* __restrict__ Vsw) {
  __shared__ float2 Mg[46 * 4];
  const int tid = threadIdx.x;
  if (tid < 46) {
    float thx, thy, thz;
    if (tid < 16)      { thx = th1[tid * 3]; thy = th1[tid * 3 + 1]; thz = th1[tid * 3 + 2]; }
    else if (tid < 30) { int u = (tid - 16) * 3; thx = th2[u]; thy = th2[u + 1]; thz = th2[u + 2]; }
    else               { int u = (tid - 30) * 3; thx = th3[u]; thy = th3[u + 1]; thz = th3[u + 2]; }
    float sx, cx_, sy, cy_, sz, cz_;
    sincosf(0.5f * thx, &sx, &cx_);
    sincosf(0.5f * thy, &sy, &cy_);
    sincosf(0.5f * thz, &sz, &cz_);
    float2 rx[4] = {{cx_, 0}, {0, -sx}, {0, -sx}, {cx_, 0}};
    float2 ry[4] = {{cy_, 0}, {-sy, 0}, {sy, 0}, {cy_, 0}};
    float2 A0 = cadd(cmul(ry[0], rx[0]), cmul(ry[1], rx[2]));
    float2 A1 = cadd(cmul(ry[0], rx[1]), cmul(ry[1], rx[3]));
    float2 A2 = cadd(cmul(ry[2], rx[0]), cmul(ry[3], rx[2]));
    float2 A3 = cadd(cmul(ry[2], rx[1]), cmul(ry[3], rx[3]));
    float2 ezm = make_float2(cz_, -sz), ezp = make_float2(cz_, sz);
    Mg[tid * 4 + 0] = cmul(ezm, A0);
    Mg[tid * 4 + 1] = cmul(ezm, A1);
    Mg[tid * 4 + 2] = cmul(ezp, A2);
    Mg[tid * 4 + 3] = cmul(ezp, A3);
  }
  __syncthreads();

  const int lane = tid & 63;
  const int j = blockIdx.x * 4 + (tid >> 6);
  Psi4 s;
#pragma unroll
  for (int r = 0; r < 4; ++r) {
    int a = (r << 6) | lane;
    s.re[r] = (a == j) ? 1.f : 0.f;
    s.im[r] = 0.f;
  }
  ansatz_f<8>(s, Mg, lane);
  ansatz_f<7>(s, Mg + 16 * 4, lane);
  ansatz_f<8>(s, Mg + 30 * 4, lane);
#pragma unroll
  for (int r = 0; r < 4; ++r) {
    int a = (r << 6) | lane;
    store_v(Vsw, a, j, s.re[r]);
    store_v(Vsw, a + 256, j, s.im[r]);
  }
}

// ---------------------------------------------------------------------------
// Kernel B: 512 blocks x 512 threads (8 waves), 64 rows/block, 2 blocks/CU.
// Wave ww: w = ww>>1 (amp slice), half = ww&1 (re|im tiles), n=64 cols/wave;
// mt = 4 row-tiles -> acc = 4x4 f32x4 = 64 AGPR. Single term: ah*bh.
// A2 col slot swizzle (cc ^ 2*quad) on write AND read: conflict-free.
// ---------------------------------------------------------------------------

__global__ __launch_bounds__(512, 4) void pqc_main(const float* __restrict__ x,
                                                   const unsigned short* __restrict__ Vsw,
                                                   float* __restrict__ out) {
  const int tid = threadIdx.x;
  const int ww = tid >> 6;
  const int w = ww >> 1;        // amp slice: i in [w*64, w*64+64)
  const int half = ww & 1;      // 0 = re tiles, 1 = im tiles
  const int L = tid & 63;
  const int quad = L >> 4;
  const int c = L & 15;
  const int row0 = blockIdx.x * 64;

  // A2[k][mt][slot*8 + j], slot = quad*16 + (cc ^ 2*quad)  (hi only, 32 KB)
  __shared__ unsigned short A2[8][4][512];
  __shared__ float ys[64][8];
  __shared__ float invn[64];
  float* part = (float*)&A2[0][0][0];        // overlay after k-loop (16 KB)

  // ---- stage A: 64 rows x 256 cols; lane covers 8 rows (r8) x wave k-group.
  {
    const float4* xsrc = (const float4*)(x + (size_t)row0 * 256);
    const int r8 = L & 7;            // row within group of 8
    const int kf = L >> 3;           // fine col 0..7 within wave's k-group
    const int q = kf >> 1;
    const int jj0 = (kf & 1) * 4;
#pragma unroll
    for (int i = 0; i < 8; ++i) {
      int row = i * 8 + r8;
      float4 f = xsrc[row * 64 + ww * 8 + kf];
      ushort4 h;
      h.x = bf_rne(f.x); h.y = bf_rne(f.y); h.z = bf_rne(f.z); h.w = bf_rne(f.w);
      int mt = row >> 4, cc = row & 15;
      int idx = (q * 16 + (cc ^ (q << 1))) * 8 + jj0;
      *(ushort4*)&A2[ww][mt][idx] = h;
    }
  }
  __syncthreads();

  // ---- MFMA K-loop (single term: ah*bh)
  f32x4 acc[4][4];
#pragma unroll
  for (int mt = 0; mt < 4; ++mt)
#pragma unroll
    for (int tt = 0; tt < 4; ++tt) acc[mt][tt] = (f32x4){0.f, 0.f, 0.f, 0.f};

  const unsigned short* pb = Vsw + (size_t)w * 4096 + (size_t)half * 2048 + (size_t)L * 8;
  const int sL8 = (quad * 16 + (c ^ (quad << 1))) * 8;   // swizzled A slot

#pragma unroll 1   // cap unroll: pipeline 1 k-iter deep, keep regs in budget
  for (int k = 0; k < 8; ++k) {
    short8 ah[4];
#pragma unroll
    for (int mt = 0; mt < 4; ++mt)
      ah[mt] = *(const short8*)&A2[k][mt][sL8];
    const unsigned short* pk = pb + (size_t)k * 16384;
#pragma unroll
    for (int tt = 0; tt < 4; ++tt) {
      short8 bh = *(const short8*)(pk + tt * 512);
#pragma unroll
      for (int mt = 0; mt < 4; ++mt)
        acc[mt][tt] = __builtin_amdgcn_mfma_f32_16x16x32_bf16(ah[mt], bh, acc[mt][tt], 0, 0, 0);
    }
  }
  __syncthreads();   // A2 dead; part overlay becomes valid

  // ---- epilogue: partial probs (re^2 or im^2) -> signed Walsh via DPP.
  // D layout: row m = mt*16 + quad*4 + r, col = c; tile tt covers amps
  // i = w*64 + tt*16 + c.
  const int m1 = (c & 1) << 31;
  const int m2 = (c & 2) << 30;
  const int m4 = (c & 4) << 29;
  const int m8 = (c & 8) << 28;
#pragma unroll
  for (int mt = 0; mt < 4; ++mt) {
#pragma unroll
    for (int r = 0; r < 4; ++r) {
      float p0 = acc[mt][0][r] * acc[mt][0][r];
      float p1 = acc[mt][1][r] * acc[mt][1][r];
      float p2 = acc[mt][2][r] * acc[mt][2][r];
      float p3 = acc[mt][3][r] * acc[mt][3][r];
      float s01 = p0 + p1, s23 = p2 + p3;
      float av = s01 + s23;               // -> j=0,1,4..7
      float bv = s01 - s23;               // sign bit5 (tt>>1) -> j=2
      float cv = (p0 - p1) + (p2 - p3);   // sign bit4 (tt&1) -> j=3
      av = px1(av) + fsgn(av, m1);
      bv += px1(bv);  cv += px1(cv);
      av = px2(av) + fsgn(av, m2);
      bv += px2(bv);  cv += px2(cv);
      av = px4(av) + fsgn(av, m4);
      bv += px4(bv);  cv += px4(cv);
      av = px8(av) + fsgn(av, m8);
      bv += px8(bv);  cv += px8(cv);
      int m = mt * 16 + quad * 4 + r;
      float* pm = part + (ww * 64 + m) * 8;
      if (c == 0) {
        pm[0] = ((w >> 1) & 1) ? -av : av;  // j=0: bit7(i)
        pm[1] = (w & 1) ? -av : av;         // j=1: bit6(i)
        pm[2] = bv;
        pm[3] = cv;
      } else if (c == 8) pm[4] = av;   // j=4: bit3
      else if (c == 4) pm[5] = av;     // j=5: bit2
      else if (c == 2) pm[6] = av;     // j=6: bit1
      else if (c == 1) pm[7] = av;     // j=7: bit0
    }
  }
  __syncthreads();

  {
    int m = tid >> 3, jj = tid & 7;
    float acc_y = 0.f;
#pragma unroll
    for (int p = 0; p < 8; ++p) acc_y += part[(p * 64 + m) * 8 + jj];
    ys[m][jj] = acc_y;
  }
  __syncthreads();

  if (tid < 64) {
    float n = 0.f;
#pragma unroll
    for (int jj = 0; jj < 8; ++jj) { float v = ys[tid][jj]; n = fmaf(v, v, n); }
    n = sqrtf(n);
    invn[tid] = (n == 0.f) ? 0.f : 1.f / n;
  }
  __syncthreads();

  // ---- write out: 64 rows x 64 float4 = 4096 float4, 8 per thread
  float4* o4 = (float4*)(out + (size_t)row0 * 256);
#pragma unroll
  for (int i = 0; i < 8; ++i) {
    int e = i * 512 + tid;
    int row = e >> 6;
    int c4 = (e & 63) * 4;
    float4 v = make_float4(0.f, 0.f, 0.f, 0.f);
    if (c4 < 8) {
      float iv = invn[row];
      float t0 = ys[row][c4 + 0] * iv;
      float t1 = ys[row][c4 + 1] * iv;
      float t2 = ys[row][c4 + 2] * iv;
      float t3 = ys[row][c4 + 3] * iv;
      v = make_float4(t0 * t0, t1 * t1, t2 * t2, t3 * t3);
    }
    o4[e] = v;
  }
}

extern "C" void kernel_launch(void* const* d_in, const int* in_sizes, int n_in,
                              void* d_out, int out_size, void* d_ws, size_t ws_size,
                              hipStream_t stream) {
  const float* x = (const float*)d_in[0];
  const float* th1 = (const float*)d_in[1];
  const float* th2 = (const float*)d_in[2];
  const float* th3 = (const float*)d_in[3];
  float* out = (float*)d_out;
  unsigned short* Vsw = (unsigned short*)d_ws;  // 256 KB swizzled V (bf16)

  build_u<<<64, 256, 0, stream>>>(th1, th2, th3, Vsw);
  pqc_main<<<512, 512, 0, stream>>>(x, Vsw, out);
}

// Round 11
// 108.846 us; speedup vs baseline: 2.2201x; 1.0002x over previous
//
#include <hip/hip_runtime.h>
#include <math.h>

// PQC autoencoder. out = g(U x), U = fixed 256x256 unitary from thetas
// (input normalization cancels: y/||y|| scale-invariant in x).
// Kernel A (build_u, ~2 us): fused-gate statevector sim -> V = [Re U; Im U]
//   as RNE f16 in MFMA-B-fragment stream order.
// Kernel B (pqc_main): SINGLE-TERM f16 MFMA GEMM (32768 x 512 x 256):
//   psi ~= A_f16 * B_f16 (11-bit mantissa vs bf16's 8 -> ~8x smaller residual
//   than R10; fp32 accumulate). R10 shape: 64 rows/block, 512 thr, grid 512
//   -> 2 blocks/CU. R11: B software pipeline (k=0 frags pre-barrier, 2-deep
//   ring in-loop), DPP row-norm (one barrier fewer), f16 1-op staging cvt.

#define DEV __device__ __forceinline__

typedef __attribute__((ext_vector_type(8))) _Float16 half8;  // 8 f16 = 4 VGPR
typedef __attribute__((ext_vector_type(4))) float f32x4;

DEV float2 cmul(float2 a, float2 b) {
  return make_float2(a.x * b.x - a.y * b.y, a.x * b.y + a.y * b.x);
}
DEV float2 cadd(float2 a, float2 b) { return make_float2(a.x + b.x, a.y + b.y); }

DEV unsigned short f16b(float v) {
  _Float16 h = (_Float16)v;                    // RNE convert
  return __builtin_bit_cast(unsigned short, h);
}

// ---- DPP cross-lane (VALU pipe, rows of 16) ------------------------------
template <int CTRL>
DEV float dppf(float v) {
  return __int_as_float(__builtin_amdgcn_mov_dpp(__float_as_int(v), CTRL, 0xF, 0xF, true));
}
DEV float px1(float v) { return dppf<0xB1>(v); }                  // lane^1
DEV float px2(float v) { return dppf<0x4E>(v); }                  // lane^2
DEV float px4(float v) { return dppf<0x1B>(dppf<0x141>(v)); }     // ^7 then ^3 = ^4
DEV float px8(float v) { return dppf<0x141>(dppf<0x140>(v)); }    // ^15 then ^7 = ^8
DEV float fsgn(float v, int m) { return __int_as_float(__float_as_int(v) ^ m); }

// ---------------------------------------------------------------------------
// Kernel A (gate math unchanged, validated R2-R10)
// ---------------------------------------------------------------------------

struct Psi4 { float re[4]; float im[4]; };
// amplitude a = (r<<6)|lane; bit q of a: q<6 -> lane bit q; q==6 -> r&1; q==7 -> r>>1

template <int Q>
DEV void pair_gate(Psi4& s, const float2* __restrict__ Mlo,
                   const float2* __restrict__ Mhi, int lane) {
  const int b0 = (lane >> Q) & 1, b1 = (lane >> (Q + 1)) & 1;
  float2 lo_d = Mlo[b0 * 2 + b0];
  float2 lo_o = Mlo[b0 * 2 + (b0 ^ 1)];
  float2 hi_d = Mhi[b1 * 2 + b1];
  float2 hi_o = Mhi[b1 * 2 + (b1 ^ 1)];
  float2 c00 = cmul(hi_d, lo_d);
  float2 c01 = cmul(hi_d, lo_o);
  float2 c10 = cmul(hi_o, lo_d);
  float2 c11 = cmul(hi_o, lo_o);
  const int m0 = 1 << Q, m1 = 2 << Q;
#pragma unroll
  for (int r = 0; r < 4; ++r) {
    float ar = s.re[r], ai = s.im[r];
    float p0r = __shfl_xor(ar, m0, 64), p0i = __shfl_xor(ai, m0, 64);
    float p1r = __shfl_xor(ar, m1, 64), p1i = __shfl_xor(ai, m1, 64);
    float p2r = __shfl_xor(ar, m0 | m1, 64), p2i = __shfl_xor(ai, m0 | m1, 64);
    float nr = c00.x * ar - c00.y * ai + c01.x * p0r - c01.y * p0i
             + c10.x * p1r - c10.y * p1i + c11.x * p2r - c11.y * p2i;
    float ni = c00.x * ai + c00.y * ar + c01.x * p0i + c01.y * p0r
             + c10.x * p1i + c10.y * p1r + c11.x * p2i + c11.y * p2r;
    s.re[r] = nr; s.im[r] = ni;
  }
}

DEV void regpair_gate(Psi4& s, const float2* __restrict__ Mlo,
                      const float2* __restrict__ Mhi) {
  float nr[4], ni[4];
#pragma unroll
  for (int r = 0; r < 4; ++r) {
    const int b0 = r & 1, b1 = (r >> 1) & 1;
    float2 c00 = cmul(Mhi[b1 * 2 + b1], Mlo[b0 * 2 + b0]);
    float2 c01 = cmul(Mhi[b1 * 2 + b1], Mlo[b0 * 2 + (b0 ^ 1)]);
    float2 c10 = cmul(Mhi[b1 * 2 + (b1 ^ 1)], Mlo[b0 * 2 + b0]);
    float2 c11 = cmul(Mhi[b1 * 2 + (b1 ^ 1)], Mlo[b0 * 2 + (b0 ^ 1)]);
    nr[r] = c00.x * s.re[r] - c00.y * s.im[r]
          + c01.x * s.re[r ^ 1] - c01.y * s.im[r ^ 1]
          + c10.x * s.re[r ^ 2] - c10.y * s.im[r ^ 2]
          + c11.x * s.re[r ^ 3] - c11.y * s.im[r ^ 3];
    ni[r] = c00.x * s.im[r] + c00.y * s.re[r]
          + c01.x * s.im[r ^ 1] + c01.y * s.re[r ^ 1]
          + c10.x * s.im[r ^ 2] + c10.y * s.re[r ^ 2]
          + c11.x * s.im[r ^ 3] + c11.y * s.re[r ^ 3];
  }
#pragma unroll
  for (int r = 0; r < 4; ++r) { s.re[r] = nr[r]; s.im[r] = ni[r]; }
}

DEV void reg0_gate(Psi4& s, const float2* __restrict__ M) {
  float nr[4], ni[4];
#pragma unroll
  for (int r = 0; r < 4; ++r) {
    const int b = r & 1;
    float2 d = M[b * 2 + b], o = M[b * 2 + (b ^ 1)];
    nr[r] = d.x * s.re[r] - d.y * s.im[r] + o.x * s.re[r ^ 1] - o.y * s.im[r ^ 1];
    ni[r] = d.x * s.im[r] + d.y * s.re[r] + o.x * s.im[r ^ 1] + o.y * s.re[r ^ 1];
  }
#pragma unroll
  for (int r = 0; r < 4; ++r) { s.re[r] = nr[r]; s.im[r] = ni[r]; }
}

template <bool FULL8>
DEV void perm_cx(Psi4& s, int lane) {
  const int slane = (lane ^ (lane << 1)) & 63;
  const bool L5 = ((lane >> 5) & 1) != 0;
  float nr[4], ni[4];
#pragma unroll
  for (int r = 0; r < 4; ++r) {
    const int r0 = r & 1, r1 = (r >> 1) & 1;
    const int hiBit = FULL8 ? (r1 ^ r0) : r1;
    const int sA = (hiBit << 1) | r0;
    const int sB = sA ^ 1;
    float aRe = __shfl(s.re[sA], slane, 64);
    float aIm = __shfl(s.im[sA], slane, 64);
    float bRe = __shfl(s.re[sB], slane, 64);
    float bIm = __shfl(s.im[sB], slane, 64);
    nr[r] = L5 ? bRe : aRe;
    ni[r] = L5 ? bIm : aIm;
  }
#pragma unroll
  for (int r = 0; r < 4; ++r) { s.re[r] = nr[r]; s.im[r] = ni[r]; }
}

template <int NQ>
DEV void ansatz_f(Psi4& s, const float2* __restrict__ Mg, int lane) {
#pragma unroll
  for (int d = 0; d < 2; ++d) {
    const float2* Md = Mg + d * NQ * 4;
    pair_gate<0>(s, Md + 0, Md + 4, lane);
    pair_gate<2>(s, Md + 8, Md + 12, lane);
    pair_gate<4>(s, Md + 16, Md + 20, lane);
    if (NQ == 8) regpair_gate(s, Md + 24, Md + 28);
    else reg0_gate(s, Md + 24);
    perm_cx<NQ == 8>(s, lane);
  }
}

// Vsw layout (single-term, validated R10): idx = k*16384 + g*512 + L*8 + jj
// g = w*8 + half*4 + t; half=0 re tiles, 1 im tiles; L = quad*16 + (n&15)
DEV void store_v(unsigned short* __restrict__ Vsw, int n, int kk, float v) {
  int k = kk >> 5, rem = kk & 31, quad = rem >> 3, jj = rem & 7;
  int nn = n & 255;
  int w = (nn >> 6) & 3, t = (nn >> 4) & 3, cl = nn & 15;
  int g = w * 8 + ((n >= 256) ? 4 + t : t);
  int L = quad * 16 + cl;
  size_t base = (size_t)k * 16384 + (size_t)g * 512 + (size_t)L * 8 + jj;
  Vsw[base] = f16b(v);
}

__global__ void build_u(const float* __restrict__ th1, const float* __restrict__ th2,
                        const float* __restrict__ th3, unsigned short* __restrict__ Vsw) {
  __shared__ float2 Mg[46 * 4];
  const int tid = threadIdx.x;
  if (tid < 46) {
    float thx, thy, thz;
    if (tid < 16)      { thx = th1[tid * 3]; thy = th1[tid * 3 + 1]; thz = th1[tid * 3 + 2]; }
    else if (tid < 30) { int u = (tid - 16) * 3; thx = th2[u]; thy = th2[u + 1]; thz = th2[u + 2]; }
    else               { int u = (tid - 30) * 3; thx = th3[u]; thy = th3[u + 1]; thz = th3[u + 2]; }
    float sx, cx_, sy, cy_, sz, cz_;
    sincosf(0.5f * thx, &sx, &cx_);
    sincosf(0.5f * thy, &sy, &cy_);
    sincosf(0.5f * thz, &sz, &cz_);
    float2 rx[4] = {{cx_, 0}, {0, -sx}, {0, -sx}, {cx_, 0}};
    float2 ry[4] = {{cy_, 0}, {-sy, 0}, {sy, 0}, {cy_, 0}};
    float2 A0 = cadd(cmul(ry[0], rx[0]), cmul(ry[1], rx[2]));
    float2 A1 = cadd(cmul(ry[0], rx[1]), cmul(ry[1], rx[3]));
    float2 A2 = cadd(cmul(ry[2], rx[0]), cmul(ry[3], rx[2]));
    float2 A3 = cadd(cmul(ry[2], rx[1]), cmul(ry[3], rx[3]));
    float2 ezm = make_float2(cz_, -sz), ezp = make_float2(cz_, sz);
    Mg[tid * 4 + 0] = cmul(ezm, A0);
    Mg[tid * 4 + 1] = cmul(ezm, A1);
    Mg[tid * 4 + 2] = cmul(ezp, A2);
    Mg[tid * 4 + 3] = cmul(ezp, A3);
  }
  __syncthreads();

  const int lane = tid & 63;
  const int j = blockIdx.x * 4 + (tid >> 6);
  Psi4 s;
#pragma unroll
  for (int r = 0; r < 4; ++r) {
    int a = (r << 6) | lane;
    s.re[r] = (a == j) ? 1.f : 0.f;
    s.im[r] = 0.f;
  }
  ansatz_f<8>(s, Mg, lane);
  ansatz_f<7>(s, Mg + 16 * 4, lane);
  ansatz_f<8>(s, Mg + 30 * 4, lane);
#pragma unroll
  for (int r = 0; r < 4; ++r) {
    int a = (r << 6) | lane;
    store_v(Vsw, a, j, s.re[r]);
    store_v(Vsw, a + 256, j, s.im[r]);
  }
}

// ---------------------------------------------------------------------------
// Kernel B: 512 blocks x 512 threads (8 waves), 64 rows/block, 2 blocks/CU.
// Wave ww: w = ww>>1 (amp slice), half = ww&1 (re|im tiles), n=64 cols/wave;
// mt = 4 row-tiles -> acc = 4x4 f32x4 = 64 AGPR. Single term f16.
// A2 col slot swizzle (cc ^ 2*quad) on write AND read: conflict-free.
// B pipeline: k=0 frags loaded pre-barrier; 2-deep ring in k-loop.
// ---------------------------------------------------------------------------

__global__ __launch_bounds__(512, 4) void pqc_main(const float* __restrict__ x,
                                                   const unsigned short* __restrict__ Vsw,
                                                   float* __restrict__ out) {
  const int tid = threadIdx.x;
  const int ww = tid >> 6;
  const int w = ww >> 1;        // amp slice: i in [w*64, w*64+64)
  const int half = ww & 1;      // 0 = re tiles, 1 = im tiles
  const int L = tid & 63;
  const int quad = L >> 4;
  const int c = L & 15;
  const int row0 = blockIdx.x * 64;

  // A2[k][mt][slot*8 + j], slot = quad*16 + (cc ^ 2*quad)  (f16, 32 KB)
  __shared__ unsigned short A2[8][4][512];
  __shared__ float ys[64][8];
  __shared__ float invn[64];
  float* part = (float*)&A2[0][0][0];        // overlay after k-loop (16 KB)

  const unsigned short* pb = Vsw + (size_t)w * 4096 + (size_t)half * 2048 + (size_t)L * 8;

  // B prefetch for k=0 (independent of LDS staging; latency hides under it)
  half8 b0 = *(const half8*)(pb);
  half8 b1 = *(const half8*)(pb + 512);

  // ---- stage A: 64 rows x 256 cols; lane covers 8 rows (r8) x wave k-group.
  {
    const float4* xsrc = (const float4*)(x + (size_t)row0 * 256);
    const int r8 = L & 7;            // row within group of 8
    const int kf = L >> 3;           // fine col 0..7 within wave's k-group
    const int q = kf >> 1;
    const int jj0 = (kf & 1) * 4;
#pragma unroll
    for (int i = 0; i < 8; ++i) {
      int row = i * 8 + r8;
      float4 f = xsrc[row * 64 + ww * 8 + kf];
      ushort4 h;
      h.x = f16b(f.x); h.y = f16b(f.y); h.z = f16b(f.z); h.w = f16b(f.w);
      int mt = row >> 4, cc = row & 15;
      int idx = (q * 16 + (cc ^ (q << 1))) * 8 + jj0;
      *(ushort4*)&A2[ww][mt][idx] = h;
    }
  }
  __syncthreads();

  // ---- MFMA K-loop (single term, 2-deep B ring)
  f32x4 acc[4][4];
#pragma unroll
  for (int mt = 0; mt < 4; ++mt)
#pragma unroll
    for (int tt = 0; tt < 4; ++tt) acc[mt][tt] = (f32x4){0.f, 0.f, 0.f, 0.f};

  const int sL8 = (quad * 16 + (c ^ (quad << 1))) * 8;   // swizzled A slot

#pragma unroll 1   // cap unroll: pipeline 1 k-iter deep, keep regs in budget
  for (int k = 0; k < 8; ++k) {
    half8 ah[4];
#pragma unroll
    for (int mt = 0; mt < 4; ++mt)
      ah[mt] = *(const half8*)&A2[k][mt][sL8];
    const unsigned short* pk = pb + (size_t)k * 16384;
    const unsigned short* pn = pb + (size_t)((k < 7) ? k + 1 : k) * 16384;

    half8 b2 = *(const half8*)(pk + 2 * 512);
#pragma unroll
    for (int mt = 0; mt < 4; ++mt)
      acc[mt][0] = __builtin_amdgcn_mfma_f32_16x16x32_f16(ah[mt], b0, acc[mt][0], 0, 0, 0);
    half8 b3 = *(const half8*)(pk + 3 * 512);
#pragma unroll
    for (int mt = 0; mt < 4; ++mt)
      acc[mt][1] = __builtin_amdgcn_mfma_f32_16x16x32_f16(ah[mt], b1, acc[mt][1], 0, 0, 0);
    b0 = *(const half8*)(pn);
#pragma unroll
    for (int mt = 0; mt < 4; ++mt)
      acc[mt][2] = __builtin_amdgcn_mfma_f32_16x16x32_f16(ah[mt], b2, acc[mt][2], 0, 0, 0);
    b1 = *(const half8*)(pn + 512);
#pragma unroll
    for (int mt = 0; mt < 4; ++mt)
      acc[mt][3] = __builtin_amdgcn_mfma_f32_16x16x32_f16(ah[mt], b3, acc[mt][3], 0, 0, 0);
  }
  __syncthreads();   // A2 dead; part overlay becomes valid

  // ---- epilogue: partial probs (re^2 or im^2) -> signed Walsh via DPP.
  // D layout: row m = mt*16 + quad*4 + r, col = c; tile tt covers amps
  // i = w*64 + tt*16 + c.
  const int m1 = (c & 1) << 31;
  const int m2 = (c & 2) << 30;
  const int m4 = (c & 4) << 29;
  const int m8 = (c & 8) << 28;
#pragma unroll
  for (int mt = 0; mt < 4; ++mt) {
#pragma unroll
    for (int r = 0; r < 4; ++r) {
      float p0 = acc[mt][0][r] * acc[mt][0][r];
      float p1 = acc[mt][1][r] * acc[mt][1][r];
      float p2 = acc[mt][2][r] * acc[mt][2][r];
      float p3 = acc[mt][3][r] * acc[mt][3][r];
      float s01 = p0 + p1, s23 = p2 + p3;
      float av = s01 + s23;               // -> j=0,1,4..7
      float bv = s01 - s23;               // sign bit5 (tt>>1) -> j=2
      float cv = (p0 - p1) + (p2 - p3);   // sign bit4 (tt&1) -> j=3
      av = px1(av) + fsgn(av, m1);
      bv += px1(bv);  cv += px1(cv);
      av = px2(av) + fsgn(av, m2);
      bv += px2(bv);  cv += px2(cv);
      av = px4(av) + fsgn(av, m4);
      bv += px4(bv);  cv += px4(cv);
      av = px8(av) + fsgn(av, m8);
      bv += px8(bv);  cv += px8(cv);
      int m = mt * 16 + quad * 4 + r;
      float* pm = part + (ww * 64 + m) * 8;
      if (c == 0) {
        pm[0] = ((w >> 1) & 1) ? -av : av;  // j=0: bit7(i)
        pm[1] = (w & 1) ? -av : av;         // j=1: bit6(i)
        pm[2] = bv;
        pm[3] = cv;
      } else if (c == 8) pm[4] = av;   // j=4: bit3
      else if (c == 4) pm[5] = av;     // j=5: bit2
      else if (c == 2) pm[6] = av;     // j=6: bit1
      else if (c == 1) pm[7] = av;     // j=7: bit0
    }
  }
  __syncthreads();

  {  // ys + row-norm in ONE phase: jj lives in 8 consecutive lanes -> DPP reduce
    int m = tid >> 3, jj = tid & 7;
    float acc_y = 0.f;
#pragma unroll
    for (int p = 0; p < 8; ++p) acc_y += part[(p * 64 + m) * 8 + jj];
    ys[m][jj] = acc_y;
    float sq = acc_y * acc_y;
    sq += px1(sq);
    sq += px2(sq);
    sq += px4(sq);          // all 8 lanes of the jj-group now hold sum_j y_j^2
    if (jj == 0) invn[m] = (sq == 0.f) ? 0.f : 1.f / sqrtf(sq);
  }
  __syncthreads();

  // ---- write out: 64 rows x 64 float4 = 4096 float4, 8 per thread
  float4* o4 = (float4*)(out + (size_t)row0 * 256);
#pragma unroll
  for (int i = 0; i < 8; ++i) {
    int e = i * 512 + tid;
    int row = e >> 6;
    int c4 = (e & 63) * 4;
    float4 v = make_float4(0.f, 0.f, 0.f, 0.f);
    if (c4 < 8) {
      float iv = invn[row];
      float t0 = ys[row][c4 + 0] * iv;
      float t1 = ys[row][c4 + 1] * iv;
      float t2 = ys[row][c4 + 2] * iv;
      float t3 = ys[row][c4 + 3] * iv;
      v = make_float4(t0 * t0, t1 * t1, t2 * t2, t3 * t3);
    }
    o4[e] = v;
  }
}

extern "C" void kernel_launch(void* const* d_in, const int* in_sizes, int n_in,
                              void* d_out, int out_size, void* d_ws, size_t ws_size,
                              hipStream_t stream) {
  const float* x = (const float*)d_in[0];
  const float* th1 = (const float*)d_in[1];
  const float* th2 = (const float*)d_in[2];
  const float* th3 = (const float*)d_in[3];
  float* out = (float*)d_out;
  unsigned short* Vsw = (unsigned short*)d_ws;  // 256 KB swizzled V (f16)

  build_u<<<64, 256, 0, stream>>>(th1, th2, th3, Vsw);
  pqc_main<<<512, 512, 0, stream>>>(x, Vsw, out);
}